// Round 1
// baseline (1088.996 us; speedup 1.0000x reference)
//
#include <hip/hip_runtime.h>
#include <hip/hip_bf16.h>

#define N_NODES 50000
#define N_EDGES 640000
#define HIDDEN 128
#define N_LAYERS 4
#define NUM_RBF 50
#define CUTOFF 4.0f
#define N_GRAPHS 64
#define TAB 2048

// ---------------------------------------------------------------------------
// Filter table: w_i(d) tabulated on TAB grid points over [0, CUTOFF].
// One block (128 threads) per (layer, grid point).
__global__ void k_table(const float* __restrict__ fw1, const float* __restrict__ fb1,
                        const float* __restrict__ fw2, const float* __restrict__ fb2,
                        float* __restrict__ table) {
    int bid = blockIdx.x;
    int layer = bid / TAB;
    int g = bid % TAB;
    int j = threadIdx.x;
    __shared__ float rbf[NUM_RBF];
    __shared__ float hid[HIDDEN];
    float d = (CUTOFF * g) / (float)(TAB - 1);
    if (j < NUM_RBF) {
        float offset = (CUTOFF * j) / (float)(NUM_RBF - 1);
        float delta = CUTOFF / (float)(NUM_RBF - 1);
        float coeff = -0.5f / (delta * delta);
        float t = d - offset;
        rbf[j] = expf(coeff * t * t);
    }
    __syncthreads();
    const float* w1 = fw1 + layer * NUM_RBF * HIDDEN;
    float acc = fb1[layer * HIDDEN + j];
    #pragma unroll 10
    for (int r = 0; r < NUM_RBF; r++) acc = fmaf(rbf[r], w1[r * HIDDEN + j], acc);
    hid[j] = fmaxf(acc, 0.0f);
    __syncthreads();
    const float* w2 = fw2 + layer * HIDDEN * HIDDEN;
    float acc2 = fb2[layer * HIDDEN + j];
    #pragma unroll 8
    for (int k = 0; k < HIDDEN; k++) acc2 = fmaf(hid[k], w2[k * HIDDEN + j], acc2);
    table[(layer * TAB + g) * HIDDEN + j] = acc2;
}

// ---------------------------------------------------------------------------
// Embedding gather: h[n][:] = emb[x[n]][:]
__global__ void k_embed(const int* __restrict__ x, const float* __restrict__ emb,
                        float* __restrict__ h) {
    int idx = blockIdx.x * 256 + threadIdx.x;   // over N_NODES*32 float4s
    if (idx >= N_NODES * 32) return;
    int n = idx >> 5, q = idx & 31;
    ((float4*)h)[idx] = ((const float4*)emb)[x[n] * 32 + q];
}

// ---------------------------------------------------------------------------
// CSR build (by destination = row)
__global__ void k_count(const int* __restrict__ row, int* __restrict__ counts) {
    int e = blockIdx.x * 256 + threadIdx.x;
    if (e < N_EDGES) atomicAdd(&counts[row[e]], 1);
}

__global__ void k_scan1(const int* __restrict__ counts, int* __restrict__ partial,
                        int* __restrict__ blocksum) {
    int i = blockIdx.x * 256 + threadIdx.x;
    int v = (i < N_NODES) ? counts[i] : 0;
    int lane = threadIdx.x & 63;
    int wid = threadIdx.x >> 6;
    int s = v;
    #pragma unroll
    for (int off = 1; off < 64; off <<= 1) {
        int t = __shfl_up(s, off, 64);
        if (lane >= off) s += t;
    }
    __shared__ int wsum[4];
    if (lane == 63) wsum[wid] = s;
    __syncthreads();
    int woff = 0;
    for (int w = 0; w < wid; w++) woff += wsum[w];
    int incl = s + woff;
    if (i < N_NODES) partial[i] = incl - v;           // exclusive within block
    if (threadIdx.x == 255) blocksum[blockIdx.x] = incl;
}

__global__ void k_scan2(int* __restrict__ blocksum, int nblk) {
    int tid = threadIdx.x;
    int v = (tid < nblk) ? blocksum[tid] : 0;
    int lane = tid & 63, wid = tid >> 6;
    int s = v;
    #pragma unroll
    for (int off = 1; off < 64; off <<= 1) {
        int t = __shfl_up(s, off, 64);
        if (lane >= off) s += t;
    }
    __shared__ int wsum[4];
    if (lane == 63) wsum[wid] = s;
    __syncthreads();
    int woff = 0;
    for (int w = 0; w < wid; w++) woff += wsum[w];
    int incl = s + woff;
    if (tid < nblk) blocksum[tid] = incl - v;         // exclusive
}

__global__ void k_scan3(const int* __restrict__ partial, const int* __restrict__ blocksum,
                        int* __restrict__ offsets, int* __restrict__ cursor) {
    int i = blockIdx.x * 256 + threadIdx.x;
    if (i < N_NODES) {
        int o = partial[i] + blocksum[blockIdx.x];
        offsets[i] = o;
        cursor[i] = o;
    }
    if (i == 0) offsets[N_NODES] = N_EDGES;
}

// Pack per-edge (col, table coordinate t) into CSR slots.
__global__ void k_fill(const int* __restrict__ row, const int* __restrict__ col,
                       const float* __restrict__ eattr, int* __restrict__ cursor,
                       int2* __restrict__ meta) {
    int e = blockIdx.x * 256 + threadIdx.x;
    if (e >= N_EDGES) return;
    int r = row[e];
    int pos = atomicAdd(&cursor[r], 1);
    float t = eattr[e] * ((float)(TAB - 1) / CUTOFF);
    t = fminf(fmaxf(t, 0.0f), (float)(TAB - 2) + 0.9999f);
    int2 m;
    m.x = col[e];
    m.y = __float_as_int(t);
    meta[pos] = m;
}

// ---------------------------------------------------------------------------
// xl = h @ lw + lb  (fp32 register-tiled GEMM, 4 nodes x 4 outputs / thread)
__global__ __launch_bounds__(256) void k_xl(const float* __restrict__ h,
                                            const float* __restrict__ lw,
                                            const float* __restrict__ lb,
                                            float* __restrict__ xl) {
    int jt = threadIdx.x & 31;       // output group: j = jt*4 .. jt*4+3
    int mt = threadIdx.x >> 5;       // 0..7
    int n0 = blockIdx.x * 32 + mt * 4;
    const float4* lw4 = (const float4*)lw;
    const float4* h4 = (const float4*)h;
    float4 bias = ((const float4*)lb)[jt];
    float4 acc[4];
    #pragma unroll
    for (int r = 0; r < 4; r++) acc[r] = bias;
    for (int k4 = 0; k4 < 32; k4++) {
        float4 w0 = lw4[(4 * k4 + 0) * 32 + jt];
        float4 w1 = lw4[(4 * k4 + 1) * 32 + jt];
        float4 w2 = lw4[(4 * k4 + 2) * 32 + jt];
        float4 w3 = lw4[(4 * k4 + 3) * 32 + jt];
        #pragma unroll
        for (int r = 0; r < 4; r++) {
            int n = n0 + r;
            int nc = n < N_NODES ? n : N_NODES - 1;
            float4 hv = h4[nc * 32 + k4];
            acc[r].x = fmaf(hv.x, w0.x, fmaf(hv.y, w1.x, fmaf(hv.z, w2.x, fmaf(hv.w, w3.x, acc[r].x))));
            acc[r].y = fmaf(hv.x, w0.y, fmaf(hv.y, w1.y, fmaf(hv.z, w2.y, fmaf(hv.w, w3.y, acc[r].y))));
            acc[r].z = fmaf(hv.x, w0.z, fmaf(hv.y, w1.z, fmaf(hv.z, w2.z, fmaf(hv.w, w3.z, acc[r].z))));
            acc[r].w = fmaf(hv.x, w0.w, fmaf(hv.y, w1.w, fmaf(hv.z, w2.w, fmaf(hv.w, w3.w, acc[r].w))));
        }
    }
    #pragma unroll
    for (int r = 0; r < 4; r++) {
        int n = n0 + r;
        if (n < N_NODES) ((float4*)xl)[n * 32 + jt] = acc[r];
    }
}

// ---------------------------------------------------------------------------
// Aggregation + residual + LayerNorm, fused. One wave (64 lanes x float2) per node.
__global__ __launch_bounds__(256) void k_agg(const float* __restrict__ xl,
                                             const int2* __restrict__ meta,
                                             const int* __restrict__ offsets,
                                             const float* __restrict__ tab,
                                             const float* __restrict__ h_in,
                                             const float* __restrict__ g,
                                             const float* __restrict__ b,
                                             float* __restrict__ h_out) {
    int wid = threadIdx.x >> 6;
    int lane = threadIdx.x & 63;
    int n = blockIdx.x * 4 + wid;
    if (n >= N_NODES) return;
    const float2* xl2 = (const float2*)xl;
    const float2* tab2 = (const float2*)tab;
    float accx = 0.f, accy = 0.f;
    int p0 = offsets[n], p1 = offsets[n + 1];
    for (int p = p0; p < p1; p++) {
        int2 m = meta[p];
        float t = __int_as_float(m.y);
        int i0 = (int)t;
        float fr = t - (float)i0;
        float2 w0 = tab2[i0 * 64 + lane];
        float2 w1 = tab2[(i0 + 1) * 64 + lane];
        float2 xv = xl2[m.x * 64 + lane];
        float wx = fmaf(fr, w1.x - w0.x, w0.x);
        float wy = fmaf(fr, w1.y - w0.y, w0.y);
        accx = fmaf(wx, xv.x, accx);
        accy = fmaf(wy, xv.y, accy);
    }
    float2 hv = ((const float2*)h_in)[n * 64 + lane];
    float vx = hv.x + accx, vy = hv.y + accy;
    float s = vx + vy;
    #pragma unroll
    for (int off = 32; off; off >>= 1) s += __shfl_xor(s, off, 64);
    float mu = s * (1.0f / 128.0f);
    float dx = vx - mu, dy = vy - mu;
    float s2 = dx * dx + dy * dy;
    #pragma unroll
    for (int off = 32; off; off >>= 1) s2 += __shfl_xor(s2, off, 64);
    float rstd = rsqrtf(s2 * (1.0f / 128.0f) + 1e-5f);
    float2 gv = ((const float2*)g)[lane];
    float2 bv = ((const float2*)b)[lane];
    float2 o;
    o.x = fmaf(dx * rstd, gv.x, bv.x);
    o.y = fmaf(dy * rstd, gv.y, bv.y);
    ((float2*)h_out)[n * 64 + lane] = o;
}

// ---------------------------------------------------------------------------
// Global mean pool
__global__ void k_pool(const float* __restrict__ h, const int* __restrict__ batch,
                       float* __restrict__ pool) {
    int idx = blockIdx.x * 256 + threadIdx.x;
    if (idx >= N_NODES * HIDDEN) return;
    int n = idx >> 7;
    int j = idx & 127;
    atomicAdd(&pool[batch[n] * HIDDEN + j], h[idx]);
}

__global__ void k_cnt(const int* __restrict__ batch, int* __restrict__ cnt) {
    int n = blockIdx.x * 256 + threadIdx.x;
    if (n < N_NODES) atomicAdd(&cnt[batch[n]], 1);
}

__global__ void k_final(const float* __restrict__ pool, const int* __restrict__ cnt,
                        float* __restrict__ out) {
    int idx = blockIdx.x * 256 + threadIdx.x;
    if (idx >= N_GRAPHS * HIDDEN) return;
    int gg = idx >> 7;
    float c = (float)cnt[gg];
    out[idx] = pool[idx] / fmaxf(c, 1.0f);
}

// ---------------------------------------------------------------------------
extern "C" void kernel_launch(void* const* d_in, const int* in_sizes, int n_in,
                              void* d_out, int out_size, void* d_ws, size_t ws_size,
                              hipStream_t stream) {
    const int* x = (const int*)d_in[0];
    const int* edge_index = (const int*)d_in[1];
    const int* row = edge_index;               // edge_index[0]
    const int* col = edge_index + N_EDGES;     // edge_index[1]
    const float* eattr = (const float*)d_in[2];
    const int* batch = (const int*)d_in[3];
    const float* emb = (const float*)d_in[4];
    const float* fw1 = (const float*)d_in[5];
    const float* fb1 = (const float*)d_in[6];
    const float* fw2 = (const float*)d_in[7];
    const float* fb2 = (const float*)d_in[8];
    const float* lw = (const float*)d_in[9];
    const float* lb = (const float*)d_in[10];
    const float* ln_g = (const float*)d_in[11];
    const float* ln_b = (const float*)d_in[12];
    float* out = (float*)d_out;

    char* ws = (char*)d_ws;
    size_t off = 0;
    auto alloc = [&](size_t bytes) -> void* {
        void* p = ws + off;
        off = (off + bytes + 255) & ~(size_t)255;
        return p;
    };
    float* table  = (float*)alloc((size_t)N_LAYERS * TAB * HIDDEN * 4);
    float* h_a    = (float*)alloc((size_t)N_NODES * HIDDEN * 4);
    float* h_b    = (float*)alloc((size_t)N_NODES * HIDDEN * 4);
    float* xl     = (float*)alloc((size_t)N_NODES * HIDDEN * 4);
    int* counts   = (int*)alloc((size_t)(N_NODES + 1) * 4);
    int* offsets  = (int*)alloc((size_t)(N_NODES + 1) * 4);
    int* cursor   = (int*)alloc((size_t)N_NODES * 4);
    int* partial  = (int*)alloc((size_t)N_NODES * 4);
    int* blocksum = (int*)alloc(256 * 4);
    int2* meta    = (int2*)alloc((size_t)N_EDGES * 8);
    float* pool   = (float*)alloc((size_t)N_GRAPHS * HIDDEN * 4);
    int* cnt      = (int*)alloc((size_t)N_GRAPHS * 4);

    hipMemsetAsync(counts, 0, (size_t)(N_NODES + 1) * 4, stream);
    hipMemsetAsync(pool, 0, (size_t)N_GRAPHS * HIDDEN * 4, stream);
    hipMemsetAsync(cnt, 0, (size_t)N_GRAPHS * 4, stream);

    k_table<<<N_LAYERS * TAB, HIDDEN, 0, stream>>>(fw1, fb1, fw2, fb2, table);
    k_embed<<<(N_NODES * 32 + 255) / 256, 256, 0, stream>>>(x, emb, h_a);
    k_count<<<(N_EDGES + 255) / 256, 256, 0, stream>>>(row, counts);
    const int NBLK = (N_NODES + 255) / 256;   // 196
    k_scan1<<<NBLK, 256, 0, stream>>>(counts, partial, blocksum);
    k_scan2<<<1, 256, 0, stream>>>(blocksum, NBLK);
    k_scan3<<<NBLK, 256, 0, stream>>>(partial, blocksum, offsets, cursor);
    k_fill<<<(N_EDGES + 255) / 256, 256, 0, stream>>>(row, col, eattr, cursor, meta);

    float* h_cur = h_a;
    float* h_nxt = h_b;
    for (int i = 0; i < N_LAYERS; i++) {
        k_xl<<<(N_NODES + 31) / 32, 256, 0, stream>>>(h_cur, lw + i * HIDDEN * HIDDEN,
                                                      lb + i * HIDDEN, xl);
        k_agg<<<(N_NODES + 3) / 4, 256, 0, stream>>>(xl, meta, offsets,
                                                     table + (size_t)i * TAB * HIDDEN,
                                                     h_cur, ln_g + i * HIDDEN,
                                                     ln_b + i * HIDDEN, h_nxt);
        float* tmp = h_cur; h_cur = h_nxt; h_nxt = tmp;
    }
    k_pool<<<(N_NODES * HIDDEN + 255) / 256, 256, 0, stream>>>(h_cur, batch, pool);
    k_cnt<<<(N_NODES + 255) / 256, 256, 0, stream>>>(batch, cnt);
    k_final<<<(N_GRAPHS * HIDDEN + 255) / 256, 256, 0, stream>>>(pool, cnt, out);
}

// Round 2
// 889.125 us; speedup vs baseline: 1.2248x; 1.2248x over previous
//
#include <hip/hip_runtime.h>
#include <hip/hip_bf16.h>

#define N_NODES 50000
#define N_EDGES 640000
#define HIDDEN 128
#define N_LAYERS 4
#define NUM_RBF 50
#define CUTOFF 4.0f
#define N_GRAPHS 64
#define TAB 2048

// ---------------------------------------------------------------------------
// Filter table: w_i(d) tabulated on TAB grid points over [0, CUTOFF].
// One block (128 threads) per (layer, grid point).
__global__ void k_table(const float* __restrict__ fw1, const float* __restrict__ fb1,
                        const float* __restrict__ fw2, const float* __restrict__ fb2,
                        float* __restrict__ table) {
    int bid = blockIdx.x;
    int layer = bid / TAB;
    int g = bid % TAB;
    int j = threadIdx.x;
    __shared__ float rbf[NUM_RBF];
    __shared__ float hid[HIDDEN];
    float d = (CUTOFF * g) / (float)(TAB - 1);
    if (j < NUM_RBF) {
        float offset = (CUTOFF * j) / (float)(NUM_RBF - 1);
        float delta = CUTOFF / (float)(NUM_RBF - 1);
        float coeff = -0.5f / (delta * delta);
        float t = d - offset;
        rbf[j] = expf(coeff * t * t);
    }
    __syncthreads();
    const float* w1 = fw1 + layer * NUM_RBF * HIDDEN;
    float acc = fb1[layer * HIDDEN + j];
    #pragma unroll 10
    for (int r = 0; r < NUM_RBF; r++) acc = fmaf(rbf[r], w1[r * HIDDEN + j], acc);
    hid[j] = fmaxf(acc, 0.0f);
    __syncthreads();
    const float* w2 = fw2 + layer * HIDDEN * HIDDEN;
    float acc2 = fb2[layer * HIDDEN + j];
    #pragma unroll 8
    for (int k = 0; k < HIDDEN; k++) acc2 = fmaf(hid[k], w2[k * HIDDEN + j], acc2);
    table[(layer * TAB + g) * HIDDEN + j] = acc2;
}

// ---------------------------------------------------------------------------
// Embedding gather: h[n][:] = emb[x[n]][:]
__global__ void k_embed(const int* __restrict__ x, const float* __restrict__ emb,
                        float* __restrict__ h) {
    int idx = blockIdx.x * 256 + threadIdx.x;   // over N_NODES*32 float4s
    if (idx >= N_NODES * 32) return;
    int n = idx >> 5, q = idx & 31;
    ((float4*)h)[idx] = ((const float4*)emb)[x[n] * 32 + q];
}

// ---------------------------------------------------------------------------
// CSR build (by destination = row). row is ~uniform-random -> low contention.
__global__ void k_count(const int* __restrict__ row, int* __restrict__ counts) {
    int e = blockIdx.x * 256 + threadIdx.x;
    if (e < N_EDGES) atomicAdd(&counts[row[e]], 1);
}

__global__ void k_scan1(const int* __restrict__ counts, int* __restrict__ partial,
                        int* __restrict__ blocksum) {
    int i = blockIdx.x * 256 + threadIdx.x;
    int v = (i < N_NODES) ? counts[i] : 0;
    int lane = threadIdx.x & 63;
    int wid = threadIdx.x >> 6;
    int s = v;
    #pragma unroll
    for (int off = 1; off < 64; off <<= 1) {
        int t = __shfl_up(s, off, 64);
        if (lane >= off) s += t;
    }
    __shared__ int wsum[4];
    if (lane == 63) wsum[wid] = s;
    __syncthreads();
    int woff = 0;
    for (int w = 0; w < wid; w++) woff += wsum[w];
    int incl = s + woff;
    if (i < N_NODES) partial[i] = incl - v;           // exclusive within block
    if (threadIdx.x == 255) blocksum[blockIdx.x] = incl;
}

__global__ void k_scan2(int* __restrict__ blocksum, int nblk) {
    int tid = threadIdx.x;
    int v = (tid < nblk) ? blocksum[tid] : 0;
    int lane = tid & 63, wid = tid >> 6;
    int s = v;
    #pragma unroll
    for (int off = 1; off < 64; off <<= 1) {
        int t = __shfl_up(s, off, 64);
        if (lane >= off) s += t;
    }
    __shared__ int wsum[4];
    if (lane == 63) wsum[wid] = s;
    __syncthreads();
    int woff = 0;
    for (int w = 0; w < wid; w++) woff += wsum[w];
    int incl = s + woff;
    if (tid < nblk) blocksum[tid] = incl - v;         // exclusive
}

__global__ void k_scan3(const int* __restrict__ partial, const int* __restrict__ blocksum,
                        int* __restrict__ offsets, int* __restrict__ cursor) {
    int i = blockIdx.x * 256 + threadIdx.x;
    if (i < N_NODES) {
        int o = partial[i] + blocksum[blockIdx.x];
        offsets[i] = o;
        cursor[i] = o;
    }
    if (i == 0) offsets[N_NODES] = N_EDGES;
}

// Pack per-edge (col, table coordinate t) into CSR slots.
__global__ void k_fill(const int* __restrict__ row, const int* __restrict__ col,
                       const float* __restrict__ eattr, int* __restrict__ cursor,
                       int2* __restrict__ meta) {
    int e = blockIdx.x * 256 + threadIdx.x;
    if (e >= N_EDGES) return;
    int r = row[e];
    int pos = atomicAdd(&cursor[r], 1);
    float t = eattr[e] * ((float)(TAB - 1) / CUTOFF);
    t = fminf(fmaxf(t, 0.0f), (float)(TAB - 2) + 0.9999f);
    int2 m;
    m.x = col[e];
    m.y = __float_as_int(t);
    meta[pos] = m;
}

// ---------------------------------------------------------------------------
// xl = h @ lw + lb  (fp32 register-tiled GEMM, 4 nodes x 4 outputs / thread)
__global__ __launch_bounds__(256) void k_xl(const float* __restrict__ h,
                                            const float* __restrict__ lw,
                                            const float* __restrict__ lb,
                                            float* __restrict__ xl) {
    int jt = threadIdx.x & 31;       // output group: j = jt*4 .. jt*4+3
    int mt = threadIdx.x >> 5;       // 0..7
    int n0 = blockIdx.x * 32 + mt * 4;
    const float4* lw4 = (const float4*)lw;
    const float4* h4 = (const float4*)h;
    float4 bias = ((const float4*)lb)[jt];
    float4 acc[4];
    #pragma unroll
    for (int r = 0; r < 4; r++) acc[r] = bias;
    for (int k4 = 0; k4 < 32; k4++) {
        float4 w0 = lw4[(4 * k4 + 0) * 32 + jt];
        float4 w1 = lw4[(4 * k4 + 1) * 32 + jt];
        float4 w2 = lw4[(4 * k4 + 2) * 32 + jt];
        float4 w3 = lw4[(4 * k4 + 3) * 32 + jt];
        #pragma unroll
        for (int r = 0; r < 4; r++) {
            int n = n0 + r;
            int nc = n < N_NODES ? n : N_NODES - 1;
            float4 hv = h4[nc * 32 + k4];
            acc[r].x = fmaf(hv.x, w0.x, fmaf(hv.y, w1.x, fmaf(hv.z, w2.x, fmaf(hv.w, w3.x, acc[r].x))));
            acc[r].y = fmaf(hv.x, w0.y, fmaf(hv.y, w1.y, fmaf(hv.z, w2.y, fmaf(hv.w, w3.y, acc[r].y))));
            acc[r].z = fmaf(hv.x, w0.z, fmaf(hv.y, w1.z, fmaf(hv.z, w2.z, fmaf(hv.w, w3.z, acc[r].z))));
            acc[r].w = fmaf(hv.x, w0.w, fmaf(hv.y, w1.w, fmaf(hv.z, w2.w, fmaf(hv.w, w3.w, acc[r].w))));
        }
    }
    #pragma unroll
    for (int r = 0; r < 4; r++) {
        int n = n0 + r;
        if (n < N_NODES) ((float4*)xl)[n * 32 + jt] = acc[r];
    }
}

// ---------------------------------------------------------------------------
// Aggregation + residual + LayerNorm, fused. One wave (64 lanes x float2) per node.
__global__ __launch_bounds__(256) void k_agg(const float* __restrict__ xl,
                                             const int2* __restrict__ meta,
                                             const int* __restrict__ offsets,
                                             const float* __restrict__ tab,
                                             const float* __restrict__ h_in,
                                             const float* __restrict__ g,
                                             const float* __restrict__ b,
                                             float* __restrict__ h_out) {
    int wid = threadIdx.x >> 6;
    int lane = threadIdx.x & 63;
    int n = blockIdx.x * 4 + wid;
    if (n >= N_NODES) return;
    const float2* xl2 = (const float2*)xl;
    const float2* tab2 = (const float2*)tab;
    float accx = 0.f, accy = 0.f;
    int p0 = offsets[n], p1 = offsets[n + 1];
    for (int p = p0; p < p1; p++) {
        int2 m = meta[p];
        float t = __int_as_float(m.y);
        int i0 = (int)t;
        float fr = t - (float)i0;
        float2 w0 = tab2[i0 * 64 + lane];
        float2 w1 = tab2[(i0 + 1) * 64 + lane];
        float2 xv = xl2[m.x * 64 + lane];
        float wx = fmaf(fr, w1.x - w0.x, w0.x);
        float wy = fmaf(fr, w1.y - w0.y, w0.y);
        accx = fmaf(wx, xv.x, accx);
        accy = fmaf(wy, xv.y, accy);
    }
    float2 hv = ((const float2*)h_in)[n * 64 + lane];
    float vx = hv.x + accx, vy = hv.y + accy;
    float s = vx + vy;
    #pragma unroll
    for (int off = 32; off; off >>= 1) s += __shfl_xor(s, off, 64);
    float mu = s * (1.0f / 128.0f);
    float dx = vx - mu, dy = vy - mu;
    float s2 = dx * dx + dy * dy;
    #pragma unroll
    for (int off = 32; off; off >>= 1) s2 += __shfl_xor(s2, off, 64);
    float rstd = rsqrtf(s2 * (1.0f / 128.0f) + 1e-5f);
    float2 gv = ((const float2*)g)[lane];
    float2 bv = ((const float2*)b)[lane];
    float2 o;
    o.x = fmaf(dx * rstd, gv.x, bv.x);
    o.y = fmaf(dy * rstd, gv.y, bv.y);
    ((float2*)h_out)[n * 64 + lane] = o;
}

// ---------------------------------------------------------------------------
// Graph boundaries via binary search (batch is sorted). gstart[g] = first node
// with batch >= g; gstart[N_GRAPHS] = N_NODES.
__global__ void k_bounds(const int* __restrict__ batch, int* __restrict__ gstart) {
    int g = threadIdx.x;
    if (g > N_GRAPHS) return;
    int lo = 0, hi = N_NODES;
    while (lo < hi) {
        int mid = (lo + hi) >> 1;
        if (batch[mid] < g) lo = mid + 1; else hi = mid;
    }
    gstart[g] = lo;
}

// Mean pool per graph: one block per graph, 256 threads = 2 node-rows x 128 feats.
__global__ __launch_bounds__(256) void k_pool2(const float* __restrict__ h,
                                               const int* __restrict__ gstart,
                                               float* __restrict__ out) {
    int g = blockIdx.x;
    int j = threadIdx.x & 127;
    int half = threadIdx.x >> 7;
    int s = gstart[g], e = gstart[g + 1];
    float acc = 0.f;
    for (int n = s + half; n < e; n += 2) acc += h[n * HIDDEN + j];
    __shared__ float red[256];
    red[threadIdx.x] = acc;
    __syncthreads();
    if (half == 0) {
        float tot = red[j] + red[j + 128];
        float c = (float)(e - s);
        out[g * HIDDEN + j] = tot / fmaxf(c, 1.0f);
    }
}

// ---------------------------------------------------------------------------
extern "C" void kernel_launch(void* const* d_in, const int* in_sizes, int n_in,
                              void* d_out, int out_size, void* d_ws, size_t ws_size,
                              hipStream_t stream) {
    const int* x = (const int*)d_in[0];
    const int* edge_index = (const int*)d_in[1];
    const int* row = edge_index;               // edge_index[0]
    const int* col = edge_index + N_EDGES;     // edge_index[1]
    const float* eattr = (const float*)d_in[2];
    const int* batch = (const int*)d_in[3];
    const float* emb = (const float*)d_in[4];
    const float* fw1 = (const float*)d_in[5];
    const float* fb1 = (const float*)d_in[6];
    const float* fw2 = (const float*)d_in[7];
    const float* fb2 = (const float*)d_in[8];
    const float* lw = (const float*)d_in[9];
    const float* lb = (const float*)d_in[10];
    const float* ln_g = (const float*)d_in[11];
    const float* ln_b = (const float*)d_in[12];
    float* out = (float*)d_out;

    char* ws = (char*)d_ws;
    size_t off = 0;
    auto alloc = [&](size_t bytes) -> void* {
        void* p = ws + off;
        off = (off + bytes + 255) & ~(size_t)255;
        return p;
    };
    float* table  = (float*)alloc((size_t)N_LAYERS * TAB * HIDDEN * 4);
    float* h_a    = (float*)alloc((size_t)N_NODES * HIDDEN * 4);
    float* h_b    = (float*)alloc((size_t)N_NODES * HIDDEN * 4);
    float* xl     = (float*)alloc((size_t)N_NODES * HIDDEN * 4);
    int* counts   = (int*)alloc((size_t)(N_NODES + 1) * 4);
    int* offsets  = (int*)alloc((size_t)(N_NODES + 1) * 4);
    int* cursor   = (int*)alloc((size_t)N_NODES * 4);
    int* partial  = (int*)alloc((size_t)N_NODES * 4);
    int* blocksum = (int*)alloc(256 * 4);
    int2* meta    = (int2*)alloc((size_t)N_EDGES * 8);
    int* gstart   = (int*)alloc((size_t)(N_GRAPHS + 1) * 4);

    hipMemsetAsync(counts, 0, (size_t)(N_NODES + 1) * 4, stream);

    k_table<<<N_LAYERS * TAB, HIDDEN, 0, stream>>>(fw1, fb1, fw2, fb2, table);
    k_embed<<<(N_NODES * 32 + 255) / 256, 256, 0, stream>>>(x, emb, h_a);
    k_count<<<(N_EDGES + 255) / 256, 256, 0, stream>>>(row, counts);
    const int NBLK = (N_NODES + 255) / 256;   // 196
    k_scan1<<<NBLK, 256, 0, stream>>>(counts, partial, blocksum);
    k_scan2<<<1, 256, 0, stream>>>(blocksum, NBLK);
    k_scan3<<<NBLK, 256, 0, stream>>>(partial, blocksum, offsets, cursor);
    k_fill<<<(N_EDGES + 255) / 256, 256, 0, stream>>>(row, col, eattr, cursor, meta);
    k_bounds<<<1, 128, 0, stream>>>(batch, gstart);

    float* h_cur = h_a;
    float* h_nxt = h_b;
    for (int i = 0; i < N_LAYERS; i++) {
        k_xl<<<(N_NODES + 31) / 32, 256, 0, stream>>>(h_cur, lw + i * HIDDEN * HIDDEN,
                                                      lb + i * HIDDEN, xl);
        k_agg<<<(N_NODES + 3) / 4, 256, 0, stream>>>(xl, meta, offsets,
                                                     table + (size_t)i * TAB * HIDDEN,
                                                     h_cur, ln_g + i * HIDDEN,
                                                     ln_b + i * HIDDEN, h_nxt);
        float* tmp = h_cur; h_cur = h_nxt; h_nxt = tmp;
    }
    k_pool2<<<N_GRAPHS, 256, 0, stream>>>(h_cur, gstart, out);
}

// Round 3
// 726.568 us; speedup vs baseline: 1.4988x; 1.2237x over previous
//
#include <hip/hip_runtime.h>
#include <hip/hip_bf16.h>

#define N_NODES 50000
#define N_EDGES 640000
#define HIDDEN 128
#define N_LAYERS 4
#define NUM_RBF 50
#define CUTOFF 4.0f
#define N_GRAPHS 64
#define TAB 2048
#define TG 8            // grid points per k_table block
#define PSPLIT 16       // pool blocks per graph

typedef unsigned int uint;
typedef unsigned short ushort;

__device__ inline ushort f2bf(float f) {   // RNE float->bf16 (finite inputs)
    uint u = __float_as_uint(f);
    uint r = (u + 0x7fffu + ((u >> 16) & 1u)) >> 16;
    return (ushort)r;
}

// ---------------------------------------------------------------------------
// Filter table in bf16: one block (128 threads) computes TG grid points for
// one layer, reusing each w1/w2 element across TG accumulators (L2 traffic /TG).
__global__ __launch_bounds__(128) void k_table(const float* __restrict__ fw1,
                                               const float* __restrict__ fb1,
                                               const float* __restrict__ fw2,
                                               const float* __restrict__ fb2,
                                               ushort* __restrict__ table) {
    int bid = blockIdx.x;
    int layer = bid / (TAB / TG);
    int g0 = (bid % (TAB / TG)) * TG;
    int j = threadIdx.x;
    __shared__ float rbf[TG][NUM_RBF];
    __shared__ float hid[TG][HIDDEN];
    for (int idx = j; idx < TG * NUM_RBF; idx += 128) {
        int gg = idx / NUM_RBF, r = idx % NUM_RBF;
        float d = (CUTOFF * (g0 + gg)) / (float)(TAB - 1);
        float offset = (CUTOFF * r) / (float)(NUM_RBF - 1);
        float delta = CUTOFF / (float)(NUM_RBF - 1);
        float coeff = -0.5f / (delta * delta);
        float t = d - offset;
        rbf[gg][r] = expf(coeff * t * t);
    }
    __syncthreads();
    const float* w1 = fw1 + layer * NUM_RBF * HIDDEN;
    float b1 = fb1[layer * HIDDEN + j];
    float acc[TG];
    #pragma unroll
    for (int gg = 0; gg < TG; gg++) acc[gg] = b1;
    for (int r = 0; r < NUM_RBF; r++) {
        float w = w1[r * HIDDEN + j];
        #pragma unroll
        for (int gg = 0; gg < TG; gg++) acc[gg] = fmaf(rbf[gg][r], w, acc[gg]);
    }
    #pragma unroll
    for (int gg = 0; gg < TG; gg++) hid[gg][j] = fmaxf(acc[gg], 0.0f);
    __syncthreads();
    const float* w2 = fw2 + layer * HIDDEN * HIDDEN;
    float b2 = fb2[layer * HIDDEN + j];
    float acc2[TG];
    #pragma unroll
    for (int gg = 0; gg < TG; gg++) acc2[gg] = b2;
    for (int k = 0; k < HIDDEN; k += 4) {
        float w0 = w2[(k + 0) * HIDDEN + j];
        float w1v = w2[(k + 1) * HIDDEN + j];
        float w2v = w2[(k + 2) * HIDDEN + j];
        float w3 = w2[(k + 3) * HIDDEN + j];
        #pragma unroll
        for (int gg = 0; gg < TG; gg++) {
            acc2[gg] = fmaf(hid[gg][k + 0], w0, acc2[gg]);
            acc2[gg] = fmaf(hid[gg][k + 1], w1v, acc2[gg]);
            acc2[gg] = fmaf(hid[gg][k + 2], w2v, acc2[gg]);
            acc2[gg] = fmaf(hid[gg][k + 3], w3, acc2[gg]);
        }
    }
    #pragma unroll
    for (int gg = 0; gg < TG; gg++)
        table[((size_t)layer * TAB + g0 + gg) * HIDDEN + j] = f2bf(acc2[gg]);
}

// ---------------------------------------------------------------------------
// Embedding gather: h[n][:] = emb[x[n]][:]
__global__ void k_embed(const int* __restrict__ x, const float* __restrict__ emb,
                        float* __restrict__ h) {
    int idx = blockIdx.x * 256 + threadIdx.x;   // over N_NODES*32 float4s
    if (idx >= N_NODES * 32) return;
    int n = idx >> 5, q = idx & 31;
    ((float4*)h)[idx] = ((const float4*)emb)[x[n] * 32 + q];
}

// ---------------------------------------------------------------------------
// CSR build (by destination = row). row is ~uniform-random -> low contention.
__global__ void k_count(const int* __restrict__ row, int* __restrict__ counts) {
    int e = blockIdx.x * 256 + threadIdx.x;
    if (e < N_EDGES) atomicAdd(&counts[row[e]], 1);
}

__global__ void k_scan1(const int* __restrict__ counts, int* __restrict__ partial,
                        int* __restrict__ blocksum) {
    int i = blockIdx.x * 256 + threadIdx.x;
    int v = (i < N_NODES) ? counts[i] : 0;
    int lane = threadIdx.x & 63;
    int wid = threadIdx.x >> 6;
    int s = v;
    #pragma unroll
    for (int off = 1; off < 64; off <<= 1) {
        int t = __shfl_up(s, off, 64);
        if (lane >= off) s += t;
    }
    __shared__ int wsum[4];
    if (lane == 63) wsum[wid] = s;
    __syncthreads();
    int woff = 0;
    for (int w = 0; w < wid; w++) woff += wsum[w];
    int incl = s + woff;
    if (i < N_NODES) partial[i] = incl - v;           // exclusive within block
    if (threadIdx.x == 255) blocksum[blockIdx.x] = incl;
}

__global__ void k_scan2(int* __restrict__ blocksum, int nblk) {
    int tid = threadIdx.x;
    int v = (tid < nblk) ? blocksum[tid] : 0;
    int lane = tid & 63, wid = tid >> 6;
    int s = v;
    #pragma unroll
    for (int off = 1; off < 64; off <<= 1) {
        int t = __shfl_up(s, off, 64);
        if (lane >= off) s += t;
    }
    __shared__ int wsum[4];
    if (lane == 63) wsum[wid] = s;
    __syncthreads();
    int woff = 0;
    for (int w = 0; w < wid; w++) woff += wsum[w];
    int incl = s + woff;
    if (tid < nblk) blocksum[tid] = incl - v;         // exclusive
}

__global__ void k_scan3(const int* __restrict__ partial, const int* __restrict__ blocksum,
                        int* __restrict__ offsets, int* __restrict__ cursor) {
    int i = blockIdx.x * 256 + threadIdx.x;
    if (i < N_NODES) {
        int o = partial[i] + blocksum[blockIdx.x];
        offsets[i] = o;
        cursor[i] = o;
    }
    if (i == 0) offsets[N_NODES] = N_EDGES;
}

// Pack per-edge (col, table coordinate t) into CSR slots.
__global__ void k_fill(const int* __restrict__ row, const int* __restrict__ col,
                       const float* __restrict__ eattr, int* __restrict__ cursor,
                       int2* __restrict__ meta) {
    int e = blockIdx.x * 256 + threadIdx.x;
    if (e >= N_EDGES) return;
    int r = row[e];
    int pos = atomicAdd(&cursor[r], 1);
    float t = eattr[e] * ((float)(TAB - 1) / CUTOFF);
    t = fminf(fmaxf(t, 0.0f), (float)(TAB - 2) + 0.9999f);
    int2 m;
    m.x = col[e];
    m.y = __float_as_int(t);
    meta[pos] = m;
}

// ---------------------------------------------------------------------------
// xl = h @ lw + lb  (fp32 register-tiled GEMM), output stored as bf16.
__global__ __launch_bounds__(256) void k_xl(const float* __restrict__ h,
                                            const float* __restrict__ lw,
                                            const float* __restrict__ lb,
                                            ushort* __restrict__ xlb) {
    int jt = threadIdx.x & 31;       // output group: j = jt*4 .. jt*4+3
    int mt = threadIdx.x >> 5;       // 0..7
    int n0 = blockIdx.x * 32 + mt * 4;
    const float4* lw4 = (const float4*)lw;
    const float4* h4 = (const float4*)h;
    float4 bias = ((const float4*)lb)[jt];
    float4 acc[4];
    #pragma unroll
    for (int r = 0; r < 4; r++) acc[r] = bias;
    for (int k4 = 0; k4 < 32; k4++) {
        float4 w0 = lw4[(4 * k4 + 0) * 32 + jt];
        float4 w1 = lw4[(4 * k4 + 1) * 32 + jt];
        float4 w2 = lw4[(4 * k4 + 2) * 32 + jt];
        float4 w3 = lw4[(4 * k4 + 3) * 32 + jt];
        #pragma unroll
        for (int r = 0; r < 4; r++) {
            int n = n0 + r;
            int nc = n < N_NODES ? n : N_NODES - 1;
            float4 hv = h4[nc * 32 + k4];
            acc[r].x = fmaf(hv.x, w0.x, fmaf(hv.y, w1.x, fmaf(hv.z, w2.x, fmaf(hv.w, w3.x, acc[r].x))));
            acc[r].y = fmaf(hv.x, w0.y, fmaf(hv.y, w1.y, fmaf(hv.z, w2.y, fmaf(hv.w, w3.y, acc[r].y))));
            acc[r].z = fmaf(hv.x, w0.z, fmaf(hv.y, w1.z, fmaf(hv.z, w2.z, fmaf(hv.w, w3.z, acc[r].z))));
            acc[r].w = fmaf(hv.x, w0.w, fmaf(hv.y, w1.w, fmaf(hv.z, w2.w, fmaf(hv.w, w3.w, acc[r].w))));
        }
    }
    #pragma unroll
    for (int r = 0; r < 4; r++) {
        int n = n0 + r;
        if (n < N_NODES) {
            ushort4 st;
            st.x = f2bf(acc[r].x);
            st.y = f2bf(acc[r].y);
            st.z = f2bf(acc[r].z);
            st.w = f2bf(acc[r].w);
            ((ushort4*)xlb)[n * 32 + jt] = st;
        }
    }
}

// ---------------------------------------------------------------------------
// Aggregation + residual + LayerNorm, fused. One wave (64 lanes x 2 feats)
// per node; table and xl gathered as bf16 pairs (half the R1 traffic).
__global__ __launch_bounds__(256) void k_agg(const ushort* __restrict__ xlb,
                                             const int2* __restrict__ meta,
                                             const int* __restrict__ offsets,
                                             const ushort* __restrict__ tab,
                                             const float* __restrict__ h_in,
                                             const float* __restrict__ g,
                                             const float* __restrict__ b,
                                             float* __restrict__ h_out) {
    int wid = threadIdx.x >> 6;
    int lane = threadIdx.x & 63;
    int n = blockIdx.x * 4 + wid;
    if (n >= N_NODES) return;
    const uint* xl2 = (const uint*)xlb;    // bf16 pair per uint
    const uint* tab2 = (const uint*)tab;
    float accx = 0.f, accy = 0.f;
    int p0 = offsets[n], p1 = offsets[n + 1];
    for (int p = p0; p < p1; p++) {
        int2 m = meta[p];
        float t = __int_as_float(m.y);
        int i0 = (int)t;
        float fr = t - (float)i0;
        uint w0p = tab2[i0 * 64 + lane];
        uint w1p = tab2[(i0 + 1) * 64 + lane];
        uint xvp = xl2[m.x * 64 + lane];
        float w0x = __uint_as_float(w0p << 16);
        float w0y = __uint_as_float(w0p & 0xffff0000u);
        float w1x = __uint_as_float(w1p << 16);
        float w1y = __uint_as_float(w1p & 0xffff0000u);
        float xx  = __uint_as_float(xvp << 16);
        float xy  = __uint_as_float(xvp & 0xffff0000u);
        float wx = fmaf(fr, w1x - w0x, w0x);
        float wy = fmaf(fr, w1y - w0y, w0y);
        accx = fmaf(wx, xx, accx);
        accy = fmaf(wy, xy, accy);
    }
    float2 hv = ((const float2*)h_in)[n * 64 + lane];
    float vx = hv.x + accx, vy = hv.y + accy;
    float s = vx + vy;
    #pragma unroll
    for (int off = 32; off; off >>= 1) s += __shfl_xor(s, off, 64);
    float mu = s * (1.0f / 128.0f);
    float dx = vx - mu, dy = vy - mu;
    float s2 = dx * dx + dy * dy;
    #pragma unroll
    for (int off = 32; off; off >>= 1) s2 += __shfl_xor(s2, off, 64);
    float rstd = rsqrtf(s2 * (1.0f / 128.0f) + 1e-5f);
    float2 gv = ((const float2*)g)[lane];
    float2 bv = ((const float2*)b)[lane];
    float2 o;
    o.x = fmaf(dx * rstd, gv.x, bv.x);
    o.y = fmaf(dy * rstd, gv.y, bv.y);
    ((float2*)h_out)[n * 64 + lane] = o;
}

// ---------------------------------------------------------------------------
// Graph boundaries via binary search (batch is sorted).
__global__ void k_bounds(const int* __restrict__ batch, int* __restrict__ gstart) {
    int g = threadIdx.x;
    if (g > N_GRAPHS) return;
    int lo = 0, hi = N_NODES;
    while (lo < hi) {
        int mid = (lo + hi) >> 1;
        if (batch[mid] < g) lo = mid + 1; else hi = mid;
    }
    gstart[g] = lo;
}

// Mean pool, stage 1: PSPLIT blocks per graph write partial sums.
__global__ __launch_bounds__(256) void k_pool_part(const float* __restrict__ h,
                                                   const int* __restrict__ gstart,
                                                   float* __restrict__ partial) {
    int g = blockIdx.x / PSPLIT;
    int t = blockIdx.x % PSPLIT;
    int j = threadIdx.x & 127;
    int half = threadIdx.x >> 7;
    int s = gstart[g], e = gstart[g + 1];
    float acc = 0.f;
    for (int n = s + t * 2 + half; n < e; n += PSPLIT * 2) acc += h[n * HIDDEN + j];
    __shared__ float red[256];
    red[threadIdx.x] = acc;
    __syncthreads();
    if (half == 0) partial[(g * PSPLIT + t) * HIDDEN + j] = red[j] + red[j + 128];
}

// Mean pool, stage 2: reduce PSPLIT partials, divide by count.
__global__ void k_pool_fin(const float* __restrict__ partial,
                           const int* __restrict__ gstart,
                           float* __restrict__ out) {
    int idx = blockIdx.x * 128 + threadIdx.x;   // N_GRAPHS*HIDDEN total
    int g = idx >> 7, j = idx & 127;
    float tot = 0.f;
    #pragma unroll
    for (int t = 0; t < PSPLIT; t++) tot += partial[(g * PSPLIT + t) * HIDDEN + j];
    float c = (float)(gstart[g + 1] - gstart[g]);
    out[idx] = tot / fmaxf(c, 1.0f);
}

// ---------------------------------------------------------------------------
extern "C" void kernel_launch(void* const* d_in, const int* in_sizes, int n_in,
                              void* d_out, int out_size, void* d_ws, size_t ws_size,
                              hipStream_t stream) {
    const int* x = (const int*)d_in[0];
    const int* edge_index = (const int*)d_in[1];
    const int* row = edge_index;               // edge_index[0]
    const int* col = edge_index + N_EDGES;     // edge_index[1]
    const float* eattr = (const float*)d_in[2];
    const int* batch = (const int*)d_in[3];
    const float* emb = (const float*)d_in[4];
    const float* fw1 = (const float*)d_in[5];
    const float* fb1 = (const float*)d_in[6];
    const float* fw2 = (const float*)d_in[7];
    const float* fb2 = (const float*)d_in[8];
    const float* lw = (const float*)d_in[9];
    const float* lb = (const float*)d_in[10];
    const float* ln_g = (const float*)d_in[11];
    const float* ln_b = (const float*)d_in[12];
    float* out = (float*)d_out;

    char* ws = (char*)d_ws;
    size_t off = 0;
    auto alloc = [&](size_t bytes) -> void* {
        void* p = ws + off;
        off = (off + bytes + 255) & ~(size_t)255;
        return p;
    };
    ushort* table  = (ushort*)alloc((size_t)N_LAYERS * TAB * HIDDEN * 2);
    float* h_a     = (float*)alloc((size_t)N_NODES * HIDDEN * 4);
    float* h_b     = (float*)alloc((size_t)N_NODES * HIDDEN * 4);
    ushort* xlb    = (ushort*)alloc((size_t)N_NODES * HIDDEN * 2);
    int* counts    = (int*)alloc((size_t)(N_NODES + 1) * 4);
    int* offsets   = (int*)alloc((size_t)(N_NODES + 1) * 4);
    int* cursor    = (int*)alloc((size_t)N_NODES * 4);
    int* partial   = (int*)alloc((size_t)N_NODES * 4);
    int* blocksum  = (int*)alloc(256 * 4);
    int2* meta     = (int2*)alloc((size_t)N_EDGES * 8);
    int* gstart    = (int*)alloc((size_t)(N_GRAPHS + 1) * 4);
    float* ppart   = (float*)alloc((size_t)N_GRAPHS * PSPLIT * HIDDEN * 4);

    hipMemsetAsync(counts, 0, (size_t)(N_NODES + 1) * 4, stream);

    k_table<<<N_LAYERS * (TAB / TG), 128, 0, stream>>>(fw1, fb1, fw2, fb2, table);
    k_embed<<<(N_NODES * 32 + 255) / 256, 256, 0, stream>>>(x, emb, h_a);
    k_count<<<(N_EDGES + 255) / 256, 256, 0, stream>>>(row, counts);
    const int NBLK = (N_NODES + 255) / 256;   // 196
    k_scan1<<<NBLK, 256, 0, stream>>>(counts, partial, blocksum);
    k_scan2<<<1, 256, 0, stream>>>(blocksum, NBLK);
    k_scan3<<<NBLK, 256, 0, stream>>>(partial, blocksum, offsets, cursor);
    k_fill<<<(N_EDGES + 255) / 256, 256, 0, stream>>>(row, col, eattr, cursor, meta);
    k_bounds<<<1, 128, 0, stream>>>(batch, gstart);

    float* h_cur = h_a;
    float* h_nxt = h_b;
    for (int i = 0; i < N_LAYERS; i++) {
        k_xl<<<(N_NODES + 31) / 32, 256, 0, stream>>>(h_cur, lw + i * HIDDEN * HIDDEN,
                                                      lb + i * HIDDEN, xlb);
        k_agg<<<(N_NODES + 3) / 4, 256, 0, stream>>>(xlb, meta, offsets,
                                                     table + (size_t)i * TAB * HIDDEN,
                                                     h_cur, ln_g + i * HIDDEN,
                                                     ln_b + i * HIDDEN, h_nxt);
        float* tmp = h_cur; h_cur = h_nxt; h_nxt = tmp;
    }
    k_pool_part<<<N_GRAPHS * PSPLIT, 256, 0, stream>>>(h_cur, gstart, ppart);
    k_pool_fin<<<(N_GRAPHS * HIDDEN + 127) / 128, 128, 0, stream>>>(ppart, gstart, out);
}

// Round 4
// 609.387 us; speedup vs baseline: 1.7870x; 1.1923x over previous
//
#include <hip/hip_runtime.h>
#include <hip/hip_bf16.h>

#define N_NODES 50000
#define N_EDGES 640000
#define HIDDEN 128
#define N_LAYERS 4
#define NUM_RBF 50
#define CUTOFF 4.0f
#define N_GRAPHS 64
#define TAB 2048
#define TG 8            // grid points per k_table block
#define PSPLIT 16       // pool blocks per graph

typedef unsigned int uint;
typedef unsigned short ushort;

__device__ inline ushort f2bf(float f) {   // RNE float->bf16 (finite inputs)
    uint u = __float_as_uint(f);
    uint r = (u + 0x7fffu + ((u >> 16) & 1u)) >> 16;
    return (ushort)r;
}
__device__ inline uint packbf(float lo, float hi) {
    return (uint)f2bf(lo) | ((uint)f2bf(hi) << 16);
}
__device__ inline float bflo(uint u) { return __uint_as_float(u << 16); }
__device__ inline float bfhi(uint u) { return __uint_as_float(u & 0xffff0000u); }

// ---------------------------------------------------------------------------
// Combined lerp table: for each (layer, grid point g) a 512B row of 64 uint2:
//   .x = bf16 pair (w[g][2jp], w[g][2jp+1])
//   .y = bf16 pair (w[g+1]-w[g]) deltas
// One block computes TG+1 grid points (one overlap) in fp32 and emits TG rows.
__global__ __launch_bounds__(128) void k_table(const float* __restrict__ fw1,
                                               const float* __restrict__ fb1,
                                               const float* __restrict__ fw2,
                                               const float* __restrict__ fb2,
                                               uint2* __restrict__ ctab) {
    int bid = blockIdx.x;
    int layer = bid / (TAB / TG);
    int g0 = (bid % (TAB / TG)) * TG;
    int j = threadIdx.x;
    const int NP = TG + 1;
    __shared__ float rbf[NP][NUM_RBF];
    __shared__ float hid[NP][HIDDEN];
    __shared__ float wout[NP][HIDDEN];
    for (int idx = j; idx < NP * NUM_RBF; idx += 128) {
        int gg = idx / NUM_RBF, r = idx % NUM_RBF;
        float d = (CUTOFF * (g0 + gg)) / (float)(TAB - 1);
        float offset = (CUTOFF * r) / (float)(NUM_RBF - 1);
        float delta = CUTOFF / (float)(NUM_RBF - 1);
        float coeff = -0.5f / (delta * delta);
        float t = d - offset;
        rbf[gg][r] = expf(coeff * t * t);
    }
    __syncthreads();
    const float* w1 = fw1 + layer * NUM_RBF * HIDDEN;
    float b1 = fb1[layer * HIDDEN + j];
    float acc[NP];
    #pragma unroll
    for (int gg = 0; gg < NP; gg++) acc[gg] = b1;
    for (int r = 0; r < NUM_RBF; r++) {
        float w = w1[r * HIDDEN + j];
        #pragma unroll
        for (int gg = 0; gg < NP; gg++) acc[gg] = fmaf(rbf[gg][r], w, acc[gg]);
    }
    #pragma unroll
    for (int gg = 0; gg < NP; gg++) hid[gg][j] = fmaxf(acc[gg], 0.0f);
    __syncthreads();
    const float* w2 = fw2 + layer * HIDDEN * HIDDEN;
    float b2 = fb2[layer * HIDDEN + j];
    float acc2[NP];
    #pragma unroll
    for (int gg = 0; gg < NP; gg++) acc2[gg] = b2;
    for (int k = 0; k < HIDDEN; k += 4) {
        float w0 = w2[(k + 0) * HIDDEN + j];
        float w1v = w2[(k + 1) * HIDDEN + j];
        float w2v = w2[(k + 2) * HIDDEN + j];
        float w3 = w2[(k + 3) * HIDDEN + j];
        #pragma unroll
        for (int gg = 0; gg < NP; gg++) {
            acc2[gg] = fmaf(hid[gg][k + 0], w0, acc2[gg]);
            acc2[gg] = fmaf(hid[gg][k + 1], w1v, acc2[gg]);
            acc2[gg] = fmaf(hid[gg][k + 2], w2v, acc2[gg]);
            acc2[gg] = fmaf(hid[gg][k + 3], w3, acc2[gg]);
        }
    }
    #pragma unroll
    for (int gg = 0; gg < NP; gg++) wout[gg][j] = acc2[gg];
    __syncthreads();
    for (int idx = j; idx < TG * 64; idx += 128) {
        int gg = idx >> 6, jp = idx & 63;
        float wl = wout[gg][2 * jp], wh = wout[gg][2 * jp + 1];
        float dl = wout[gg + 1][2 * jp] - wl, dh = wout[gg + 1][2 * jp + 1] - wh;
        uint2 e;
        e.x = packbf(wl, wh);
        e.y = packbf(dl, dh);
        ctab[((size_t)layer * TAB + g0 + gg) * 64 + jp] = e;
    }
}

// ---------------------------------------------------------------------------
// Embedding gather: h[n][:] = emb[x[n]][:]
__global__ void k_embed(const int* __restrict__ x, const float* __restrict__ emb,
                        float* __restrict__ h) {
    int idx = blockIdx.x * 256 + threadIdx.x;   // over N_NODES*32 float4s
    if (idx >= N_NODES * 32) return;
    int n = idx >> 5, q = idx & 31;
    ((float4*)h)[idx] = ((const float4*)emb)[x[n] * 32 + q];
}

// ---------------------------------------------------------------------------
// CSR build (by destination = row). row is ~uniform-random -> low contention.
__global__ void k_count(const int* __restrict__ row, int* __restrict__ counts) {
    int e = blockIdx.x * 256 + threadIdx.x;
    if (e < N_EDGES) atomicAdd(&counts[row[e]], 1);
}

__global__ void k_scan1(const int* __restrict__ counts, int* __restrict__ partial,
                        int* __restrict__ blocksum) {
    int i = blockIdx.x * 256 + threadIdx.x;
    int v = (i < N_NODES) ? counts[i] : 0;
    int lane = threadIdx.x & 63;
    int wid = threadIdx.x >> 6;
    int s = v;
    #pragma unroll
    for (int off = 1; off < 64; off <<= 1) {
        int t = __shfl_up(s, off, 64);
        if (lane >= off) s += t;
    }
    __shared__ int wsum[4];
    if (lane == 63) wsum[wid] = s;
    __syncthreads();
    int woff = 0;
    for (int w = 0; w < wid; w++) woff += wsum[w];
    int incl = s + woff;
    if (i < N_NODES) partial[i] = incl - v;           // exclusive within block
    if (threadIdx.x == 255) blocksum[blockIdx.x] = incl;
}

__global__ void k_scan2(int* __restrict__ blocksum, int nblk) {
    int tid = threadIdx.x;
    int v = (tid < nblk) ? blocksum[tid] : 0;
    int lane = tid & 63, wid = tid >> 6;
    int s = v;
    #pragma unroll
    for (int off = 1; off < 64; off <<= 1) {
        int t = __shfl_up(s, off, 64);
        if (lane >= off) s += t;
    }
    __shared__ int wsum[4];
    if (lane == 63) wsum[wid] = s;
    __syncthreads();
    int woff = 0;
    for (int w = 0; w < wid; w++) woff += wsum[w];
    int incl = s + woff;
    if (tid < nblk) blocksum[tid] = incl - v;         // exclusive
}

__global__ void k_scan3(const int* __restrict__ partial, const int* __restrict__ blocksum,
                        int* __restrict__ offsets, int* __restrict__ cursor) {
    int i = blockIdx.x * 256 + threadIdx.x;
    if (i < N_NODES) {
        int o = partial[i] + blocksum[blockIdx.x];
        offsets[i] = o;
        cursor[i] = o;
    }
    if (i == 0) offsets[N_NODES] = N_EDGES;
}

// Pack per-edge (col, table coordinate t) into CSR slots.
__global__ void k_fill(const int* __restrict__ row, const int* __restrict__ col,
                       const float* __restrict__ eattr, int* __restrict__ cursor,
                       int2* __restrict__ meta) {
    int e = blockIdx.x * 256 + threadIdx.x;
    if (e >= N_EDGES) return;
    int r = row[e];
    int pos = atomicAdd(&cursor[r], 1);
    float t = eattr[e] * ((float)(TAB - 1) / CUTOFF);
    t = fminf(fmaxf(t, 0.0f), (float)(TAB - 2) + 0.9999f);
    int2 m;
    m.x = col[e];
    m.y = __float_as_int(t);
    meta[pos] = m;
}

// ---------------------------------------------------------------------------
// xl = h @ lw + lb  (fp32 register-tiled GEMM), output stored as bf16.
__global__ __launch_bounds__(256) void k_xl(const float* __restrict__ h,
                                            const float* __restrict__ lw,
                                            const float* __restrict__ lb,
                                            ushort* __restrict__ xlb) {
    int jt = threadIdx.x & 31;       // output group: j = jt*4 .. jt*4+3
    int mt = threadIdx.x >> 5;       // 0..7
    int n0 = blockIdx.x * 32 + mt * 4;
    const float4* lw4 = (const float4*)lw;
    const float4* h4 = (const float4*)h;
    float4 bias = ((const float4*)lb)[jt];
    float4 acc[4];
    #pragma unroll
    for (int r = 0; r < 4; r++) acc[r] = bias;
    for (int k4 = 0; k4 < 32; k4++) {
        float4 w0 = lw4[(4 * k4 + 0) * 32 + jt];
        float4 w1 = lw4[(4 * k4 + 1) * 32 + jt];
        float4 w2 = lw4[(4 * k4 + 2) * 32 + jt];
        float4 w3 = lw4[(4 * k4 + 3) * 32 + jt];
        #pragma unroll
        for (int r = 0; r < 4; r++) {
            int n = n0 + r;
            int nc = n < N_NODES ? n : N_NODES - 1;
            float4 hv = h4[nc * 32 + k4];
            acc[r].x = fmaf(hv.x, w0.x, fmaf(hv.y, w1.x, fmaf(hv.z, w2.x, fmaf(hv.w, w3.x, acc[r].x))));
            acc[r].y = fmaf(hv.x, w0.y, fmaf(hv.y, w1.y, fmaf(hv.z, w2.y, fmaf(hv.w, w3.y, acc[r].y))));
            acc[r].z = fmaf(hv.x, w0.z, fmaf(hv.y, w1.z, fmaf(hv.z, w2.z, fmaf(hv.w, w3.z, acc[r].z))));
            acc[r].w = fmaf(hv.x, w0.w, fmaf(hv.y, w1.w, fmaf(hv.z, w2.w, fmaf(hv.w, w3.w, acc[r].w))));
        }
    }
    #pragma unroll
    for (int r = 0; r < 4; r++) {
        int n = n0 + r;
        if (n < N_NODES) {
            ushort4 st;
            st.x = f2bf(acc[r].x);
            st.y = f2bf(acc[r].y);
            st.z = f2bf(acc[r].z);
            st.w = f2bf(acc[r].w);
            ((ushort4*)xlb)[n * 32 + jt] = st;
        }
    }
}

// ---------------------------------------------------------------------------
// Aggregation + residual + LayerNorm, fused. One wave (64 lanes x 2 feats)
// per node. Edge loop unrolled x4: 4 independent meta loads then 8 independent
// gathers in flight (latency chain /4 vs serial). ctab gives w+dw in one load.
__global__ __launch_bounds__(256) void k_agg(const ushort* __restrict__ xlb,
                                             const int2* __restrict__ meta,
                                             const int* __restrict__ offsets,
                                             const uint2* __restrict__ ctab,
                                             const float* __restrict__ h_in,
                                             const float* __restrict__ g,
                                             const float* __restrict__ b,
                                             float* __restrict__ h_out) {
    int wid = threadIdx.x >> 6;
    int lane = threadIdx.x & 63;
    int n = blockIdx.x * 4 + wid;
    if (n >= N_NODES) return;
    const uint* xl2 = (const uint*)xlb;    // bf16 pair per uint
    float accx = 0.f, accy = 0.f;
    int p0 = offsets[n], p1 = offsets[n + 1];
    const int2* mp = meta + p0;
    int cnt = p1 - p0;
    int k4 = cnt & ~3;
    int p = 0;
    for (; p < k4; p += 4) {
        int2 m0 = mp[p + 0];
        int2 m1 = mp[p + 1];
        int2 m2 = mp[p + 2];
        int2 m3 = mp[p + 3];
        float t0 = __int_as_float(m0.y), t1 = __int_as_float(m1.y);
        float t2 = __int_as_float(m2.y), t3 = __int_as_float(m3.y);
        int i0 = (int)t0, i1 = (int)t1, i2 = (int)t2, i3 = (int)t3;
        uint2 c0 = ctab[i0 * 64 + lane];
        uint2 c1 = ctab[i1 * 64 + lane];
        uint2 c2 = ctab[i2 * 64 + lane];
        uint2 c3 = ctab[i3 * 64 + lane];
        uint x0 = xl2[m0.x * 64 + lane];
        uint x1 = xl2[m1.x * 64 + lane];
        uint x2 = xl2[m2.x * 64 + lane];
        uint x3 = xl2[m3.x * 64 + lane];
        float f0 = t0 - (float)i0, f1 = t1 - (float)i1;
        float f2 = t2 - (float)i2, f3 = t3 - (float)i3;
        accx = fmaf(fmaf(f0, bflo(c0.y), bflo(c0.x)), bflo(x0), accx);
        accy = fmaf(fmaf(f0, bfhi(c0.y), bfhi(c0.x)), bfhi(x0), accy);
        accx = fmaf(fmaf(f1, bflo(c1.y), bflo(c1.x)), bflo(x1), accx);
        accy = fmaf(fmaf(f1, bfhi(c1.y), bfhi(c1.x)), bfhi(x1), accy);
        accx = fmaf(fmaf(f2, bflo(c2.y), bflo(c2.x)), bflo(x2), accx);
        accy = fmaf(fmaf(f2, bfhi(c2.y), bfhi(c2.x)), bfhi(x2), accy);
        accx = fmaf(fmaf(f3, bflo(c3.y), bflo(c3.x)), bflo(x3), accx);
        accy = fmaf(fmaf(f3, bfhi(c3.y), bfhi(c3.x)), bfhi(x3), accy);
    }
    for (; p < cnt; p++) {
        int2 m = mp[p];
        float t = __int_as_float(m.y);
        int i0 = (int)t;
        float fr = t - (float)i0;
        uint2 ce = ctab[i0 * 64 + lane];
        uint xu = xl2[m.x * 64 + lane];
        accx = fmaf(fmaf(fr, bflo(ce.y), bflo(ce.x)), bflo(xu), accx);
        accy = fmaf(fmaf(fr, bfhi(ce.y), bfhi(ce.x)), bfhi(xu), accy);
    }
    float2 hv = ((const float2*)h_in)[n * 64 + lane];
    float vx = hv.x + accx, vy = hv.y + accy;
    float s = vx + vy;
    #pragma unroll
    for (int off = 32; off; off >>= 1) s += __shfl_xor(s, off, 64);
    float mu = s * (1.0f / 128.0f);
    float dx = vx - mu, dy = vy - mu;
    float s2 = dx * dx + dy * dy;
    #pragma unroll
    for (int off = 32; off; off >>= 1) s2 += __shfl_xor(s2, off, 64);
    float rstd = rsqrtf(s2 * (1.0f / 128.0f) + 1e-5f);
    float2 gv = ((const float2*)g)[lane];
    float2 bv = ((const float2*)b)[lane];
    float2 o;
    o.x = fmaf(dx * rstd, gv.x, bv.x);
    o.y = fmaf(dy * rstd, gv.y, bv.y);
    ((float2*)h_out)[n * 64 + lane] = o;
}

// ---------------------------------------------------------------------------
// Graph boundaries via binary search (batch is sorted).
__global__ void k_bounds(const int* __restrict__ batch, int* __restrict__ gstart) {
    int g = threadIdx.x;
    if (g > N_GRAPHS) return;
    int lo = 0, hi = N_NODES;
    while (lo < hi) {
        int mid = (lo + hi) >> 1;
        if (batch[mid] < g) lo = mid + 1; else hi = mid;
    }
    gstart[g] = lo;
}

// Mean pool, stage 1: PSPLIT blocks per graph write partial sums.
__global__ __launch_bounds__(256) void k_pool_part(const float* __restrict__ h,
                                                   const int* __restrict__ gstart,
                                                   float* __restrict__ partial) {
    int g = blockIdx.x / PSPLIT;
    int t = blockIdx.x % PSPLIT;
    int j = threadIdx.x & 127;
    int half = threadIdx.x >> 7;
    int s = gstart[g], e = gstart[g + 1];
    float acc = 0.f;
    for (int n = s + t * 2 + half; n < e; n += PSPLIT * 2) acc += h[n * HIDDEN + j];
    __shared__ float red[256];
    red[threadIdx.x] = acc;
    __syncthreads();
    if (half == 0) partial[(g * PSPLIT + t) * HIDDEN + j] = red[j] + red[j + 128];
}

// Mean pool, stage 2: reduce PSPLIT partials, divide by count.
__global__ void k_pool_fin(const float* __restrict__ partial,
                           const int* __restrict__ gstart,
                           float* __restrict__ out) {
    int idx = blockIdx.x * 128 + threadIdx.x;   // N_GRAPHS*HIDDEN total
    int g = idx >> 7, j = idx & 127;
    float tot = 0.f;
    #pragma unroll
    for (int t = 0; t < PSPLIT; t++) tot += partial[(g * PSPLIT + t) * HIDDEN + j];
    float c = (float)(gstart[g + 1] - gstart[g]);
    out[idx] = tot / fmaxf(c, 1.0f);
}

// ---------------------------------------------------------------------------
extern "C" void kernel_launch(void* const* d_in, const int* in_sizes, int n_in,
                              void* d_out, int out_size, void* d_ws, size_t ws_size,
                              hipStream_t stream) {
    const int* x = (const int*)d_in[0];
    const int* edge_index = (const int*)d_in[1];
    const int* row = edge_index;               // edge_index[0]
    const int* col = edge_index + N_EDGES;     // edge_index[1]
    const float* eattr = (const float*)d_in[2];
    const int* batch = (const int*)d_in[3];
    const float* emb = (const float*)d_in[4];
    const float* fw1 = (const float*)d_in[5];
    const float* fb1 = (const float*)d_in[6];
    const float* fw2 = (const float*)d_in[7];
    const float* fb2 = (const float*)d_in[8];
    const float* lw = (const float*)d_in[9];
    const float* lb = (const float*)d_in[10];
    const float* ln_g = (const float*)d_in[11];
    const float* ln_b = (const float*)d_in[12];
    float* out = (float*)d_out;

    char* ws = (char*)d_ws;
    size_t off = 0;
    auto alloc = [&](size_t bytes) -> void* {
        void* p = ws + off;
        off = (off + bytes + 255) & ~(size_t)255;
        return p;
    };
    uint2* ctab    = (uint2*)alloc((size_t)N_LAYERS * TAB * 64 * 8);
    float* h_a     = (float*)alloc((size_t)N_NODES * HIDDEN * 4);
    float* h_b     = (float*)alloc((size_t)N_NODES * HIDDEN * 4);
    ushort* xlb    = (ushort*)alloc((size_t)N_NODES * HIDDEN * 2);
    int* counts    = (int*)alloc((size_t)(N_NODES + 1) * 4);
    int* offsets   = (int*)alloc((size_t)(N_NODES + 1) * 4);
    int* cursor    = (int*)alloc((size_t)N_NODES * 4);
    int* partial   = (int*)alloc((size_t)N_NODES * 4);
    int* blocksum  = (int*)alloc(256 * 4);
    int2* meta     = (int2*)alloc((size_t)N_EDGES * 8);
    int* gstart    = (int*)alloc((size_t)(N_GRAPHS + 1) * 4);
    float* ppart   = (float*)alloc((size_t)N_GRAPHS * PSPLIT * HIDDEN * 4);

    hipMemsetAsync(counts, 0, (size_t)(N_NODES + 1) * 4, stream);

    k_table<<<N_LAYERS * (TAB / TG), 128, 0, stream>>>(fw1, fb1, fw2, fb2, ctab);
    k_embed<<<(N_NODES * 32 + 255) / 256, 256, 0, stream>>>(x, emb, h_a);
    k_count<<<(N_EDGES + 255) / 256, 256, 0, stream>>>(row, counts);
    const int NBLK = (N_NODES + 255) / 256;   // 196
    k_scan1<<<NBLK, 256, 0, stream>>>(counts, partial, blocksum);
    k_scan2<<<1, 256, 0, stream>>>(blocksum, NBLK);
    k_scan3<<<NBLK, 256, 0, stream>>>(partial, blocksum, offsets, cursor);
    k_fill<<<(N_EDGES + 255) / 256, 256, 0, stream>>>(row, col, eattr, cursor, meta);
    k_bounds<<<1, 128, 0, stream>>>(batch, gstart);

    float* h_cur = h_a;
    float* h_nxt = h_b;
    for (int i = 0; i < N_LAYERS; i++) {
        k_xl<<<(N_NODES + 31) / 32, 256, 0, stream>>>(h_cur, lw + i * HIDDEN * HIDDEN,
                                                      lb + i * HIDDEN, xlb);
        k_agg<<<(N_NODES + 3) / 4, 256, 0, stream>>>(xlb, meta, offsets,
                                                     ctab + (size_t)i * TAB * 64,
                                                     h_cur, ln_g + i * HIDDEN,
                                                     ln_b + i * HIDDEN, h_nxt);
        float* tmp = h_cur; h_cur = h_nxt; h_nxt = tmp;
    }
    k_pool_part<<<N_GRAPHS * PSPLIT, 256, 0, stream>>>(h_cur, gstart, ppart);
    k_pool_fin<<<(N_GRAPHS * HIDDEN + 127) / 128, 128, 0, stream>>>(ppart, gstart, out);
}

// Round 5
// 437.401 us; speedup vs baseline: 2.4897x; 1.3932x over previous
//
#include <hip/hip_runtime.h>
#include <hip/hip_bf16.h>

#define N_NODES 50000
#define N_EDGES 640000
#define HIDDEN 128
#define N_LAYERS 4
#define NUM_RBF 50
#define CUTOFF 4.0f
#define N_GRAPHS 64
#define TAB 2048
#define TG 8            // grid points per k_table block
#define PSPLIT 16       // pool blocks per graph

typedef unsigned int uint;
typedef unsigned short ushort;
typedef __attribute__((ext_vector_type(8))) short bf16x8;   // MFMA A/B frag (4 VGPRs)
typedef __attribute__((ext_vector_type(4))) float f32x4;    // MFMA C/D frag

__device__ inline ushort f2bf(float f) {   // RNE float->bf16 (finite inputs)
    uint u = __float_as_uint(f);
    uint r = (u + 0x7fffu + ((u >> 16) & 1u)) >> 16;
    return (ushort)r;
}
__device__ inline uint packbf(float lo, float hi) {
    return (uint)f2bf(lo) | ((uint)f2bf(hi) << 16);
}
__device__ inline float bflo(uint u) { return __uint_as_float(u << 16); }
__device__ inline float bfhi(uint u) { return __uint_as_float(u & 0xffff0000u); }

// ---------------------------------------------------------------------------
// Combined lerp table: for each (layer, grid point g) a 512B row of 64 uint2:
//   .x = bf16 pair (w[g][2jp], w[g][2jp+1]) ; .y = bf16 pair of deltas.
__global__ __launch_bounds__(128) void k_table(const float* __restrict__ fw1,
                                               const float* __restrict__ fb1,
                                               const float* __restrict__ fw2,
                                               const float* __restrict__ fb2,
                                               uint2* __restrict__ ctab) {
    int bid = blockIdx.x;
    int layer = bid / (TAB / TG);
    int g0 = (bid % (TAB / TG)) * TG;
    int j = threadIdx.x;
    const int NP = TG + 1;
    __shared__ float rbf[NP][NUM_RBF];
    __shared__ float hid[NP][HIDDEN];
    __shared__ float wout[NP][HIDDEN];
    for (int idx = j; idx < NP * NUM_RBF; idx += 128) {
        int gg = idx / NUM_RBF, r = idx % NUM_RBF;
        float d = (CUTOFF * (g0 + gg)) / (float)(TAB - 1);
        float offset = (CUTOFF * r) / (float)(NUM_RBF - 1);
        float delta = CUTOFF / (float)(NUM_RBF - 1);
        float coeff = -0.5f / (delta * delta);
        float t = d - offset;
        rbf[gg][r] = expf(coeff * t * t);
    }
    __syncthreads();
    const float* w1 = fw1 + layer * NUM_RBF * HIDDEN;
    float b1 = fb1[layer * HIDDEN + j];
    float acc[NP];
    #pragma unroll
    for (int gg = 0; gg < NP; gg++) acc[gg] = b1;
    for (int r = 0; r < NUM_RBF; r++) {
        float w = w1[r * HIDDEN + j];
        #pragma unroll
        for (int gg = 0; gg < NP; gg++) acc[gg] = fmaf(rbf[gg][r], w, acc[gg]);
    }
    #pragma unroll
    for (int gg = 0; gg < NP; gg++) hid[gg][j] = fmaxf(acc[gg], 0.0f);
    __syncthreads();
    const float* w2 = fw2 + layer * HIDDEN * HIDDEN;
    float b2 = fb2[layer * HIDDEN + j];
    float acc2[NP];
    #pragma unroll
    for (int gg = 0; gg < NP; gg++) acc2[gg] = b2;
    for (int k = 0; k < HIDDEN; k += 4) {
        float w0 = w2[(k + 0) * HIDDEN + j];
        float w1v = w2[(k + 1) * HIDDEN + j];
        float w2v = w2[(k + 2) * HIDDEN + j];
        float w3 = w2[(k + 3) * HIDDEN + j];
        #pragma unroll
        for (int gg = 0; gg < NP; gg++) {
            acc2[gg] = fmaf(hid[gg][k + 0], w0, acc2[gg]);
            acc2[gg] = fmaf(hid[gg][k + 1], w1v, acc2[gg]);
            acc2[gg] = fmaf(hid[gg][k + 2], w2v, acc2[gg]);
            acc2[gg] = fmaf(hid[gg][k + 3], w3, acc2[gg]);
        }
    }
    #pragma unroll
    for (int gg = 0; gg < NP; gg++) wout[gg][j] = acc2[gg];
    __syncthreads();
    for (int idx = j; idx < TG * 64; idx += 128) {
        int gg = idx >> 6, jp = idx & 63;
        float wl = wout[gg][2 * jp], wh = wout[gg][2 * jp + 1];
        float dl = wout[gg + 1][2 * jp] - wl, dh = wout[gg + 1][2 * jp + 1] - wh;
        uint2 e;
        e.x = packbf(wl, wh);
        e.y = packbf(dl, dh);
        ctab[((size_t)layer * TAB + g0 + gg) * 64 + jp] = e;
    }
}

// ---------------------------------------------------------------------------
// Embedding gather: h[n][:] = emb[x[n]][:] (fp32 + bf16 copy for MFMA k_xl).
__global__ void k_embed(const int* __restrict__ x, const float* __restrict__ emb,
                        float* __restrict__ h, ushort* __restrict__ hbf) {
    int idx = blockIdx.x * 256 + threadIdx.x;   // over N_NODES*32 float4s
    if (idx >= N_NODES * 32) return;
    int n = idx >> 5, q = idx & 31;
    float4 v = ((const float4*)emb)[x[n] * 32 + q];
    ((float4*)h)[idx] = v;
    uint2 p;
    p.x = packbf(v.x, v.y);
    p.y = packbf(v.z, v.w);
    ((uint2*)hbf)[idx] = p;
}

// ---------------------------------------------------------------------------
// Pack lw into B-fragment order for mfma_f32_16x16x32_bf16:
// pb[layer][nt][kc][lane] = 8 bf16, element j = lw[k=kc*32+(lane>>4)*8+j][n=nt*16+(lane&15)]
__global__ void k_packw(const float* __restrict__ lw, uint4* __restrict__ pb) {
    int idx = blockIdx.x * 256 + threadIdx.x;   // N_LAYERS*8*4*64 = 8192
    if (idx >= N_LAYERS * 8 * 4 * 64) return;
    int lane = idx & 63;
    int kc = (idx >> 6) & 3;
    int nt = (idx >> 8) & 7;
    int layer = idx >> 11;
    int quad = lane >> 4, nl = lane & 15;
    int n = nt * 16 + nl;
    const float* w = lw + layer * HIDDEN * HIDDEN;
    uint r[4];
    #pragma unroll
    for (int jj = 0; jj < 4; jj++) {
        int k = kc * 32 + quad * 8 + 2 * jj;
        r[jj] = packbf(w[k * HIDDEN + n], w[(k + 1) * HIDDEN + n]);
    }
    uint4 o; o.x = r[0]; o.y = r[1]; o.z = r[2]; o.w = r[3];
    pb[idx] = o;
}

// ---------------------------------------------------------------------------
// CSR build (by destination = row). row is ~uniform-random -> low contention.
__global__ void k_count(const int* __restrict__ row, int* __restrict__ counts) {
    int e = blockIdx.x * 256 + threadIdx.x;
    if (e < N_EDGES) atomicAdd(&counts[row[e]], 1);
}

__global__ void k_scan1(const int* __restrict__ counts, int* __restrict__ partial,
                        int* __restrict__ blocksum) {
    int i = blockIdx.x * 256 + threadIdx.x;
    int v = (i < N_NODES) ? counts[i] : 0;
    int lane = threadIdx.x & 63;
    int wid = threadIdx.x >> 6;
    int s = v;
    #pragma unroll
    for (int off = 1; off < 64; off <<= 1) {
        int t = __shfl_up(s, off, 64);
        if (lane >= off) s += t;
    }
    __shared__ int wsum[4];
    if (lane == 63) wsum[wid] = s;
    __syncthreads();
    int woff = 0;
    for (int w = 0; w < wid; w++) woff += wsum[w];
    int incl = s + woff;
    if (i < N_NODES) partial[i] = incl - v;           // exclusive within block
    if (threadIdx.x == 255) blocksum[blockIdx.x] = incl;
}

__global__ void k_scan2(int* __restrict__ blocksum, int nblk) {
    int tid = threadIdx.x;
    int v = (tid < nblk) ? blocksum[tid] : 0;
    int lane = tid & 63, wid = tid >> 6;
    int s = v;
    #pragma unroll
    for (int off = 1; off < 64; off <<= 1) {
        int t = __shfl_up(s, off, 64);
        if (lane >= off) s += t;
    }
    __shared__ int wsum[4];
    if (lane == 63) wsum[wid] = s;
    __syncthreads();
    int woff = 0;
    for (int w = 0; w < wid; w++) woff += wsum[w];
    int incl = s + woff;
    if (tid < nblk) blocksum[tid] = incl - v;         // exclusive
}

__global__ void k_scan3(const int* __restrict__ partial, const int* __restrict__ blocksum,
                        int* __restrict__ offsets, int* __restrict__ cursor) {
    int i = blockIdx.x * 256 + threadIdx.x;
    if (i < N_NODES) {
        int o = partial[i] + blocksum[blockIdx.x];
        offsets[i] = o;
        cursor[i] = o;
    }
    if (i == 0) offsets[N_NODES] = N_EDGES;
}

// Pack per-edge (col, table coordinate t) into CSR slots.
__global__ void k_fill(const int* __restrict__ row, const int* __restrict__ col,
                       const float* __restrict__ eattr, int* __restrict__ cursor,
                       int2* __restrict__ meta) {
    int e = blockIdx.x * 256 + threadIdx.x;
    if (e >= N_EDGES) return;
    int r = row[e];
    int pos = atomicAdd(&cursor[r], 1);
    float t = eattr[e] * ((float)(TAB - 1) / CUTOFF);
    t = fminf(fmaxf(t, 0.0f), (float)(TAB - 2) + 0.9999f);
    int2 m;
    m.x = col[e];
    m.y = __float_as_int(t);
    meta[pos] = m;
}

// ---------------------------------------------------------------------------
// xl = h @ lw + lb via bf16 MFMA. One wave = 16 rows x 128 cols:
// 8 n-tiles x 4 k-chunks of v_mfma_f32_16x16x32_bf16.
// A layout: A[m=lane&15][k=(lane>>4)*8+j]; C/D: col=lane&15, row=(lane>>4)*4+reg.
__global__ __launch_bounds__(256) void k_xl(const ushort* __restrict__ hbf,
                                            const uint4* __restrict__ pb,
                                            const float* __restrict__ lb,
                                            ushort* __restrict__ xlb) {
    int wave = threadIdx.x >> 6, lane = threadIdx.x & 63;
    int m0 = (blockIdx.x * 4 + wave) * 16;
    if (m0 >= N_NODES) return;
    int quad = lane >> 4, ml = lane & 15;
    const ushort* arow = hbf + (size_t)(m0 + ml) * HIDDEN + quad * 8;
    bf16x8 a[4];
    #pragma unroll
    for (int kc = 0; kc < 4; kc++) a[kc] = *(const bf16x8*)(arow + kc * 32);
    #pragma unroll
    for (int nt = 0; nt < 8; nt++) {
        f32x4 acc = {0.f, 0.f, 0.f, 0.f};
        #pragma unroll
        for (int kc = 0; kc < 4; kc++) {
            bf16x8 b = *(const bf16x8*)(pb + (nt * 4 + kc) * 64 + lane);
            acc = __builtin_amdgcn_mfma_f32_16x16x32_bf16(a[kc], b, acc, 0, 0, 0);
        }
        int col = nt * 16 + ml;
        float bias = lb[col];
        #pragma unroll
        for (int r = 0; r < 4; r++) {
            int row = m0 + quad * 4 + r;
            xlb[(size_t)row * HIDDEN + col] = f2bf(acc[r] + bias);
        }
    }
}

// ---------------------------------------------------------------------------
// Aggregation + residual + LayerNorm, fused. One wave (64 lanes x 2 feats)
// per node; unroll x4; ctab gives w+dw in one load. Emits fp32 h and bf16 h.
__global__ __launch_bounds__(256) void k_agg(const ushort* __restrict__ xlb,
                                             const int2* __restrict__ meta,
                                             const int* __restrict__ offsets,
                                             const uint2* __restrict__ ctab,
                                             const float* __restrict__ h_in,
                                             const float* __restrict__ g,
                                             const float* __restrict__ b,
                                             float* __restrict__ h_out,
                                             ushort* __restrict__ hbf_out) {
    int wid = threadIdx.x >> 6;
    int lane = threadIdx.x & 63;
    int n = blockIdx.x * 4 + wid;
    if (n >= N_NODES) return;
    const uint* xl2 = (const uint*)xlb;    // bf16 pair per uint
    float accx = 0.f, accy = 0.f;
    int p0 = offsets[n], p1 = offsets[n + 1];
    const int2* mp = meta + p0;
    int cnt = p1 - p0;
    int k4 = cnt & ~3;
    int p = 0;
    for (; p < k4; p += 4) {
        int2 m0 = mp[p + 0];
        int2 m1 = mp[p + 1];
        int2 m2 = mp[p + 2];
        int2 m3 = mp[p + 3];
        float t0 = __int_as_float(m0.y), t1 = __int_as_float(m1.y);
        float t2 = __int_as_float(m2.y), t3 = __int_as_float(m3.y);
        int i0 = (int)t0, i1 = (int)t1, i2 = (int)t2, i3 = (int)t3;
        uint2 c0 = ctab[i0 * 64 + lane];
        uint2 c1 = ctab[i1 * 64 + lane];
        uint2 c2 = ctab[i2 * 64 + lane];
        uint2 c3 = ctab[i3 * 64 + lane];
        uint x0 = xl2[m0.x * 64 + lane];
        uint x1 = xl2[m1.x * 64 + lane];
        uint x2 = xl2[m2.x * 64 + lane];
        uint x3 = xl2[m3.x * 64 + lane];
        float f0 = t0 - (float)i0, f1 = t1 - (float)i1;
        float f2 = t2 - (float)i2, f3 = t3 - (float)i3;
        accx = fmaf(fmaf(f0, bflo(c0.y), bflo(c0.x)), bflo(x0), accx);
        accy = fmaf(fmaf(f0, bfhi(c0.y), bfhi(c0.x)), bfhi(x0), accy);
        accx = fmaf(fmaf(f1, bflo(c1.y), bflo(c1.x)), bflo(x1), accx);
        accy = fmaf(fmaf(f1, bfhi(c1.y), bfhi(c1.x)), bfhi(x1), accy);
        accx = fmaf(fmaf(f2, bflo(c2.y), bflo(c2.x)), bflo(x2), accx);
        accy = fmaf(fmaf(f2, bfhi(c2.y), bfhi(c2.x)), bfhi(x2), accy);
        accx = fmaf(fmaf(f3, bflo(c3.y), bflo(c3.x)), bflo(x3), accx);
        accy = fmaf(fmaf(f3, bfhi(c3.y), bfhi(c3.x)), bfhi(x3), accy);
    }
    for (; p < cnt; p++) {
        int2 m = mp[p];
        float t = __int_as_float(m.y);
        int i0 = (int)t;
        float fr = t - (float)i0;
        uint2 ce = ctab[i0 * 64 + lane];
        uint xu = xl2[m.x * 64 + lane];
        accx = fmaf(fmaf(fr, bflo(ce.y), bflo(ce.x)), bflo(xu), accx);
        accy = fmaf(fmaf(fr, bfhi(ce.y), bfhi(ce.x)), bfhi(xu), accy);
    }
    float2 hv = ((const float2*)h_in)[n * 64 + lane];
    float vx = hv.x + accx, vy = hv.y + accy;
    float s = vx + vy;
    #pragma unroll
    for (int off = 32; off; off >>= 1) s += __shfl_xor(s, off, 64);
    float mu = s * (1.0f / 128.0f);
    float dx = vx - mu, dy = vy - mu;
    float s2 = dx * dx + dy * dy;
    #pragma unroll
    for (int off = 32; off; off >>= 1) s2 += __shfl_xor(s2, off, 64);
    float rstd = rsqrtf(s2 * (1.0f / 128.0f) + 1e-5f);
    float2 gv = ((const float2*)g)[lane];
    float2 bv = ((const float2*)b)[lane];
    float2 o;
    o.x = fmaf(dx * rstd, gv.x, bv.x);
    o.y = fmaf(dy * rstd, gv.y, bv.y);
    ((float2*)h_out)[n * 64 + lane] = o;
    ((uint*)hbf_out)[n * 64 + lane] = packbf(o.x, o.y);
}

// ---------------------------------------------------------------------------
// Graph boundaries via binary search (batch is sorted).
__global__ void k_bounds(const int* __restrict__ batch, int* __restrict__ gstart) {
    int g = threadIdx.x;
    if (g > N_GRAPHS) return;
    int lo = 0, hi = N_NODES;
    while (lo < hi) {
        int mid = (lo + hi) >> 1;
        if (batch[mid] < g) lo = mid + 1; else hi = mid;
    }
    gstart[g] = lo;
}

// Mean pool, stage 1: PSPLIT blocks per graph write partial sums.
__global__ __launch_bounds__(256) void k_pool_part(const float* __restrict__ h,
                                                   const int* __restrict__ gstart,
                                                   float* __restrict__ partial) {
    int g = blockIdx.x / PSPLIT;
    int t = blockIdx.x % PSPLIT;
    int j = threadIdx.x & 127;
    int half = threadIdx.x >> 7;
    int s = gstart[g], e = gstart[g + 1];
    float acc = 0.f;
    for (int n = s + t * 2 + half; n < e; n += PSPLIT * 2) acc += h[n * HIDDEN + j];
    __shared__ float red[256];
    red[threadIdx.x] = acc;
    __syncthreads();
    if (half == 0) partial[(g * PSPLIT + t) * HIDDEN + j] = red[j] + red[j + 128];
}

// Mean pool, stage 2: reduce PSPLIT partials, divide by count.
__global__ void k_pool_fin(const float* __restrict__ partial,
                           const int* __restrict__ gstart,
                           float* __restrict__ out) {
    int idx = blockIdx.x * 128 + threadIdx.x;   // N_GRAPHS*HIDDEN total
    int g = idx >> 7, j = idx & 127;
    float tot = 0.f;
    #pragma unroll
    for (int t = 0; t < PSPLIT; t++) tot += partial[(g * PSPLIT + t) * HIDDEN + j];
    float c = (float)(gstart[g + 1] - gstart[g]);
    out[idx] = tot / fmaxf(c, 1.0f);
}

// ---------------------------------------------------------------------------
extern "C" void kernel_launch(void* const* d_in, const int* in_sizes, int n_in,
                              void* d_out, int out_size, void* d_ws, size_t ws_size,
                              hipStream_t stream) {
    const int* x = (const int*)d_in[0];
    const int* edge_index = (const int*)d_in[1];
    const int* row = edge_index;               // edge_index[0]
    const int* col = edge_index + N_EDGES;     // edge_index[1]
    const float* eattr = (const float*)d_in[2];
    const int* batch = (const int*)d_in[3];
    const float* emb = (const float*)d_in[4];
    const float* fw1 = (const float*)d_in[5];
    const float* fb1 = (const float*)d_in[6];
    const float* fw2 = (const float*)d_in[7];
    const float* fb2 = (const float*)d_in[8];
    const float* lw = (const float*)d_in[9];
    const float* lb = (const float*)d_in[10];
    const float* ln_g = (const float*)d_in[11];
    const float* ln_b = (const float*)d_in[12];
    float* out = (float*)d_out;

    char* ws = (char*)d_ws;
    size_t off = 0;
    auto alloc = [&](size_t bytes) -> void* {
        void* p = ws + off;
        off = (off + bytes + 255) & ~(size_t)255;
        return p;
    };
    uint2* ctab    = (uint2*)alloc((size_t)N_LAYERS * TAB * 64 * 8);
    float* h_a     = (float*)alloc((size_t)N_NODES * HIDDEN * 4);
    float* h_b     = (float*)alloc((size_t)N_NODES * HIDDEN * 4);
    ushort* hbf_a  = (ushort*)alloc((size_t)N_NODES * HIDDEN * 2);
    ushort* hbf_b  = (ushort*)alloc((size_t)N_NODES * HIDDEN * 2);
    ushort* xlb    = (ushort*)alloc((size_t)N_NODES * HIDDEN * 2);
    uint4* pb      = (uint4*)alloc((size_t)N_LAYERS * 8 * 4 * 64 * 16);
    int* counts    = (int*)alloc((size_t)(N_NODES + 1) * 4);
    int* offsets   = (int*)alloc((size_t)(N_NODES + 1) * 4);
    int* cursor    = (int*)alloc((size_t)N_NODES * 4);
    int* partial   = (int*)alloc((size_t)N_NODES * 4);
    int* blocksum  = (int*)alloc(256 * 4);
    int2* meta     = (int2*)alloc((size_t)N_EDGES * 8);
    int* gstart    = (int*)alloc((size_t)(N_GRAPHS + 1) * 4);
    float* ppart   = (float*)alloc((size_t)N_GRAPHS * PSPLIT * HIDDEN * 4);

    hipMemsetAsync(counts, 0, (size_t)(N_NODES + 1) * 4, stream);

    k_table<<<N_LAYERS * (TAB / TG), 128, 0, stream>>>(fw1, fb1, fw2, fb2, ctab);
    k_embed<<<(N_NODES * 32 + 255) / 256, 256, 0, stream>>>(x, emb, h_a, hbf_a);
    k_packw<<<(N_LAYERS * 8 * 4 * 64 + 255) / 256, 256, 0, stream>>>(lw, pb);
    k_count<<<(N_EDGES + 255) / 256, 256, 0, stream>>>(row, counts);
    const int NBLK = (N_NODES + 255) / 256;   // 196
    k_scan1<<<NBLK, 256, 0, stream>>>(counts, partial, blocksum);
    k_scan2<<<1, 256, 0, stream>>>(blocksum, NBLK);
    k_scan3<<<NBLK, 256, 0, stream>>>(partial, blocksum, offsets, cursor);
    k_fill<<<(N_EDGES + 255) / 256, 256, 0, stream>>>(row, col, eattr, cursor, meta);
    k_bounds<<<1, 128, 0, stream>>>(batch, gstart);

    float* h_cur = h_a;   float* h_nxt = h_b;
    ushort* hb_cur = hbf_a; ushort* hb_nxt = hbf_b;
    const int XLBLK = (N_NODES / 16 + 3) / 4;   // 3125 waves -> 782 blocks
    for (int i = 0; i < N_LAYERS; i++) {
        k_xl<<<XLBLK, 256, 0, stream>>>(hb_cur, pb + (size_t)i * 8 * 4 * 64,
                                        lb + i * HIDDEN, xlb);
        k_agg<<<(N_NODES + 3) / 4, 256, 0, stream>>>(xlb, meta, offsets,
                                                     ctab + (size_t)i * TAB * 64,
                                                     h_cur, ln_g + i * HIDDEN,
                                                     ln_b + i * HIDDEN, h_nxt, hb_nxt);
        float* tf = h_cur; h_cur = h_nxt; h_nxt = tf;
        ushort* tb = hb_cur; hb_cur = hb_nxt; hb_nxt = tb;
    }
    k_pool_part<<<N_GRAPHS * PSPLIT, 256, 0, stream>>>(h_cur, gstart, ppart);
    k_pool_fin<<<(N_GRAPHS * HIDDEN + 127) / 128, 128, 0, stream>>>(ppart, gstart, out);
}

// Round 6
// 425.941 us; speedup vs baseline: 2.5567x; 1.0269x over previous
//
#include <hip/hip_runtime.h>
#include <hip/hip_bf16.h>

#define N_NODES 50000
#define N_EDGES 640000
#define HIDDEN 128
#define N_LAYERS 4
#define NUM_RBF 50
#define CUTOFF 4.0f
#define N_GRAPHS 64
#define TAB 2048
#define TG 8            // grid points per k_table block
#define PSPLIT 16       // pool blocks per graph

typedef unsigned int uint;
typedef unsigned short ushort;
typedef __attribute__((ext_vector_type(8))) short bf16x8;   // MFMA A/B frag (4 VGPRs)
typedef __attribute__((ext_vector_type(4))) float f32x4;    // MFMA C/D frag

__device__ inline ushort f2bf(float f) {   // RNE float->bf16 (finite inputs)
    uint u = __float_as_uint(f);
    uint r = (u + 0x7fffu + ((u >> 16) & 1u)) >> 16;
    return (ushort)r;
}
__device__ inline uint packbf(float lo, float hi) {
    return (uint)f2bf(lo) | ((uint)f2bf(hi) << 16);
}
__device__ inline float bflo(uint u) { return __uint_as_float(u << 16); }
__device__ inline float bfhi(uint u) { return __uint_as_float(u & 0xffff0000u); }

// ---------------------------------------------------------------------------
// Combined lerp table: for each (layer, grid point g) a 512B row of 64 uint2:
//   .x = bf16 pair (w[g][2jp], w[g][2jp+1]) ; .y = bf16 pair of deltas.
__global__ __launch_bounds__(128) void k_table(const float* __restrict__ fw1,
                                               const float* __restrict__ fb1,
                                               const float* __restrict__ fw2,
                                               const float* __restrict__ fb2,
                                               uint2* __restrict__ ctab) {
    int bid = blockIdx.x;
    int layer = bid / (TAB / TG);
    int g0 = (bid % (TAB / TG)) * TG;
    int j = threadIdx.x;
    const int NP = TG + 1;
    __shared__ float rbf[NP][NUM_RBF];
    __shared__ float hid[NP][HIDDEN];
    __shared__ float wout[NP][HIDDEN];
    for (int idx = j; idx < NP * NUM_RBF; idx += 128) {
        int gg = idx / NUM_RBF, r = idx % NUM_RBF;
        float d = (CUTOFF * (g0 + gg)) / (float)(TAB - 1);
        float offset = (CUTOFF * r) / (float)(NUM_RBF - 1);
        float delta = CUTOFF / (float)(NUM_RBF - 1);
        float coeff = -0.5f / (delta * delta);
        float t = d - offset;
        rbf[gg][r] = expf(coeff * t * t);
    }
    __syncthreads();
    const float* w1 = fw1 + layer * NUM_RBF * HIDDEN;
    float b1 = fb1[layer * HIDDEN + j];
    float acc[NP];
    #pragma unroll
    for (int gg = 0; gg < NP; gg++) acc[gg] = b1;
    for (int r = 0; r < NUM_RBF; r++) {
        float w = w1[r * HIDDEN + j];
        #pragma unroll
        for (int gg = 0; gg < NP; gg++) acc[gg] = fmaf(rbf[gg][r], w, acc[gg]);
    }
    #pragma unroll
    for (int gg = 0; gg < NP; gg++) hid[gg][j] = fmaxf(acc[gg], 0.0f);
    __syncthreads();
    const float* w2 = fw2 + layer * HIDDEN * HIDDEN;
    float b2 = fb2[layer * HIDDEN + j];
    float acc2[NP];
    #pragma unroll
    for (int gg = 0; gg < NP; gg++) acc2[gg] = b2;
    for (int k = 0; k < HIDDEN; k += 4) {
        float w0 = w2[(k + 0) * HIDDEN + j];
        float w1v = w2[(k + 1) * HIDDEN + j];
        float w2v = w2[(k + 2) * HIDDEN + j];
        float w3 = w2[(k + 3) * HIDDEN + j];
        #pragma unroll
        for (int gg = 0; gg < NP; gg++) {
            acc2[gg] = fmaf(hid[gg][k + 0], w0, acc2[gg]);
            acc2[gg] = fmaf(hid[gg][k + 1], w1v, acc2[gg]);
            acc2[gg] = fmaf(hid[gg][k + 2], w2v, acc2[gg]);
            acc2[gg] = fmaf(hid[gg][k + 3], w3, acc2[gg]);
        }
    }
    #pragma unroll
    for (int gg = 0; gg < NP; gg++) wout[gg][j] = acc2[gg];
    __syncthreads();
    for (int idx = j; idx < TG * 64; idx += 128) {
        int gg = idx >> 6, jp = idx & 63;
        float wl = wout[gg][2 * jp], wh = wout[gg][2 * jp + 1];
        float dl = wout[gg + 1][2 * jp] - wl, dh = wout[gg + 1][2 * jp + 1] - wh;
        uint2 e;
        e.x = packbf(wl, wh);
        e.y = packbf(dl, dh);
        ctab[((size_t)layer * TAB + g0 + gg) * 64 + jp] = e;
    }
}

// ---------------------------------------------------------------------------
// Embedding gather: hbf[n][:] = bf16(emb[x[n]][:])
__global__ void k_embed(const int* __restrict__ x, const float* __restrict__ emb,
                        ushort* __restrict__ hbf) {
    int idx = blockIdx.x * 256 + threadIdx.x;   // over N_NODES*32 float4s
    if (idx >= N_NODES * 32) return;
    int n = idx >> 5, q = idx & 31;
    float4 v = ((const float4*)emb)[x[n] * 32 + q];
    uint2 p;
    p.x = packbf(v.x, v.y);
    p.y = packbf(v.z, v.w);
    ((uint2*)hbf)[idx] = p;
}

// ---------------------------------------------------------------------------
// Pack lw into B-fragment order for mfma_f32_16x16x32_bf16:
// pb[layer][nt][kc][lane] = 8 bf16, element j = lw[k=kc*32+(lane>>4)*8+j][n=nt*16+(lane&15)]
__global__ void k_packw(const float* __restrict__ lw, uint4* __restrict__ pb) {
    int idx = blockIdx.x * 256 + threadIdx.x;   // N_LAYERS*8*4*64 = 8192
    if (idx >= N_LAYERS * 8 * 4 * 64) return;
    int lane = idx & 63;
    int kc = (idx >> 6) & 3;
    int nt = (idx >> 8) & 7;
    int layer = idx >> 11;
    int quad = lane >> 4, nl = lane & 15;
    int n = nt * 16 + nl;
    const float* w = lw + layer * HIDDEN * HIDDEN;
    uint r[4];
    #pragma unroll
    for (int jj = 0; jj < 4; jj++) {
        int k = kc * 32 + quad * 8 + 2 * jj;
        r[jj] = packbf(w[k * HIDDEN + n], w[(k + 1) * HIDDEN + n]);
    }
    uint4 o; o.x = r[0]; o.y = r[1]; o.z = r[2]; o.w = r[3];
    pb[idx] = o;
}

// ---------------------------------------------------------------------------
// CSR build (by destination = row). row is ~uniform-random -> low contention.
__global__ void k_count(const int* __restrict__ row, int* __restrict__ counts) {
    int e = blockIdx.x * 256 + threadIdx.x;
    if (e < N_EDGES) atomicAdd(&counts[row[e]], 1);
}

__global__ void k_scan1(const int* __restrict__ counts, int* __restrict__ partial,
                        int* __restrict__ blocksum) {
    int i = blockIdx.x * 256 + threadIdx.x;
    int v = (i < N_NODES) ? counts[i] : 0;
    int lane = threadIdx.x & 63;
    int wid = threadIdx.x >> 6;
    int s = v;
    #pragma unroll
    for (int off = 1; off < 64; off <<= 1) {
        int t = __shfl_up(s, off, 64);
        if (lane >= off) s += t;
    }
    __shared__ int wsum[4];
    if (lane == 63) wsum[wid] = s;
    __syncthreads();
    int woff = 0;
    for (int w = 0; w < wid; w++) woff += wsum[w];
    int incl = s + woff;
    if (i < N_NODES) partial[i] = incl - v;           // exclusive within block
    if (threadIdx.x == 255) blocksum[blockIdx.x] = incl;
}

__global__ void k_scan2(int* __restrict__ blocksum, int nblk) {
    int tid = threadIdx.x;
    int v = (tid < nblk) ? blocksum[tid] : 0;
    int lane = tid & 63, wid = tid >> 6;
    int s = v;
    #pragma unroll
    for (int off = 1; off < 64; off <<= 1) {
        int t = __shfl_up(s, off, 64);
        if (lane >= off) s += t;
    }
    __shared__ int wsum[4];
    if (lane == 63) wsum[wid] = s;
    __syncthreads();
    int woff = 0;
    for (int w = 0; w < wid; w++) woff += wsum[w];
    int incl = s + woff;
    if (tid < nblk) blocksum[tid] = incl - v;         // exclusive
}

__global__ void k_scan3(const int* __restrict__ partial, const int* __restrict__ blocksum,
                        int* __restrict__ offsets, int* __restrict__ cursor) {
    int i = blockIdx.x * 256 + threadIdx.x;
    if (i < N_NODES) {
        int o = partial[i] + blocksum[blockIdx.x];
        offsets[i] = o;
        cursor[i] = o;
    }
    if (i == 0) offsets[N_NODES] = N_EDGES;
}

// Pack per-edge (col, table coordinate t) into CSR slots.
__global__ void k_fill(const int* __restrict__ row, const int* __restrict__ col,
                       const float* __restrict__ eattr, int* __restrict__ cursor,
                       int2* __restrict__ meta) {
    int e = blockIdx.x * 256 + threadIdx.x;
    if (e >= N_EDGES) return;
    int r = row[e];
    int pos = atomicAdd(&cursor[r], 1);
    float t = eattr[e] * ((float)(TAB - 1) / CUTOFF);
    t = fminf(fmaxf(t, 0.0f), (float)(TAB - 2) + 0.9999f);
    int2 m;
    m.x = col[e];
    m.y = __float_as_int(t);
    meta[pos] = m;
}

// ---------------------------------------------------------------------------
// xl = h @ lw + lb via bf16 MFMA. One wave = 16 rows x 128 cols:
// 8 n-tiles x 4 k-chunks of v_mfma_f32_16x16x32_bf16.
// A layout: A[m=lane&15][k=(lane>>4)*8+j]; C/D: col=lane&15, row=(lane>>4)*4+reg.
__global__ __launch_bounds__(256) void k_xl(const ushort* __restrict__ hbf,
                                            const uint4* __restrict__ pb,
                                            const float* __restrict__ lb,
                                            ushort* __restrict__ xlb) {
    int wave = threadIdx.x >> 6, lane = threadIdx.x & 63;
    int m0 = (blockIdx.x * 4 + wave) * 16;
    if (m0 >= N_NODES) return;
    int quad = lane >> 4, ml = lane & 15;
    const ushort* arow = hbf + (size_t)(m0 + ml) * HIDDEN + quad * 8;
    bf16x8 a[4];
    #pragma unroll
    for (int kc = 0; kc < 4; kc++) a[kc] = *(const bf16x8*)(arow + kc * 32);
    #pragma unroll
    for (int nt = 0; nt < 8; nt++) {
        f32x4 acc = {0.f, 0.f, 0.f, 0.f};
        #pragma unroll
        for (int kc = 0; kc < 4; kc++) {
            bf16x8 b = *(const bf16x8*)(pb + (nt * 4 + kc) * 64 + lane);
            acc = __builtin_amdgcn_mfma_f32_16x16x32_bf16(a[kc], b, acc, 0, 0, 0);
        }
        int col = nt * 16 + ml;
        float bias = lb[col];
        #pragma unroll
        for (int r = 0; r < 4; r++) {
            int row = m0 + quad * 4 + r;
            xlb[(size_t)row * HIDDEN + col] = f2bf(acc[r] + bias);
        }
    }
}

// ---------------------------------------------------------------------------
// Aggregation + residual + LayerNorm, fused. One wave (64 lanes x 2 feats)
// per node; unroll x4; ctab gives w+dw in one load. bf16 residual stream.
__global__ __launch_bounds__(256) void k_agg(const ushort* __restrict__ xlb,
                                             const int2* __restrict__ meta,
                                             const int* __restrict__ offsets,
                                             const uint2* __restrict__ ctab,
                                             const ushort* __restrict__ hb_in,
                                             const float* __restrict__ g,
                                             const float* __restrict__ b,
                                             ushort* __restrict__ hbf_out) {
    int wid = threadIdx.x >> 6;
    int lane = threadIdx.x & 63;
    int n = blockIdx.x * 4 + wid;
    if (n >= N_NODES) return;
    const uint* xl2 = (const uint*)xlb;    // bf16 pair per uint
    float accx = 0.f, accy = 0.f;
    int p0 = offsets[n], p1 = offsets[n + 1];
    const int2* mp = meta + p0;
    int cnt = p1 - p0;
    int k4 = cnt & ~3;
    int p = 0;
    for (; p < k4; p += 4) {
        int2 m0 = mp[p + 0];
        int2 m1 = mp[p + 1];
        int2 m2 = mp[p + 2];
        int2 m3 = mp[p + 3];
        float t0 = __int_as_float(m0.y), t1 = __int_as_float(m1.y);
        float t2 = __int_as_float(m2.y), t3 = __int_as_float(m3.y);
        int i0 = (int)t0, i1 = (int)t1, i2 = (int)t2, i3 = (int)t3;
        uint2 c0 = ctab[i0 * 64 + lane];
        uint2 c1 = ctab[i1 * 64 + lane];
        uint2 c2 = ctab[i2 * 64 + lane];
        uint2 c3 = ctab[i3 * 64 + lane];
        uint x0 = xl2[m0.x * 64 + lane];
        uint x1 = xl2[m1.x * 64 + lane];
        uint x2 = xl2[m2.x * 64 + lane];
        uint x3 = xl2[m3.x * 64 + lane];
        float f0 = t0 - (float)i0, f1 = t1 - (float)i1;
        float f2 = t2 - (float)i2, f3 = t3 - (float)i3;
        accx = fmaf(fmaf(f0, bflo(c0.y), bflo(c0.x)), bflo(x0), accx);
        accy = fmaf(fmaf(f0, bfhi(c0.y), bfhi(c0.x)), bfhi(x0), accy);
        accx = fmaf(fmaf(f1, bflo(c1.y), bflo(c1.x)), bflo(x1), accx);
        accy = fmaf(fmaf(f1, bfhi(c1.y), bfhi(c1.x)), bfhi(x1), accy);
        accx = fmaf(fmaf(f2, bflo(c2.y), bflo(c2.x)), bflo(x2), accx);
        accy = fmaf(fmaf(f2, bfhi(c2.y), bfhi(c2.x)), bfhi(x2), accy);
        accx = fmaf(fmaf(f3, bflo(c3.y), bflo(c3.x)), bflo(x3), accx);
        accy = fmaf(fmaf(f3, bfhi(c3.y), bfhi(c3.x)), bfhi(x3), accy);
    }
    for (; p < cnt; p++) {
        int2 m = mp[p];
        float t = __int_as_float(m.y);
        int i0 = (int)t;
        float fr = t - (float)i0;
        uint2 ce = ctab[i0 * 64 + lane];
        uint xu = xl2[m.x * 64 + lane];
        accx = fmaf(fmaf(fr, bflo(ce.y), bflo(ce.x)), bflo(xu), accx);
        accy = fmaf(fmaf(fr, bfhi(ce.y), bfhi(ce.x)), bfhi(xu), accy);
    }
    uint hvp = ((const uint*)hb_in)[n * 64 + lane];
    float vx = bflo(hvp) + accx, vy = bfhi(hvp) + accy;
    float s = vx + vy;
    #pragma unroll
    for (int off = 32; off; off >>= 1) s += __shfl_xor(s, off, 64);
    float mu = s * (1.0f / 128.0f);
    float dx = vx - mu, dy = vy - mu;
    float s2 = dx * dx + dy * dy;
    #pragma unroll
    for (int off = 32; off; off >>= 1) s2 += __shfl_xor(s2, off, 64);
    float rstd = rsqrtf(s2 * (1.0f / 128.0f) + 1e-5f);
    float2 gv = ((const float2*)g)[lane];
    float2 bv = ((const float2*)b)[lane];
    float ox = fmaf(dx * rstd, gv.x, bv.x);
    float oy = fmaf(dy * rstd, gv.y, bv.y);
    ((uint*)hbf_out)[n * 64 + lane] = packbf(ox, oy);
}

// ---------------------------------------------------------------------------
// Graph boundaries via binary search (batch is sorted).
__global__ void k_bounds(const int* __restrict__ batch, int* __restrict__ gstart) {
    int g = threadIdx.x;
    if (g > N_GRAPHS) return;
    int lo = 0, hi = N_NODES;
    while (lo < hi) {
        int mid = (lo + hi) >> 1;
        if (batch[mid] < g) lo = mid + 1; else hi = mid;
    }
    gstart[g] = lo;
}

// Mean pool, stage 1: PSPLIT blocks per graph write partial sums (bf16 input).
__global__ __launch_bounds__(256) void k_pool_part(const ushort* __restrict__ hbf,
                                                   const int* __restrict__ gstart,
                                                   float* __restrict__ partial) {
    int g = blockIdx.x / PSPLIT;
    int t = blockIdx.x % PSPLIT;
    int jp = threadIdx.x & 63;       // bf16-pair index (2 feats per thread)
    int half = threadIdx.x >> 6;     // 4 node-rows in flight
    int s = gstart[g], e = gstart[g + 1];
    float accx = 0.f, accy = 0.f;
    const uint* h2 = (const uint*)hbf;
    for (int n = s + t * 4 + half; n < e; n += PSPLIT * 4) {
        uint v = h2[n * 64 + jp];
        accx += bflo(v);
        accy += bfhi(v);
    }
    __shared__ float redx[256], redy[256];
    redx[threadIdx.x] = accx;
    redy[threadIdx.x] = accy;
    __syncthreads();
    if (half == 0) {
        float tx = redx[jp] + redx[jp + 64] + redx[jp + 128] + redx[jp + 192];
        float ty = redy[jp] + redy[jp + 64] + redy[jp + 128] + redy[jp + 192];
        float2 o; o.x = tx; o.y = ty;
        ((float2*)partial)[(g * PSPLIT + t) * 64 + jp] = o;
    }
}

// Mean pool, stage 2: reduce PSPLIT partials, divide by count.
__global__ void k_pool_fin(const float* __restrict__ partial,
                           const int* __restrict__ gstart,
                           float* __restrict__ out) {
    int idx = blockIdx.x * 128 + threadIdx.x;   // N_GRAPHS*HIDDEN total
    int g = idx >> 7, j = idx & 127;
    float tot = 0.f;
    #pragma unroll
    for (int t = 0; t < PSPLIT; t++) tot += partial[(g * PSPLIT + t) * HIDDEN + j];
    float c = (float)(gstart[g + 1] - gstart[g]);
    out[idx] = tot / fmaxf(c, 1.0f);
}

// ---------------------------------------------------------------------------
extern "C" void kernel_launch(void* const* d_in, const int* in_sizes, int n_in,
                              void* d_out, int out_size, void* d_ws, size_t ws_size,
                              hipStream_t stream) {
    const int* x = (const int*)d_in[0];
    const int* edge_index = (const int*)d_in[1];
    const int* row = edge_index;               // edge_index[0]
    const int* col = edge_index + N_EDGES;     // edge_index[1]
    const float* eattr = (const float*)d_in[2];
    const int* batch = (const int*)d_in[3];
    const float* emb = (const float*)d_in[4];
    const float* fw1 = (const float*)d_in[5];
    const float* fb1 = (const float*)d_in[6];
    const float* fw2 = (const float*)d_in[7];
    const float* fb2 = (const float*)d_in[8];
    const float* lw = (const float*)d_in[9];
    const float* lb = (const float*)d_in[10];
    const float* ln_g = (const float*)d_in[11];
    const float* ln_b = (const float*)d_in[12];
    float* out = (float*)d_out;

    char* ws = (char*)d_ws;
    size_t off = 0;
    auto alloc = [&](size_t bytes) -> void* {
        void* p = ws + off;
        off = (off + bytes + 255) & ~(size_t)255;
        return p;
    };
    uint2* ctab    = (uint2*)alloc((size_t)N_LAYERS * TAB * 64 * 8);
    ushort* hbf_a  = (ushort*)alloc((size_t)N_NODES * HIDDEN * 2);
    ushort* hbf_b  = (ushort*)alloc((size_t)N_NODES * HIDDEN * 2);
    ushort* xlb    = (ushort*)alloc((size_t)N_NODES * HIDDEN * 2);
    uint4* pb      = (uint4*)alloc((size_t)N_LAYERS * 8 * 4 * 64 * 16);
    int* counts    = (int*)alloc((size_t)(N_NODES + 1) * 4);
    int* offsets   = (int*)alloc((size_t)(N_NODES + 1) * 4);
    int* cursor    = (int*)alloc((size_t)N_NODES * 4);
    int* partial   = (int*)alloc((size_t)N_NODES * 4);
    int* blocksum  = (int*)alloc(256 * 4);
    int2* meta     = (int2*)alloc((size_t)N_EDGES * 8);
    int* gstart    = (int*)alloc((size_t)(N_GRAPHS + 1) * 4);
    float* ppart   = (float*)alloc((size_t)N_GRAPHS * PSPLIT * HIDDEN * 4);

    hipMemsetAsync(counts, 0, (size_t)(N_NODES + 1) * 4, stream);

    k_table<<<N_LAYERS * (TAB / TG), 128, 0, stream>>>(fw1, fb1, fw2, fb2, ctab);
    k_embed<<<(N_NODES * 32 + 255) / 256, 256, 0, stream>>>(x, emb, hbf_a);
    k_packw<<<(N_LAYERS * 8 * 4 * 64 + 255) / 256, 256, 0, stream>>>(lw, pb);
    k_count<<<(N_EDGES + 255) / 256, 256, 0, stream>>>(row, counts);
    const int NBLK = (N_NODES + 255) / 256;   // 196
    k_scan1<<<NBLK, 256, 0, stream>>>(counts, partial, blocksum);
    k_scan2<<<1, 256, 0, stream>>>(blocksum, NBLK);
    k_scan3<<<NBLK, 256, 0, stream>>>(partial, blocksum, offsets, cursor);
    k_fill<<<(N_EDGES + 255) / 256, 256, 0, stream>>>(row, col, eattr, cursor, meta);
    k_bounds<<<1, 128, 0, stream>>>(batch, gstart);

    ushort* hb_cur = hbf_a; ushort* hb_nxt = hbf_b;
    const int XLBLK = (N_NODES / 16 + 3) / 4;   // 3125 waves -> 782 blocks
    for (int i = 0; i < N_LAYERS; i++) {
        k_xl<<<XLBLK, 256, 0, stream>>>(hb_cur, pb + (size_t)i * 8 * 4 * 64,
                                        lb + i * HIDDEN, xlb);
        k_agg<<<(N_NODES + 3) / 4, 256, 0, stream>>>(xlb, meta, offsets,
                                                     ctab + (size_t)i * TAB * 64,
                                                     hb_cur, ln_g + i * HIDDEN,
                                                     ln_b + i * HIDDEN, hb_nxt);
        ushort* tb = hb_cur; hb_cur = hb_nxt; hb_nxt = tb;
    }
    k_pool_part<<<N_GRAPHS * PSPLIT, 256, 0, stream>>>(hb_cur, gstart, ppart);
    k_pool_fin<<<(N_GRAPHS * HIDDEN + 127) / 128, 128, 0, stream>>>(ppart, gstart, out);
}

// Round 7
// 418.694 us; speedup vs baseline: 2.6009x; 1.0173x over previous
//
#include <hip/hip_runtime.h>
#include <hip/hip_bf16.h>

#define N_NODES 50000
#define N_EDGES 640000
#define HIDDEN 128
#define N_LAYERS 4
#define NUM_RBF 50
#define CUTOFF 4.0f
#define N_GRAPHS 64
#define TAB 8192        // nearest-neighbor table (half-step 2.44e-4)
#define TG 8            // grid points per k_table block
#define PSPLIT 16       // pool blocks per graph
#define COLBITS 17      // meta packing: col in [0,2^17), gi in high bits

typedef unsigned int uint;
typedef unsigned short ushort;
typedef __attribute__((ext_vector_type(8))) short bf16x8;   // MFMA A/B frag (4 VGPRs)
typedef __attribute__((ext_vector_type(4))) float f32x4;    // MFMA C/D frag

__device__ inline ushort f2bf(float f) {   // RNE float->bf16 (finite inputs)
    uint u = __float_as_uint(f);
    uint r = (u + 0x7fffu + ((u >> 16) & 1u)) >> 16;
    return (ushort)r;
}
__device__ inline uint packbf(float lo, float hi) {
    return (uint)f2bf(lo) | ((uint)f2bf(hi) << 16);
}
__device__ inline float bflo(uint u) { return __uint_as_float(u << 16); }
__device__ inline float bfhi(uint u) { return __uint_as_float(u & 0xffff0000u); }

// ---------------------------------------------------------------------------
// Nearest-neighbor filter table: row g = 64 uints (256B), bf16 pair per lane.
// One block (128 threads) computes TG grid points for one layer.
__global__ __launch_bounds__(128) void k_table(const float* __restrict__ fw1,
                                               const float* __restrict__ fb1,
                                               const float* __restrict__ fw2,
                                               const float* __restrict__ fb2,
                                               uint* __restrict__ ctab) {
    int bid = blockIdx.x;
    int layer = bid / (TAB / TG);
    int g0 = (bid % (TAB / TG)) * TG;
    int j = threadIdx.x;
    __shared__ float rbf[TG][NUM_RBF];
    __shared__ float wout[TG][HIDDEN];
    __shared__ float hid[TG][HIDDEN];
    for (int idx = j; idx < TG * NUM_RBF; idx += 128) {
        int gg = idx / NUM_RBF, r = idx % NUM_RBF;
        float d = (CUTOFF * (g0 + gg)) / (float)(TAB - 1);
        float offset = (CUTOFF * r) / (float)(NUM_RBF - 1);
        float delta = CUTOFF / (float)(NUM_RBF - 1);
        float coeff = -0.5f / (delta * delta);
        float t = d - offset;
        rbf[gg][r] = expf(coeff * t * t);
    }
    __syncthreads();
    const float* w1 = fw1 + layer * NUM_RBF * HIDDEN;
    float b1 = fb1[layer * HIDDEN + j];
    float acc[TG];
    #pragma unroll
    for (int gg = 0; gg < TG; gg++) acc[gg] = b1;
    for (int r = 0; r < NUM_RBF; r++) {
        float w = w1[r * HIDDEN + j];
        #pragma unroll
        for (int gg = 0; gg < TG; gg++) acc[gg] = fmaf(rbf[gg][r], w, acc[gg]);
    }
    #pragma unroll
    for (int gg = 0; gg < TG; gg++) hid[gg][j] = fmaxf(acc[gg], 0.0f);
    __syncthreads();
    const float* w2 = fw2 + layer * HIDDEN * HIDDEN;
    float b2 = fb2[layer * HIDDEN + j];
    float acc2[TG];
    #pragma unroll
    for (int gg = 0; gg < TG; gg++) acc2[gg] = b2;
    for (int k = 0; k < HIDDEN; k += 4) {
        float w0 = w2[(k + 0) * HIDDEN + j];
        float w1v = w2[(k + 1) * HIDDEN + j];
        float w2v = w2[(k + 2) * HIDDEN + j];
        float w3 = w2[(k + 3) * HIDDEN + j];
        #pragma unroll
        for (int gg = 0; gg < TG; gg++) {
            acc2[gg] = fmaf(hid[gg][k + 0], w0, acc2[gg]);
            acc2[gg] = fmaf(hid[gg][k + 1], w1v, acc2[gg]);
            acc2[gg] = fmaf(hid[gg][k + 2], w2v, acc2[gg]);
            acc2[gg] = fmaf(hid[gg][k + 3], w3, acc2[gg]);
        }
    }
    #pragma unroll
    for (int gg = 0; gg < TG; gg++) wout[gg][j] = acc2[gg];
    __syncthreads();
    for (int idx = j; idx < TG * 64; idx += 128) {
        int gg = idx >> 6, jp = idx & 63;
        ctab[((size_t)layer * TAB + g0 + gg) * 64 + jp] =
            packbf(wout[gg][2 * jp], wout[gg][2 * jp + 1]);
    }
}

// ---------------------------------------------------------------------------
// Embedding gather: hbf[n][:] = bf16(emb[x[n]][:])
__global__ void k_embed(const int* __restrict__ x, const float* __restrict__ emb,
                        ushort* __restrict__ hbf) {
    int idx = blockIdx.x * 256 + threadIdx.x;   // over N_NODES*32 float4s
    if (idx >= N_NODES * 32) return;
    int n = idx >> 5, q = idx & 31;
    float4 v = ((const float4*)emb)[x[n] * 32 + q];
    uint2 p;
    p.x = packbf(v.x, v.y);
    p.y = packbf(v.z, v.w);
    ((uint2*)hbf)[idx] = p;
}

// ---------------------------------------------------------------------------
// Pack lw into B-fragment order for mfma_f32_16x16x32_bf16.
__global__ void k_packw(const float* __restrict__ lw, uint4* __restrict__ pb) {
    int idx = blockIdx.x * 256 + threadIdx.x;   // N_LAYERS*8*4*64 = 8192
    if (idx >= N_LAYERS * 8 * 4 * 64) return;
    int lane = idx & 63;
    int kc = (idx >> 6) & 3;
    int nt = (idx >> 8) & 7;
    int layer = idx >> 11;
    int quad = lane >> 4, nl = lane & 15;
    int n = nt * 16 + nl;
    const float* w = lw + layer * HIDDEN * HIDDEN;
    uint r[4];
    #pragma unroll
    for (int jj = 0; jj < 4; jj++) {
        int k = kc * 32 + quad * 8 + 2 * jj;
        r[jj] = packbf(w[k * HIDDEN + n], w[(k + 1) * HIDDEN + n]);
    }
    uint4 o; o.x = r[0]; o.y = r[1]; o.z = r[2]; o.w = r[3];
    pb[idx] = o;
}

// ---------------------------------------------------------------------------
// CSR build (by destination = row). row is ~uniform-random -> low contention.
__global__ void k_count(const int* __restrict__ row, int* __restrict__ counts) {
    int e = blockIdx.x * 256 + threadIdx.x;
    if (e < N_EDGES) atomicAdd(&counts[row[e]], 1);
}

__global__ void k_scan1(const int* __restrict__ counts, int* __restrict__ partial,
                        int* __restrict__ blocksum) {
    int i = blockIdx.x * 256 + threadIdx.x;
    int v = (i < N_NODES) ? counts[i] : 0;
    int lane = threadIdx.x & 63;
    int wid = threadIdx.x >> 6;
    int s = v;
    #pragma unroll
    for (int off = 1; off < 64; off <<= 1) {
        int t = __shfl_up(s, off, 64);
        if (lane >= off) s += t;
    }
    __shared__ int wsum[4];
    if (lane == 63) wsum[wid] = s;
    __syncthreads();
    int woff = 0;
    for (int w = 0; w < wid; w++) woff += wsum[w];
    int incl = s + woff;
    if (i < N_NODES) partial[i] = incl - v;           // exclusive within block
    if (threadIdx.x == 255) blocksum[blockIdx.x] = incl;
}

__global__ void k_scan2(int* __restrict__ blocksum, int nblk) {
    int tid = threadIdx.x;
    int v = (tid < nblk) ? blocksum[tid] : 0;
    int lane = tid & 63, wid = tid >> 6;
    int s = v;
    #pragma unroll
    for (int off = 1; off < 64; off <<= 1) {
        int t = __shfl_up(s, off, 64);
        if (lane >= off) s += t;
    }
    __shared__ int wsum[4];
    if (lane == 63) wsum[wid] = s;
    __syncthreads();
    int woff = 0;
    for (int w = 0; w < wid; w++) woff += wsum[w];
    int incl = s + woff;
    if (tid < nblk) blocksum[tid] = incl - v;         // exclusive
}

__global__ void k_scan3(const int* __restrict__ partial, const int* __restrict__ blocksum,
                        int* __restrict__ offsets, int* __restrict__ cursor) {
    int i = blockIdx.x * 256 + threadIdx.x;
    if (i < N_NODES) {
        int o = partial[i] + blocksum[blockIdx.x];
        offsets[i] = o;
        cursor[i] = o;
    }
    if (i == 0) offsets[N_NODES] = N_EDGES;
}

// Pack per-edge (col | nearest-table-row << COLBITS) into CSR slots.
__global__ void k_fill(const int* __restrict__ row, const int* __restrict__ col,
                       const float* __restrict__ eattr, int* __restrict__ cursor,
                       uint* __restrict__ meta) {
    int e = blockIdx.x * 256 + threadIdx.x;
    if (e >= N_EDGES) return;
    int r = row[e];
    int pos = atomicAdd(&cursor[r], 1);
    float t = eattr[e] * ((float)(TAB - 1) / CUTOFF);
    int gi = (int)(t + 0.5f);
    gi = min(max(gi, 0), TAB - 1);
    meta[pos] = (uint)col[e] | ((uint)gi << COLBITS);
}

// ---------------------------------------------------------------------------
// xl = h @ lw + lb via bf16 MFMA. One wave = 16 rows x 128 cols.
__global__ __launch_bounds__(256) void k_xl(const ushort* __restrict__ hbf,
                                            const uint4* __restrict__ pb,
                                            const float* __restrict__ lb,
                                            ushort* __restrict__ xlb) {
    int wave = threadIdx.x >> 6, lane = threadIdx.x & 63;
    int m0 = (blockIdx.x * 4 + wave) * 16;
    if (m0 >= N_NODES) return;
    int quad = lane >> 4, ml = lane & 15;
    const ushort* arow = hbf + (size_t)(m0 + ml) * HIDDEN + quad * 8;
    bf16x8 a[4];
    #pragma unroll
    for (int kc = 0; kc < 4; kc++) a[kc] = *(const bf16x8*)(arow + kc * 32);
    #pragma unroll
    for (int nt = 0; nt < 8; nt++) {
        f32x4 acc = {0.f, 0.f, 0.f, 0.f};
        #pragma unroll
        for (int kc = 0; kc < 4; kc++) {
            bf16x8 b = *(const bf16x8*)(pb + (nt * 4 + kc) * 64 + lane);
            acc = __builtin_amdgcn_mfma_f32_16x16x32_bf16(a[kc], b, acc, 0, 0, 0);
        }
        int col = nt * 16 + ml;
        float bias = lb[col];
        #pragma unroll
        for (int r = 0; r < 4; r++) {
            int row = m0 + quad * 4 + r;
            xlb[(size_t)row * HIDDEN + col] = f2bf(acc[r] + bias);
        }
    }
}

// ---------------------------------------------------------------------------
// Aggregation + residual + LayerNorm, fused. One wave per node.
// Meta batch-loaded coalesced (64 edges per load), broadcast via readlane ->
// col/gi live in SGPRs, addresses computed scalar. Nearest table: one uint
// per lane per edge; xl: one uint. 2 fma/edge/lane.
__global__ __launch_bounds__(256) void k_agg(const ushort* __restrict__ xlb,
                                             const uint* __restrict__ meta,
                                             const int* __restrict__ offsets,
                                             const uint* __restrict__ ctab,
                                             const ushort* __restrict__ hb_in,
                                             const float* __restrict__ g,
                                             const float* __restrict__ b,
                                             ushort* __restrict__ hbf_out) {
    int wid = threadIdx.x >> 6;
    int lane = threadIdx.x & 63;
    int n = blockIdx.x * 4 + wid;
    if (n >= N_NODES) return;
    const uint* xl2 = (const uint*)xlb;    // bf16 pair per uint
    float accx = 0.f, accy = 0.f;
    int p0 = offsets[n], p1 = offsets[n + 1];
    int cnt = p1 - p0;
    for (int base = 0; base < cnt; base += 64) {
        int li = p0 + base + lane;
        uint mlv = meta[min(li, N_EDGES - 1)];   // coalesced batch load
        int kk = min(64, cnt - base);
        int k4 = kk & ~3;
        int p = 0;
        for (; p < k4; p += 4) {
            uint m0 = __builtin_amdgcn_readlane(mlv, p + 0);
            uint m1 = __builtin_amdgcn_readlane(mlv, p + 1);
            uint m2 = __builtin_amdgcn_readlane(mlv, p + 2);
            uint m3 = __builtin_amdgcn_readlane(mlv, p + 3);
            uint w0 = ctab[(m0 >> COLBITS) * 64 + lane];
            uint w1 = ctab[(m1 >> COLBITS) * 64 + lane];
            uint w2 = ctab[(m2 >> COLBITS) * 64 + lane];
            uint w3 = ctab[(m3 >> COLBITS) * 64 + lane];
            uint x0 = xl2[(m0 & ((1u << COLBITS) - 1)) * 64 + lane];
            uint x1 = xl2[(m1 & ((1u << COLBITS) - 1)) * 64 + lane];
            uint x2 = xl2[(m2 & ((1u << COLBITS) - 1)) * 64 + lane];
            uint x3 = xl2[(m3 & ((1u << COLBITS) - 1)) * 64 + lane];
            accx = fmaf(bflo(w0), bflo(x0), accx);
            accy = fmaf(bfhi(w0), bfhi(x0), accy);
            accx = fmaf(bflo(w1), bflo(x1), accx);
            accy = fmaf(bfhi(w1), bfhi(x1), accy);
            accx = fmaf(bflo(w2), bflo(x2), accx);
            accy = fmaf(bfhi(w2), bfhi(x2), accy);
            accx = fmaf(bflo(w3), bflo(x3), accx);
            accy = fmaf(bfhi(w3), bfhi(x3), accy);
        }
        for (; p < kk; p++) {
            uint m = __builtin_amdgcn_readlane(mlv, p);
            uint w = ctab[(m >> COLBITS) * 64 + lane];
            uint xv = xl2[(m & ((1u << COLBITS) - 1)) * 64 + lane];
            accx = fmaf(bflo(w), bflo(xv), accx);
            accy = fmaf(bfhi(w), bfhi(xv), accy);
        }
    }
    uint hvp = ((const uint*)hb_in)[n * 64 + lane];
    float vx = bflo(hvp) + accx, vy = bfhi(hvp) + accy;
    float s = vx + vy;
    #pragma unroll
    for (int off = 32; off; off >>= 1) s += __shfl_xor(s, off, 64);
    float mu = s * (1.0f / 128.0f);
    float dx = vx - mu, dy = vy - mu;
    float s2 = dx * dx + dy * dy;
    #pragma unroll
    for (int off = 32; off; off >>= 1) s2 += __shfl_xor(s2, off, 64);
    float rstd = rsqrtf(s2 * (1.0f / 128.0f) + 1e-5f);
    float2 gv = ((const float2*)g)[lane];
    float2 bv = ((const float2*)b)[lane];
    float ox = fmaf(dx * rstd, gv.x, bv.x);
    float oy = fmaf(dy * rstd, gv.y, bv.y);
    ((uint*)hbf_out)[n * 64 + lane] = packbf(ox, oy);
}

// ---------------------------------------------------------------------------
// Graph boundaries via binary search (batch is sorted).
__global__ void k_bounds(const int* __restrict__ batch, int* __restrict__ gstart) {
    int g = threadIdx.x;
    if (g > N_GRAPHS) return;
    int lo = 0, hi = N_NODES;
    while (lo < hi) {
        int mid = (lo + hi) >> 1;
        if (batch[mid] < g) lo = mid + 1; else hi = mid;
    }
    gstart[g] = lo;
}

// Mean pool, stage 1: PSPLIT blocks per graph write partial sums (bf16 input).
__global__ __launch_bounds__(256) void k_pool_part(const ushort* __restrict__ hbf,
                                                   const int* __restrict__ gstart,
                                                   float* __restrict__ partial) {
    int g = blockIdx.x / PSPLIT;
    int t = blockIdx.x % PSPLIT;
    int jp = threadIdx.x & 63;       // bf16-pair index (2 feats per thread)
    int half = threadIdx.x >> 6;     // 4 node-rows in flight
    int s = gstart[g], e = gstart[g + 1];
    float accx = 0.f, accy = 0.f;
    const uint* h2 = (const uint*)hbf;
    for (int n = s + t * 4 + half; n < e; n += PSPLIT * 4) {
        uint v = h2[n * 64 + jp];
        accx += bflo(v);
        accy += bfhi(v);
    }
    __shared__ float redx[256], redy[256];
    redx[threadIdx.x] = accx;
    redy[threadIdx.x] = accy;
    __syncthreads();
    if (half == 0) {
        float tx = redx[jp] + redx[jp + 64] + redx[jp + 128] + redx[jp + 192];
        float ty = redy[jp] + redy[jp + 64] + redy[jp + 128] + redy[jp + 192];
        float2 o; o.x = tx; o.y = ty;
        ((float2*)partial)[(g * PSPLIT + t) * 64 + jp] = o;
    }
}

// Mean pool, stage 2: reduce PSPLIT partials, divide by count.
__global__ void k_pool_fin(const float* __restrict__ partial,
                           const int* __restrict__ gstart,
                           float* __restrict__ out) {
    int idx = blockIdx.x * 128 + threadIdx.x;   // N_GRAPHS*HIDDEN total
    int g = idx >> 7, j = idx & 127;
    float tot = 0.f;
    #pragma unroll
    for (int t = 0; t < PSPLIT; t++) tot += partial[(g * PSPLIT + t) * HIDDEN + j];
    float c = (float)(gstart[g + 1] - gstart[g]);
    out[idx] = tot / fmaxf(c, 1.0f);
}

// ---------------------------------------------------------------------------
extern "C" void kernel_launch(void* const* d_in, const int* in_sizes, int n_in,
                              void* d_out, int out_size, void* d_ws, size_t ws_size,
                              hipStream_t stream) {
    const int* x = (const int*)d_in[0];
    const int* edge_index = (const int*)d_in[1];
    const int* row = edge_index;               // edge_index[0]
    const int* col = edge_index + N_EDGES;     // edge_index[1]
    const float* eattr = (const float*)d_in[2];
    const int* batch = (const int*)d_in[3];
    const float* emb = (const float*)d_in[4];
    const float* fw1 = (const float*)d_in[5];
    const float* fb1 = (const float*)d_in[6];
    const float* fw2 = (const float*)d_in[7];
    const float* fb2 = (const float*)d_in[8];
    const float* lw = (const float*)d_in[9];
    const float* lb = (const float*)d_in[10];
    const float* ln_g = (const float*)d_in[11];
    const float* ln_b = (const float*)d_in[12];
    float* out = (float*)d_out;

    char* ws = (char*)d_ws;
    size_t off = 0;
    auto alloc = [&](size_t bytes) -> void* {
        void* p = ws + off;
        off = (off + bytes + 255) & ~(size_t)255;
        return p;
    };
    uint* ctab     = (uint*)alloc((size_t)N_LAYERS * TAB * 64 * 4);
    ushort* hbf_a  = (ushort*)alloc((size_t)N_NODES * HIDDEN * 2);
    ushort* hbf_b  = (ushort*)alloc((size_t)N_NODES * HIDDEN * 2);
    ushort* xlb    = (ushort*)alloc((size_t)N_NODES * HIDDEN * 2);
    uint4* pb      = (uint4*)alloc((size_t)N_LAYERS * 8 * 4 * 64 * 16);
    int* counts    = (int*)alloc((size_t)(N_NODES + 1) * 4);
    int* offsets   = (int*)alloc((size_t)(N_NODES + 1) * 4);
    int* cursor    = (int*)alloc((size_t)N_NODES * 4);
    int* partial   = (int*)alloc((size_t)N_NODES * 4);
    int* blocksum  = (int*)alloc(256 * 4);
    uint* meta     = (uint*)alloc((size_t)N_EDGES * 4);
    int* gstart    = (int*)alloc((size_t)(N_GRAPHS + 1) * 4);
    float* ppart   = (float*)alloc((size_t)N_GRAPHS * PSPLIT * HIDDEN * 4);

    hipMemsetAsync(counts, 0, (size_t)(N_NODES + 1) * 4, stream);

    k_table<<<N_LAYERS * (TAB / TG), 128, 0, stream>>>(fw1, fb1, fw2, fb2, ctab);
    k_embed<<<(N_NODES * 32 + 255) / 256, 256, 0, stream>>>(x, emb, hbf_a);
    k_packw<<<(N_LAYERS * 8 * 4 * 64 + 255) / 256, 256, 0, stream>>>(lw, pb);
    k_count<<<(N_EDGES + 255) / 256, 256, 0, stream>>>(row, counts);
    const int NBLK = (N_NODES + 255) / 256;   // 196
    k_scan1<<<NBLK, 256, 0, stream>>>(counts, partial, blocksum);
    k_scan2<<<1, 256, 0, stream>>>(blocksum, NBLK);
    k_scan3<<<NBLK, 256, 0, stream>>>(partial, blocksum, offsets, cursor);
    k_fill<<<(N_EDGES + 255) / 256, 256, 0, stream>>>(row, col, eattr, cursor, meta);
    k_bounds<<<1, 128, 0, stream>>>(batch, gstart);

    ushort* hb_cur = hbf_a; ushort* hb_nxt = hbf_b;
    const int XLBLK = (N_NODES / 16 + 3) / 4;   // 3125 waves -> 782 blocks
    for (int i = 0; i < N_LAYERS; i++) {
        k_xl<<<XLBLK, 256, 0, stream>>>(hb_cur, pb + (size_t)i * 8 * 4 * 64,
                                        lb + i * HIDDEN, xlb);
        k_agg<<<(N_NODES + 3) / 4, 256, 0, stream>>>(xlb, meta, offsets,
                                                     ctab + (size_t)i * TAB * 64,
                                                     hb_cur, ln_g + i * HIDDEN,
                                                     ln_b + i * HIDDEN, hb_nxt);
        ushort* tb = hb_cur; hb_cur = hb_nxt; hb_nxt = tb;
    }
    k_pool_part<<<N_GRAPHS * PSPLIT, 256, 0, stream>>>(hb_cur, gstart, ppart);
    k_pool_fin<<<(N_GRAPHS * HIDDEN + 127) / 128, 128, 0, stream>>>(ppart, gstart, out);
}

// Round 8
// 401.651 us; speedup vs baseline: 2.7113x; 1.0424x over previous
//
#include <hip/hip_runtime.h>
#include <hip/hip_bf16.h>

#define N_NODES 50000
#define N_EDGES 640000
#define HIDDEN 128
#define N_LAYERS 4
#define NUM_RBF 50
#define CUTOFF 4.0f
#define N_GRAPHS 64
#define TAB 8192        // nearest-neighbor table (half-step 2.44e-4)
#define TG 8            // grid points per k_table block
#define PSPLIT 16       // pool blocks per graph
#define COLBITS 17      // meta packing: col in [0,2^17), gi in high bits
#define NBUCK 196       // row buckets (256 rows each)
#define CHUNK 4096      // edges per k_bucket block

typedef unsigned int uint;
typedef unsigned short ushort;
typedef __attribute__((ext_vector_type(8))) short bf16x8;   // MFMA A/B frag (4 VGPRs)
typedef __attribute__((ext_vector_type(4))) float f32x4;    // MFMA C/D frag

__device__ inline ushort f2bf(float f) {   // RNE float->bf16 (finite inputs)
    uint u = __float_as_uint(f);
    uint r = (u + 0x7fffu + ((u >> 16) & 1u)) >> 16;
    return (ushort)r;
}
__device__ inline uint packbf(float lo, float hi) {
    return (uint)f2bf(lo) | ((uint)f2bf(hi) << 16);
}
__device__ inline float bflo(uint u) { return __uint_as_float(u << 16); }
__device__ inline float bfhi(uint u) { return __uint_as_float(u & 0xffff0000u); }

// ---------------------------------------------------------------------------
// Nearest-neighbor filter table: row g = 64 uints (256B), bf16 pair per lane.
__global__ __launch_bounds__(128) void k_table(const float* __restrict__ fw1,
                                               const float* __restrict__ fb1,
                                               const float* __restrict__ fw2,
                                               const float* __restrict__ fb2,
                                               uint* __restrict__ ctab) {
    int bid = blockIdx.x;
    int layer = bid / (TAB / TG);
    int g0 = (bid % (TAB / TG)) * TG;
    int j = threadIdx.x;
    __shared__ float rbf[TG][NUM_RBF];
    __shared__ float wout[TG][HIDDEN];
    __shared__ float hid[TG][HIDDEN];
    for (int idx = j; idx < TG * NUM_RBF; idx += 128) {
        int gg = idx / NUM_RBF, r = idx % NUM_RBF;
        float d = (CUTOFF * (g0 + gg)) / (float)(TAB - 1);
        float offset = (CUTOFF * r) / (float)(NUM_RBF - 1);
        float delta = CUTOFF / (float)(NUM_RBF - 1);
        float coeff = -0.5f / (delta * delta);
        float t = d - offset;
        rbf[gg][r] = expf(coeff * t * t);
    }
    __syncthreads();
    const float* w1 = fw1 + layer * NUM_RBF * HIDDEN;
    float b1 = fb1[layer * HIDDEN + j];
    float acc[TG];
    #pragma unroll
    for (int gg = 0; gg < TG; gg++) acc[gg] = b1;
    for (int r = 0; r < NUM_RBF; r++) {
        float w = w1[r * HIDDEN + j];
        #pragma unroll
        for (int gg = 0; gg < TG; gg++) acc[gg] = fmaf(rbf[gg][r], w, acc[gg]);
    }
    #pragma unroll
    for (int gg = 0; gg < TG; gg++) hid[gg][j] = fmaxf(acc[gg], 0.0f);
    __syncthreads();
    const float* w2 = fw2 + layer * HIDDEN * HIDDEN;
    float b2 = fb2[layer * HIDDEN + j];
    float acc2[TG];
    #pragma unroll
    for (int gg = 0; gg < TG; gg++) acc2[gg] = b2;
    for (int k = 0; k < HIDDEN; k += 4) {
        float w0 = w2[(k + 0) * HIDDEN + j];
        float w1v = w2[(k + 1) * HIDDEN + j];
        float w2v = w2[(k + 2) * HIDDEN + j];
        float w3 = w2[(k + 3) * HIDDEN + j];
        #pragma unroll
        for (int gg = 0; gg < TG; gg++) {
            acc2[gg] = fmaf(hid[gg][k + 0], w0, acc2[gg]);
            acc2[gg] = fmaf(hid[gg][k + 1], w1v, acc2[gg]);
            acc2[gg] = fmaf(hid[gg][k + 2], w2v, acc2[gg]);
            acc2[gg] = fmaf(hid[gg][k + 3], w3, acc2[gg]);
        }
    }
    #pragma unroll
    for (int gg = 0; gg < TG; gg++) wout[gg][j] = acc2[gg];
    __syncthreads();
    for (int idx = j; idx < TG * 64; idx += 128) {
        int gg = idx >> 6, jp = idx & 63;
        ctab[((size_t)layer * TAB + g0 + gg) * 64 + jp] =
            packbf(wout[gg][2 * jp], wout[gg][2 * jp + 1]);
    }
}

// ---------------------------------------------------------------------------
// Embedding gather: hbf[n][:] = bf16(emb[x[n]][:])
__global__ void k_embed(const int* __restrict__ x, const float* __restrict__ emb,
                        ushort* __restrict__ hbf) {
    int idx = blockIdx.x * 256 + threadIdx.x;   // over N_NODES*32 float4s
    if (idx >= N_NODES * 32) return;
    int n = idx >> 5, q = idx & 31;
    float4 v = ((const float4*)emb)[x[n] * 32 + q];
    uint2 p;
    p.x = packbf(v.x, v.y);
    p.y = packbf(v.z, v.w);
    ((uint2*)hbf)[idx] = p;
}

// ---------------------------------------------------------------------------
// Pack lw into B-fragment order for mfma_f32_16x16x32_bf16.
__global__ void k_packw(const float* __restrict__ lw, uint4* __restrict__ pb) {
    int idx = blockIdx.x * 256 + threadIdx.x;   // N_LAYERS*8*4*64 = 8192
    if (idx >= N_LAYERS * 8 * 4 * 64) return;
    int lane = idx & 63;
    int kc = (idx >> 6) & 3;
    int nt = (idx >> 8) & 7;
    int layer = idx >> 11;
    int quad = lane >> 4, nl = lane & 15;
    int n = nt * 16 + nl;
    const float* w = lw + layer * HIDDEN * HIDDEN;
    uint r[4];
    #pragma unroll
    for (int jj = 0; jj < 4; jj++) {
        int k = kc * 32 + quad * 8 + 2 * jj;
        r[jj] = packbf(w[k * HIDDEN + n], w[(k + 1) * HIDDEN + n]);
    }
    uint4 o; o.x = r[0]; o.y = r[1]; o.z = r[2]; o.w = r[3];
    pb[idx] = o;
}

// ---------------------------------------------------------------------------
// CSR build. row is ~uniform-random -> low contention.
__global__ void k_count(const int* __restrict__ row, int* __restrict__ counts) {
    int e = blockIdx.x * 256 + threadIdx.x;
    if (e < N_EDGES) atomicAdd(&counts[row[e]], 1);
}

__global__ void k_scan1(const int* __restrict__ counts, int* __restrict__ partial,
                        int* __restrict__ blocksum) {
    int i = blockIdx.x * 256 + threadIdx.x;
    int v = (i < N_NODES) ? counts[i] : 0;
    int lane = threadIdx.x & 63;
    int wid = threadIdx.x >> 6;
    int s = v;
    #pragma unroll
    for (int off = 1; off < 64; off <<= 1) {
        int t = __shfl_up(s, off, 64);
        if (lane >= off) s += t;
    }
    __shared__ int wsum[4];
    if (lane == 63) wsum[wid] = s;
    __syncthreads();
    int woff = 0;
    for (int w = 0; w < wid; w++) woff += wsum[w];
    int incl = s + woff;
    if (i < N_NODES) partial[i] = incl - v;           // exclusive within block
    if (threadIdx.x == 255) blocksum[blockIdx.x] = incl;
}

__global__ void k_scan2(int* __restrict__ blocksum, int nblk) {
    int tid = threadIdx.x;
    int v = (tid < nblk) ? blocksum[tid] : 0;
    int lane = tid & 63, wid = tid >> 6;
    int s = v;
    #pragma unroll
    for (int off = 1; off < 64; off <<= 1) {
        int t = __shfl_up(s, off, 64);
        if (lane >= off) s += t;
    }
    __shared__ int wsum[4];
    if (lane == 63) wsum[wid] = s;
    __syncthreads();
    int woff = 0;
    for (int w = 0; w < wid; w++) woff += wsum[w];
    int incl = s + woff;
    if (tid < nblk) blocksum[tid] = incl - v;         // exclusive
}

// Writes offsets; also seeds bucket cursors at bucket row boundaries.
__global__ void k_scan3(const int* __restrict__ partial, const int* __restrict__ blocksum,
                        int* __restrict__ offsets, int* __restrict__ bcur) {
    int i = blockIdx.x * 256 + threadIdx.x;
    if (i < N_NODES) {
        int o = partial[i] + blocksum[blockIdx.x];
        offsets[i] = o;
        if ((i & 255) == 0) bcur[i >> 8] = o;
    }
    if (i == 0) offsets[N_NODES] = N_EDGES;
}

// ---------------------------------------------------------------------------
// Bucket sort pass: chunk of CHUNK edges -> LDS histogram/scan/stage ->
// coalesced run writes into per-bucket global spans (8B: packed meta + row).
// Kills the 16x write amplification of the naive CSR scatter.
__global__ __launch_bounds__(256) void k_bucket(const int* __restrict__ row,
                                                const int* __restrict__ col,
                                                const float* __restrict__ eattr,
                                                int* __restrict__ bcur,
                                                uint2* __restrict__ bs) {
    __shared__ uint2 stage[CHUNK];
    __shared__ int hist[256], lscan[256], lcur[256], gbase[256];
    __shared__ int wsum[4];
    int t = threadIdx.x;
    int e0 = blockIdx.x * CHUNK;
    int ne = min(CHUNK, N_EDGES - e0);
    hist[t] = 0;
    __syncthreads();
    for (int i = t; i < ne; i += 256)
        atomicAdd(&hist[row[e0 + i] >> 8], 1);
    __syncthreads();
    // block-wide exclusive scan of hist
    int v = hist[t];
    int lane = t & 63, wid = t >> 6;
    int s = v;
    #pragma unroll
    for (int off = 1; off < 64; off <<= 1) {
        int u = __shfl_up(s, off, 64);
        if (lane >= off) s += u;
    }
    if (lane == 63) wsum[wid] = s;
    __syncthreads();
    int woff = 0;
    for (int w = 0; w < wid; w++) woff += wsum[w];
    int excl = s + woff - v;
    lscan[t] = excl;
    lcur[t] = excl;
    if (v > 0) gbase[t] = atomicAdd(&bcur[t], v);   // reserve span in bucket
    __syncthreads();
    for (int i = t; i < ne; i += 256) {
        int e = e0 + i;
        int r = row[e];
        float tt = eattr[e] * ((float)(TAB - 1) / CUTOFF);
        int gi = (int)(tt + 0.5f);
        gi = min(max(gi, 0), TAB - 1);
        int pos = atomicAdd(&lcur[r >> 8], 1);
        uint2 sv;
        sv.x = (uint)col[e] | ((uint)gi << COLBITS);
        sv.y = (uint)r;
        stage[pos] = sv;
    }
    __syncthreads();
    for (int i = t; i < ne; i += 256) {
        uint2 sv = stage[i];
        int b = sv.y >> 8;
        bs[gbase[b] + (i - lscan[b])] = sv;   // coalesced run writes
    }
}

// Fine scatter within each bucket's <=13KB meta window: single-writer block ->
// lines assemble in one XCD's L2 before eviction (no amplification).
__global__ __launch_bounds__(256) void k_scatter(const uint2* __restrict__ bs,
                                                 const int* __restrict__ offsets,
                                                 uint* __restrict__ meta) {
    int b = blockIdx.x, t = threadIdx.x;
    int r0 = b << 8;
    __shared__ int cur[256];
    int rmax = min(r0 + 256, N_NODES);
    cur[t] = offsets[min(r0 + t, N_NODES)];
    __syncthreads();
    int s = offsets[r0], e = offsets[rmax];
    for (int i = s + t; i < e; i += 256) {
        uint2 v = bs[i];
        int slot = atomicAdd(&cur[v.y - r0], 1);
        meta[slot] = v.x;
    }
}

// ---------------------------------------------------------------------------
// xl = h @ lw + lb via bf16 MFMA. One wave = 16 rows x 128 cols.
__global__ __launch_bounds__(256) void k_xl(const ushort* __restrict__ hbf,
                                            const uint4* __restrict__ pb,
                                            const float* __restrict__ lb,
                                            ushort* __restrict__ xlb) {
    int wave = threadIdx.x >> 6, lane = threadIdx.x & 63;
    int m0 = (blockIdx.x * 4 + wave) * 16;
    if (m0 >= N_NODES) return;
    int quad = lane >> 4, ml = lane & 15;
    const ushort* arow = hbf + (size_t)(m0 + ml) * HIDDEN + quad * 8;
    bf16x8 a[4];
    #pragma unroll
    for (int kc = 0; kc < 4; kc++) a[kc] = *(const bf16x8*)(arow + kc * 32);
    #pragma unroll
    for (int nt = 0; nt < 8; nt++) {
        f32x4 acc = {0.f, 0.f, 0.f, 0.f};
        #pragma unroll
        for (int kc = 0; kc < 4; kc++) {
            bf16x8 b = *(const bf16x8*)(pb + (nt * 4 + kc) * 64 + lane);
            acc = __builtin_amdgcn_mfma_f32_16x16x32_bf16(a[kc], b, acc, 0, 0, 0);
        }
        int col = nt * 16 + ml;
        float bias = lb[col];
        #pragma unroll
        for (int r = 0; r < 4; r++) {
            int row = m0 + quad * 4 + r;
            xlb[(size_t)row * HIDDEN + col] = f2bf(acc[r] + bias);
        }
    }
}

// ---------------------------------------------------------------------------
// Aggregation + residual + LayerNorm, fused. One wave per node.
// Meta batch-loaded coalesced; readlane broadcasts -> scalar addressing.
__global__ __launch_bounds__(256) void k_agg(const ushort* __restrict__ xlb,
                                             const uint* __restrict__ meta,
                                             const int* __restrict__ offsets,
                                             const uint* __restrict__ ctab,
                                             const ushort* __restrict__ hb_in,
                                             const float* __restrict__ g,
                                             const float* __restrict__ b,
                                             ushort* __restrict__ hbf_out) {
    int wid = threadIdx.x >> 6;
    int lane = threadIdx.x & 63;
    int n = blockIdx.x * 4 + wid;
    if (n >= N_NODES) return;
    const uint* xl2 = (const uint*)xlb;    // bf16 pair per uint
    float accx = 0.f, accy = 0.f;
    int p0 = offsets[n], p1 = offsets[n + 1];
    int cnt = p1 - p0;
    for (int base = 0; base < cnt; base += 64) {
        int li = p0 + base + lane;
        uint mlv = meta[min(li, N_EDGES - 1)];   // coalesced batch load
        int kk = min(64, cnt - base);
        int k4 = kk & ~3;
        int p = 0;
        for (; p < k4; p += 4) {
            uint m0 = __builtin_amdgcn_readlane(mlv, p + 0);
            uint m1 = __builtin_amdgcn_readlane(mlv, p + 1);
            uint m2 = __builtin_amdgcn_readlane(mlv, p + 2);
            uint m3 = __builtin_amdgcn_readlane(mlv, p + 3);
            uint w0 = ctab[(m0 >> COLBITS) * 64 + lane];
            uint w1 = ctab[(m1 >> COLBITS) * 64 + lane];
            uint w2 = ctab[(m2 >> COLBITS) * 64 + lane];
            uint w3 = ctab[(m3 >> COLBITS) * 64 + lane];
            uint x0 = xl2[(m0 & ((1u << COLBITS) - 1)) * 64 + lane];
            uint x1 = xl2[(m1 & ((1u << COLBITS) - 1)) * 64 + lane];
            uint x2 = xl2[(m2 & ((1u << COLBITS) - 1)) * 64 + lane];
            uint x3 = xl2[(m3 & ((1u << COLBITS) - 1)) * 64 + lane];
            accx = fmaf(bflo(w0), bflo(x0), accx);
            accy = fmaf(bfhi(w0), bfhi(x0), accy);
            accx = fmaf(bflo(w1), bflo(x1), accx);
            accy = fmaf(bfhi(w1), bfhi(x1), accy);
            accx = fmaf(bflo(w2), bflo(x2), accx);
            accy = fmaf(bfhi(w2), bfhi(x2), accy);
            accx = fmaf(bflo(w3), bflo(x3), accx);
            accy = fmaf(bfhi(w3), bfhi(x3), accy);
        }
        for (; p < kk; p++) {
            uint m = __builtin_amdgcn_readlane(mlv, p);
            uint w = ctab[(m >> COLBITS) * 64 + lane];
            uint xv = xl2[(m & ((1u << COLBITS) - 1)) * 64 + lane];
            accx = fmaf(bflo(w), bflo(xv), accx);
            accy = fmaf(bfhi(w), bfhi(xv), accy);
        }
    }
    uint hvp = ((const uint*)hb_in)[n * 64 + lane];
    float vx = bflo(hvp) + accx, vy = bfhi(hvp) + accy;
    float s = vx + vy;
    #pragma unroll
    for (int off = 32; off; off >>= 1) s += __shfl_xor(s, off, 64);
    float mu = s * (1.0f / 128.0f);
    float dx = vx - mu, dy = vy - mu;
    float s2 = dx * dx + dy * dy;
    #pragma unroll
    for (int off = 32; off; off >>= 1) s2 += __shfl_xor(s2, off, 64);
    float rstd = rsqrtf(s2 * (1.0f / 128.0f) + 1e-5f);
    float2 gv = ((const float2*)g)[lane];
    float2 bv = ((const float2*)b)[lane];
    float ox = fmaf(dx * rstd, gv.x, bv.x);
    float oy = fmaf(dy * rstd, gv.y, bv.y);
    ((uint*)hbf_out)[n * 64 + lane] = packbf(ox, oy);
}

// ---------------------------------------------------------------------------
// Graph boundaries via binary search (batch is sorted).
__global__ void k_bounds(const int* __restrict__ batch, int* __restrict__ gstart) {
    int g = threadIdx.x;
    if (g > N_GRAPHS) return;
    int lo = 0, hi = N_NODES;
    while (lo < hi) {
        int mid = (lo + hi) >> 1;
        if (batch[mid] < g) lo = mid + 1; else hi = mid;
    }
    gstart[g] = lo;
}

// Mean pool, stage 1: PSPLIT blocks per graph write partial sums (bf16 input).
__global__ __launch_bounds__(256) void k_pool_part(const ushort* __restrict__ hbf,
                                                   const int* __restrict__ gstart,
                                                   float* __restrict__ partial) {
    int g = blockIdx.x / PSPLIT;
    int t = blockIdx.x % PSPLIT;
    int jp = threadIdx.x & 63;       // bf16-pair index (2 feats per thread)
    int half = threadIdx.x >> 6;     // 4 node-rows in flight
    int s = gstart[g], e = gstart[g + 1];
    float accx = 0.f, accy = 0.f;
    const uint* h2 = (const uint*)hbf;
    for (int n = s + t * 4 + half; n < e; n += PSPLIT * 4) {
        uint v = h2[n * 64 + jp];
        accx += bflo(v);
        accy += bfhi(v);
    }
    __shared__ float redx[256], redy[256];
    redx[threadIdx.x] = accx;
    redy[threadIdx.x] = accy;
    __syncthreads();
    if (half == 0) {
        float tx = redx[jp] + redx[jp + 64] + redx[jp + 128] + redx[jp + 192];
        float ty = redy[jp] + redy[jp + 64] + redy[jp + 128] + redy[jp + 192];
        float2 o; o.x = tx; o.y = ty;
        ((float2*)partial)[(g * PSPLIT + t) * 64 + jp] = o;
    }
}

// Mean pool, stage 2: reduce PSPLIT partials, divide by count.
__global__ void k_pool_fin(const float* __restrict__ partial,
                           const int* __restrict__ gstart,
                           float* __restrict__ out) {
    int idx = blockIdx.x * 128 + threadIdx.x;   // N_GRAPHS*HIDDEN total
    int g = idx >> 7, j = idx & 127;
    float tot = 0.f;
    #pragma unroll
    for (int t = 0; t < PSPLIT; t++) tot += partial[(g * PSPLIT + t) * HIDDEN + j];
    float c = (float)(gstart[g + 1] - gstart[g]);
    out[idx] = tot / fmaxf(c, 1.0f);
}

// ---------------------------------------------------------------------------
extern "C" void kernel_launch(void* const* d_in, const int* in_sizes, int n_in,
                              void* d_out, int out_size, void* d_ws, size_t ws_size,
                              hipStream_t stream) {
    const int* x = (const int*)d_in[0];
    const int* edge_index = (const int*)d_in[1];
    const int* row = edge_index;               // edge_index[0]
    const int* col = edge_index + N_EDGES;     // edge_index[1]
    const float* eattr = (const float*)d_in[2];
    const int* batch = (const int*)d_in[3];
    const float* emb = (const float*)d_in[4];
    const float* fw1 = (const float*)d_in[5];
    const float* fb1 = (const float*)d_in[6];
    const float* fw2 = (const float*)d_in[7];
    const float* fb2 = (const float*)d_in[8];
    const float* lw = (const float*)d_in[9];
    const float* lb = (const float*)d_in[10];
    const float* ln_g = (const float*)d_in[11];
    const float* ln_b = (const float*)d_in[12];
    float* out = (float*)d_out;

    char* ws = (char*)d_ws;
    size_t off = 0;
    auto alloc = [&](size_t bytes) -> void* {
        void* p = ws + off;
        off = (off + bytes + 255) & ~(size_t)255;
        return p;
    };
    uint* ctab     = (uint*)alloc((size_t)N_LAYERS * TAB * 64 * 4);
    ushort* hbf_a  = (ushort*)alloc((size_t)N_NODES * HIDDEN * 2);
    ushort* hbf_b  = (ushort*)alloc((size_t)N_NODES * HIDDEN * 2);
    ushort* xlb    = (ushort*)alloc((size_t)N_NODES * HIDDEN * 2);
    uint4* pb      = (uint4*)alloc((size_t)N_LAYERS * 8 * 4 * 64 * 16);
    int* counts    = (int*)alloc((size_t)(N_NODES + 1) * 4);
    int* offsets   = (int*)alloc((size_t)(N_NODES + 1) * 4);
    int* partial   = (int*)alloc((size_t)N_NODES * 4);
    int* blocksum  = (int*)alloc(256 * 4);
    int* bcur      = (int*)alloc(256 * 4);
    uint2* bs      = (uint2*)alloc((size_t)N_EDGES * 8);
    uint* meta     = (uint*)alloc((size_t)N_EDGES * 4);
    int* gstart    = (int*)alloc((size_t)(N_GRAPHS + 1) * 4);
    float* ppart   = (float*)alloc((size_t)N_GRAPHS * PSPLIT * HIDDEN * 4);

    hipMemsetAsync(counts, 0, (size_t)(N_NODES + 1) * 4, stream);

    k_table<<<N_LAYERS * (TAB / TG), 128, 0, stream>>>(fw1, fb1, fw2, fb2, ctab);
    k_embed<<<(N_NODES * 32 + 255) / 256, 256, 0, stream>>>(x, emb, hbf_a);
    k_packw<<<(N_LAYERS * 8 * 4 * 64 + 255) / 256, 256, 0, stream>>>(lw, pb);
    k_count<<<(N_EDGES + 255) / 256, 256, 0, stream>>>(row, counts);
    const int NBLK = (N_NODES + 255) / 256;   // 196
    k_scan1<<<NBLK, 256, 0, stream>>>(counts, partial, blocksum);
    k_scan2<<<1, 256, 0, stream>>>(blocksum, NBLK);
    k_scan3<<<NBLK, 256, 0, stream>>>(partial, blocksum, offsets, bcur);
    k_bucket<<<(N_EDGES + CHUNK - 1) / CHUNK, 256, 0, stream>>>(row, col, eattr, bcur, bs);
    k_scatter<<<NBUCK, 256, 0, stream>>>(bs, offsets, meta);
    k_bounds<<<1, 128, 0, stream>>>(batch, gstart);

    ushort* hb_cur = hbf_a; ushort* hb_nxt = hbf_b;
    const int XLBLK = (N_NODES / 16 + 3) / 4;   // 3125 waves -> 782 blocks
    for (int i = 0; i < N_LAYERS; i++) {
        k_xl<<<XLBLK, 256, 0, stream>>>(hb_cur, pb + (size_t)i * 8 * 4 * 64,
                                        lb + i * HIDDEN, xlb);
        k_agg<<<(N_NODES + 3) / 4, 256, 0, stream>>>(xlb, meta, offsets,
                                                     ctab + (size_t)i * TAB * 64,
                                                     hb_cur, ln_g + i * HIDDEN,
                                                     ln_b + i * HIDDEN, hb_nxt);
        ushort* tb = hb_cur; hb_cur = hb_nxt; hb_nxt = tb;
    }
    k_pool_part<<<N_GRAPHS * PSPLIT, 256, 0, stream>>>(hb_cur, gstart, ppart);
    k_pool_fin<<<(N_GRAPHS * HIDDEN + 127) / 128, 128, 0, stream>>>(ppart, gstart, out);
}

// Round 9
// 384.295 us; speedup vs baseline: 2.8338x; 1.0452x over previous
//
#include <hip/hip_runtime.h>
#include <hip/hip_bf16.h>

#define N_NODES 50000
#define N_EDGES 640000
#define HIDDEN 128
#define N_LAYERS 4
#define NUM_RBF 50
#define CUTOFF 4.0f
#define N_GRAPHS 64
#define TAB 8192        // nearest-neighbor table (half-step 2.44e-4)
#define TG 8            // grid points per k_tab1 block
#define PSPLIT 16       // pool blocks per graph
#define COLBITS 17      // meta packing: col in [0,2^17), gi in high bits
#define NBUCK 196       // row buckets (256 rows each)
#define CHUNK 4096      // edges per k_bucket block

typedef unsigned int uint;
typedef unsigned short ushort;
typedef __attribute__((ext_vector_type(8))) short bf16x8;   // MFMA A/B frag (4 VGPRs)
typedef __attribute__((ext_vector_type(4))) float f32x4;    // MFMA C/D frag

__device__ inline ushort f2bf(float f) {   // RNE float->bf16 (finite inputs)
    uint u = __float_as_uint(f);
    uint r = (u + 0x7fffu + ((u >> 16) & 1u)) >> 16;
    return (ushort)r;
}
__device__ inline uint packbf(float lo, float hi) {
    return (uint)f2bf(lo) | ((uint)f2bf(hi) << 16);
}
__device__ inline float bflo(uint u) { return __uint_as_float(u << 16); }
__device__ inline float bfhi(uint u) { return __uint_as_float(u & 0xffff0000u); }

// ---------------------------------------------------------------------------
// Table stage 1: hidbf[(layer*TAB+g)][j] = bf16(relu(rbf(g) . fw1[:,j] + fb1[j]))
__global__ __launch_bounds__(128) void k_tab1(const float* __restrict__ fw1,
                                              const float* __restrict__ fb1,
                                              ushort* __restrict__ hidbf) {
    int bid = blockIdx.x;
    int layer = bid / (TAB / TG);
    int g0 = (bid % (TAB / TG)) * TG;
    int j = threadIdx.x;
    __shared__ float rbf[TG][NUM_RBF];
    for (int idx = j; idx < TG * NUM_RBF; idx += 128) {
        int gg = idx / NUM_RBF, r = idx % NUM_RBF;
        float d = (CUTOFF * (g0 + gg)) / (float)(TAB - 1);
        float offset = (CUTOFF * r) / (float)(NUM_RBF - 1);
        float delta = CUTOFF / (float)(NUM_RBF - 1);
        float coeff = -0.5f / (delta * delta);
        float t = d - offset;
        rbf[gg][r] = expf(coeff * t * t);
    }
    __syncthreads();
    const float* w1 = fw1 + layer * NUM_RBF * HIDDEN;
    float b1 = fb1[layer * HIDDEN + j];
    float acc[TG];
    #pragma unroll
    for (int gg = 0; gg < TG; gg++) acc[gg] = b1;
    for (int r = 0; r < NUM_RBF; r++) {
        float w = w1[r * HIDDEN + j];
        #pragma unroll
        for (int gg = 0; gg < TG; gg++) acc[gg] = fmaf(rbf[gg][r], w, acc[gg]);
    }
    #pragma unroll
    for (int gg = 0; gg < TG; gg++)
        hidbf[((size_t)layer * TAB + g0 + gg) * HIDDEN + j] = f2bf(fmaxf(acc[gg], 0.0f));
}

// ---------------------------------------------------------------------------
// Table stage 2 via MFMA: ctab_rows = hidbf @ fw2 + fb2, stored as bf16 rows.
// Row = grid point (layer-major), col = channel. One wave = 16 rows.
__global__ __launch_bounds__(256) void k_tab2(const ushort* __restrict__ hidbf,
                                              const uint4* __restrict__ pb2,
                                              const float* __restrict__ fb2,
                                              ushort* __restrict__ ctab) {
    int wave = threadIdx.x >> 6, lane = threadIdx.x & 63;
    int m0 = (blockIdx.x * 4 + wave) * 16;          // global row (layer*TAB+g)
    int layer = m0 / TAB;
    int quad = lane >> 4, ml = lane & 15;
    const ushort* arow = hidbf + (size_t)(m0 + ml) * HIDDEN + quad * 8;
    bf16x8 a[4];
    #pragma unroll
    for (int kc = 0; kc < 4; kc++) a[kc] = *(const bf16x8*)(arow + kc * 32);
    const uint4* pb = pb2 + (size_t)layer * 8 * 4 * 64;
    const float* bias = fb2 + layer * HIDDEN;
    #pragma unroll
    for (int nt = 0; nt < 8; nt++) {
        f32x4 acc = {0.f, 0.f, 0.f, 0.f};
        #pragma unroll
        for (int kc = 0; kc < 4; kc++) {
            bf16x8 b = *(const bf16x8*)(pb + (nt * 4 + kc) * 64 + lane);
            acc = __builtin_amdgcn_mfma_f32_16x16x32_bf16(a[kc], b, acc, 0, 0, 0);
        }
        int col = nt * 16 + ml;
        float bv = bias[col];
        #pragma unroll
        for (int r = 0; r < 4; r++) {
            int row = m0 + quad * 4 + r;
            ctab[(size_t)row * HIDDEN + col] = f2bf(acc[r] + bv);
        }
    }
}

// ---------------------------------------------------------------------------
// Embedding gather: hbf[n][:] = bf16(emb[x[n]][:])
__global__ void k_embed(const int* __restrict__ x, const float* __restrict__ emb,
                        ushort* __restrict__ hbf) {
    int idx = blockIdx.x * 256 + threadIdx.x;   // over N_NODES*32 float4s
    if (idx >= N_NODES * 32) return;
    int n = idx >> 5, q = idx & 31;
    float4 v = ((const float4*)emb)[x[n] * 32 + q];
    uint2 p;
    p.x = packbf(v.x, v.y);
    p.y = packbf(v.z, v.w);
    ((uint2*)hbf)[idx] = p;
}

// ---------------------------------------------------------------------------
// Pack a [N_LAYERS][128][128] row-major weight into B-fragment order for
// mfma_f32_16x16x32_bf16 (generic: used for lw and fw2).
__global__ void k_packw(const float* __restrict__ w_in, uint4* __restrict__ pb) {
    int idx = blockIdx.x * 256 + threadIdx.x;   // N_LAYERS*8*4*64 = 8192
    if (idx >= N_LAYERS * 8 * 4 * 64) return;
    int lane = idx & 63;
    int kc = (idx >> 6) & 3;
    int nt = (idx >> 8) & 7;
    int layer = idx >> 11;
    int quad = lane >> 4, nl = lane & 15;
    int n = nt * 16 + nl;
    const float* w = w_in + layer * HIDDEN * HIDDEN;
    uint r[4];
    #pragma unroll
    for (int jj = 0; jj < 4; jj++) {
        int k = kc * 32 + quad * 8 + 2 * jj;
        r[jj] = packbf(w[k * HIDDEN + n], w[(k + 1) * HIDDEN + n]);
    }
    uint4 o; o.x = r[0]; o.y = r[1]; o.z = r[2]; o.w = r[3];
    pb[idx] = o;
}

// ---------------------------------------------------------------------------
// CSR build. row is ~uniform-random -> low contention.
__global__ void k_count(const int* __restrict__ row, int* __restrict__ counts) {
    int e = blockIdx.x * 256 + threadIdx.x;
    if (e < N_EDGES) atomicAdd(&counts[row[e]], 1);
}

__global__ void k_scan1(const int* __restrict__ counts, int* __restrict__ partial,
                        int* __restrict__ blocksum) {
    int i = blockIdx.x * 256 + threadIdx.x;
    int v = (i < N_NODES) ? counts[i] : 0;
    int lane = threadIdx.x & 63;
    int wid = threadIdx.x >> 6;
    int s = v;
    #pragma unroll
    for (int off = 1; off < 64; off <<= 1) {
        int t = __shfl_up(s, off, 64);
        if (lane >= off) s += t;
    }
    __shared__ int wsum[4];
    if (lane == 63) wsum[wid] = s;
    __syncthreads();
    int woff = 0;
    for (int w = 0; w < wid; w++) woff += wsum[w];
    int incl = s + woff;
    if (i < N_NODES) partial[i] = incl - v;           // exclusive within block
    if (threadIdx.x == 255) blocksum[blockIdx.x] = incl;
}

__global__ void k_scan2(int* __restrict__ blocksum, int nblk) {
    int tid = threadIdx.x;
    int v = (tid < nblk) ? blocksum[tid] : 0;
    int lane = tid & 63, wid = tid >> 6;
    int s = v;
    #pragma unroll
    for (int off = 1; off < 64; off <<= 1) {
        int t = __shfl_up(s, off, 64);
        if (lane >= off) s += t;
    }
    __shared__ int wsum[4];
    if (lane == 63) wsum[wid] = s;
    __syncthreads();
    int woff = 0;
    for (int w = 0; w < wid; w++) woff += wsum[w];
    int incl = s + woff;
    if (tid < nblk) blocksum[tid] = incl - v;         // exclusive
}

// Writes offsets; also seeds bucket cursors at bucket row boundaries.
__global__ void k_scan3(const int* __restrict__ partial, const int* __restrict__ blocksum,
                        int* __restrict__ offsets, int* __restrict__ bcur) {
    int i = blockIdx.x * 256 + threadIdx.x;
    if (i < N_NODES) {
        int o = partial[i] + blocksum[blockIdx.x];
        offsets[i] = o;
        if ((i & 255) == 0) bcur[i >> 8] = o;
    }
    if (i == 0) offsets[N_NODES] = N_EDGES;
}

// ---------------------------------------------------------------------------
// Bucket sort pass: chunk of CHUNK edges -> LDS histogram/scan/stage ->
// coalesced run writes into per-bucket global spans (8B: packed meta + row).
__global__ __launch_bounds__(256) void k_bucket(const int* __restrict__ row,
                                                const int* __restrict__ col,
                                                const float* __restrict__ eattr,
                                                int* __restrict__ bcur,
                                                uint2* __restrict__ bs) {
    __shared__ uint2 stage[CHUNK];
    __shared__ int hist[256], lscan[256], lcur[256], gbase[256];
    __shared__ int wsum[4];
    int t = threadIdx.x;
    int e0 = blockIdx.x * CHUNK;
    int ne = min(CHUNK, N_EDGES - e0);
    hist[t] = 0;
    __syncthreads();
    for (int i = t; i < ne; i += 256)
        atomicAdd(&hist[row[e0 + i] >> 8], 1);
    __syncthreads();
    int v = hist[t];
    int lane = t & 63, wid = t >> 6;
    int s = v;
    #pragma unroll
    for (int off = 1; off < 64; off <<= 1) {
        int u = __shfl_up(s, off, 64);
        if (lane >= off) s += u;
    }
    if (lane == 63) wsum[wid] = s;
    __syncthreads();
    int woff = 0;
    for (int w = 0; w < wid; w++) woff += wsum[w];
    int excl = s + woff - v;
    lscan[t] = excl;
    lcur[t] = excl;
    if (v > 0) gbase[t] = atomicAdd(&bcur[t], v);   // reserve span in bucket
    __syncthreads();
    for (int i = t; i < ne; i += 256) {
        int e = e0 + i;
        int r = row[e];
        float tt = eattr[e] * ((float)(TAB - 1) / CUTOFF);
        int gi = (int)(tt + 0.5f);
        gi = min(max(gi, 0), TAB - 1);
        int pos = atomicAdd(&lcur[r >> 8], 1);
        uint2 sv;
        sv.x = (uint)col[e] | ((uint)gi << COLBITS);
        sv.y = (uint)r;
        stage[pos] = sv;
    }
    __syncthreads();
    for (int i = t; i < ne; i += 256) {
        uint2 sv = stage[i];
        int b = sv.y >> 8;
        bs[gbase[b] + (i - lscan[b])] = sv;   // coalesced run writes
    }
}

// Fine scatter within each bucket's <=13KB meta window: single-writer block.
__global__ __launch_bounds__(256) void k_scatter(const uint2* __restrict__ bs,
                                                 const int* __restrict__ offsets,
                                                 uint* __restrict__ meta) {
    int b = blockIdx.x, t = threadIdx.x;
    int r0 = b << 8;
    __shared__ int cur[256];
    int rmax = min(r0 + 256, N_NODES);
    cur[t] = offsets[min(r0 + t, N_NODES)];
    __syncthreads();
    int s = offsets[r0], e = offsets[rmax];
    for (int i = s + t; i < e; i += 256) {
        uint2 v = bs[i];
        int slot = atomicAdd(&cur[v.y - r0], 1);
        meta[slot] = v.x;
    }
}

// ---------------------------------------------------------------------------
// xl = h @ lw + lb via bf16 MFMA. One wave = 16 rows x 128 cols.
__global__ __launch_bounds__(256) void k_xl(const ushort* __restrict__ hbf,
                                            const uint4* __restrict__ pb,
                                            const float* __restrict__ lb,
                                            ushort* __restrict__ xlb) {
    int wave = threadIdx.x >> 6, lane = threadIdx.x & 63;
    int m0 = (blockIdx.x * 4 + wave) * 16;
    if (m0 >= N_NODES) return;
    int quad = lane >> 4, ml = lane & 15;
    const ushort* arow = hbf + (size_t)(m0 + ml) * HIDDEN + quad * 8;
    bf16x8 a[4];
    #pragma unroll
    for (int kc = 0; kc < 4; kc++) a[kc] = *(const bf16x8*)(arow + kc * 32);
    #pragma unroll
    for (int nt = 0; nt < 8; nt++) {
        f32x4 acc = {0.f, 0.f, 0.f, 0.f};
        #pragma unroll
        for (int kc = 0; kc < 4; kc++) {
            bf16x8 b = *(const bf16x8*)(pb + (nt * 4 + kc) * 64 + lane);
            acc = __builtin_amdgcn_mfma_f32_16x16x32_bf16(a[kc], b, acc, 0, 0, 0);
        }
        int col = nt * 16 + ml;
        float bias = lb[col];
        #pragma unroll
        for (int r = 0; r < 4; r++) {
            int row = m0 + quad * 4 + r;
            xlb[(size_t)row * HIDDEN + col] = f2bf(acc[r] + bias);
        }
    }
}

// ---------------------------------------------------------------------------
// Aggregation + residual + LayerNorm, fused. One wave per node.
__global__ __launch_bounds__(256) void k_agg(const ushort* __restrict__ xlb,
                                             const uint* __restrict__ meta,
                                             const int* __restrict__ offsets,
                                             const uint* __restrict__ ctab,
                                             const ushort* __restrict__ hb_in,
                                             const float* __restrict__ g,
                                             const float* __restrict__ b,
                                             ushort* __restrict__ hbf_out) {
    int wid = threadIdx.x >> 6;
    int lane = threadIdx.x & 63;
    int n = blockIdx.x * 4 + wid;
    if (n >= N_NODES) return;
    const uint* xl2 = (const uint*)xlb;    // bf16 pair per uint
    float accx = 0.f, accy = 0.f;
    int p0 = offsets[n], p1 = offsets[n + 1];
    int cnt = p1 - p0;
    for (int base = 0; base < cnt; base += 64) {
        int li = p0 + base + lane;
        uint mlv = meta[min(li, N_EDGES - 1)];   // coalesced batch load
        int kk = min(64, cnt - base);
        int k4 = kk & ~3;
        int p = 0;
        for (; p < k4; p += 4) {
            uint m0 = __builtin_amdgcn_readlane(mlv, p + 0);
            uint m1 = __builtin_amdgcn_readlane(mlv, p + 1);
            uint m2 = __builtin_amdgcn_readlane(mlv, p + 2);
            uint m3 = __builtin_amdgcn_readlane(mlv, p + 3);
            uint w0 = ctab[(m0 >> COLBITS) * 64 + lane];
            uint w1 = ctab[(m1 >> COLBITS) * 64 + lane];
            uint w2 = ctab[(m2 >> COLBITS) * 64 + lane];
            uint w3 = ctab[(m3 >> COLBITS) * 64 + lane];
            uint x0 = xl2[(m0 & ((1u << COLBITS) - 1)) * 64 + lane];
            uint x1 = xl2[(m1 & ((1u << COLBITS) - 1)) * 64 + lane];
            uint x2 = xl2[(m2 & ((1u << COLBITS) - 1)) * 64 + lane];
            uint x3 = xl2[(m3 & ((1u << COLBITS) - 1)) * 64 + lane];
            accx = fmaf(bflo(w0), bflo(x0), accx);
            accy = fmaf(bfhi(w0), bfhi(x0), accy);
            accx = fmaf(bflo(w1), bflo(x1), accx);
            accy = fmaf(bfhi(w1), bfhi(x1), accy);
            accx = fmaf(bflo(w2), bflo(x2), accx);
            accy = fmaf(bfhi(w2), bfhi(x2), accy);
            accx = fmaf(bflo(w3), bflo(x3), accx);
            accy = fmaf(bfhi(w3), bfhi(x3), accy);
        }
        for (; p < kk; p++) {
            uint m = __builtin_amdgcn_readlane(mlv, p);
            uint w = ctab[(m >> COLBITS) * 64 + lane];
            uint xv = xl2[(m & ((1u << COLBITS) - 1)) * 64 + lane];
            accx = fmaf(bflo(w), bflo(xv), accx);
            accy = fmaf(bfhi(w), bfhi(xv), accy);
        }
    }
    uint hvp = ((const uint*)hb_in)[n * 64 + lane];
    float vx = bflo(hvp) + accx, vy = bfhi(hvp) + accy;
    float s = vx + vy;
    #pragma unroll
    for (int off = 32; off; off >>= 1) s += __shfl_xor(s, off, 64);
    float mu = s * (1.0f / 128.0f);
    float dx = vx - mu, dy = vy - mu;
    float s2 = dx * dx + dy * dy;
    #pragma unroll
    for (int off = 32; off; off >>= 1) s2 += __shfl_xor(s2, off, 64);
    float rstd = rsqrtf(s2 * (1.0f / 128.0f) + 1e-5f);
    float2 gv = ((const float2*)g)[lane];
    float2 bv = ((const float2*)b)[lane];
    float ox = fmaf(dx * rstd, gv.x, bv.x);
    float oy = fmaf(dy * rstd, gv.y, bv.y);
    ((uint*)hbf_out)[n * 64 + lane] = packbf(ox, oy);
}

// ---------------------------------------------------------------------------
// Graph boundaries via binary search (batch is sorted).
__global__ void k_bounds(const int* __restrict__ batch, int* __restrict__ gstart) {
    int g = threadIdx.x;
    if (g > N_GRAPHS) return;
    int lo = 0, hi = N_NODES;
    while (lo < hi) {
        int mid = (lo + hi) >> 1;
        if (batch[mid] < g) lo = mid + 1; else hi = mid;
    }
    gstart[g] = lo;
}

// Mean pool, stage 1: PSPLIT blocks per graph write partial sums (bf16 input).
__global__ __launch_bounds__(256) void k_pool_part(const ushort* __restrict__ hbf,
                                                   const int* __restrict__ gstart,
                                                   float* __restrict__ partial) {
    int g = blockIdx.x / PSPLIT;
    int t = blockIdx.x % PSPLIT;
    int jp = threadIdx.x & 63;       // bf16-pair index (2 feats per thread)
    int half = threadIdx.x >> 6;     // 4 node-rows in flight
    int s = gstart[g], e = gstart[g + 1];
    float accx = 0.f, accy = 0.f;
    const uint* h2 = (const uint*)hbf;
    for (int n = s + t * 4 + half; n < e; n += PSPLIT * 4) {
        uint v = h2[n * 64 + jp];
        accx += bflo(v);
        accy += bfhi(v);
    }
    __shared__ float redx[256], redy[256];
    redx[threadIdx.x] = accx;
    redy[threadIdx.x] = accy;
    __syncthreads();
    if (half == 0) {
        float tx = redx[jp] + redx[jp + 64] + redx[jp + 128] + redx[jp + 192];
        float ty = redy[jp] + redy[jp + 64] + redy[jp + 128] + redy[jp + 192];
        float2 o; o.x = tx; o.y = ty;
        ((float2*)partial)[(g * PSPLIT + t) * 64 + jp] = o;
    }
}

// Mean pool, stage 2: reduce PSPLIT partials, divide by count.
__global__ void k_pool_fin(const float* __restrict__ partial,
                           const int* __restrict__ gstart,
                           float* __restrict__ out) {
    int idx = blockIdx.x * 128 + threadIdx.x;   // N_GRAPHS*HIDDEN total
    int g = idx >> 7, j = idx & 127;
    float tot = 0.f;
    #pragma unroll
    for (int t = 0; t < PSPLIT; t++) tot += partial[(g * PSPLIT + t) * HIDDEN + j];
    float c = (float)(gstart[g + 1] - gstart[g]);
    out[idx] = tot / fmaxf(c, 1.0f);
}

// ---------------------------------------------------------------------------
extern "C" void kernel_launch(void* const* d_in, const int* in_sizes, int n_in,
                              void* d_out, int out_size, void* d_ws, size_t ws_size,
                              hipStream_t stream) {
    const int* x = (const int*)d_in[0];
    const int* edge_index = (const int*)d_in[1];
    const int* row = edge_index;               // edge_index[0]
    const int* col = edge_index + N_EDGES;     // edge_index[1]
    const float* eattr = (const float*)d_in[2];
    const int* batch = (const int*)d_in[3];
    const float* emb = (const float*)d_in[4];
    const float* fw1 = (const float*)d_in[5];
    const float* fb1 = (const float*)d_in[6];
    const float* fw2 = (const float*)d_in[7];
    const float* fb2 = (const float*)d_in[8];
    const float* lw = (const float*)d_in[9];
    const float* lb = (const float*)d_in[10];
    const float* ln_g = (const float*)d_in[11];
    const float* ln_b = (const float*)d_in[12];
    float* out = (float*)d_out;

    char* ws = (char*)d_ws;
    size_t off = 0;
    auto alloc = [&](size_t bytes) -> void* {
        void* p = ws + off;
        off = (off + bytes + 255) & ~(size_t)255;
        return p;
    };
    uint* ctab     = (uint*)alloc((size_t)N_LAYERS * TAB * 64 * 4);
    ushort* hidbf  = (ushort*)alloc((size_t)N_LAYERS * TAB * HIDDEN * 2);
    ushort* hbf_a  = (ushort*)alloc((size_t)N_NODES * HIDDEN * 2);
    ushort* hbf_b  = (ushort*)alloc((size_t)N_NODES * HIDDEN * 2);
    ushort* xlb    = (ushort*)alloc((size_t)N_NODES * HIDDEN * 2);
    uint4* pb      = (uint4*)alloc((size_t)N_LAYERS * 8 * 4 * 64 * 16);
    uint4* pb2     = (uint4*)alloc((size_t)N_LAYERS * 8 * 4 * 64 * 16);
    int* counts    = (int*)alloc((size_t)(N_NODES + 1) * 4);
    int* offsets   = (int*)alloc((size_t)(N_NODES + 1) * 4);
    int* partial   = (int*)alloc((size_t)N_NODES * 4);
    int* blocksum  = (int*)alloc(256 * 4);
    int* bcur      = (int*)alloc(256 * 4);
    uint2* bs      = (uint2*)alloc((size_t)N_EDGES * 8);
    uint* meta     = (uint*)alloc((size_t)N_EDGES * 4);
    int* gstart    = (int*)alloc((size_t)(N_GRAPHS + 1) * 4);
    float* ppart   = (float*)alloc((size_t)N_GRAPHS * PSPLIT * HIDDEN * 4);

    hipMemsetAsync(counts, 0, (size_t)(N_NODES + 1) * 4, stream);

    k_packw<<<(N_LAYERS * 8 * 4 * 64 + 255) / 256, 256, 0, stream>>>(lw, pb);
    k_packw<<<(N_LAYERS * 8 * 4 * 64 + 255) / 256, 256, 0, stream>>>(fw2, pb2);
    k_tab1<<<N_LAYERS * (TAB / TG), 128, 0, stream>>>(fw1, fb1, hidbf);
    k_tab2<<<(N_LAYERS * TAB) / 64, 256, 0, stream>>>(hidbf, pb2, fb2, (ushort*)ctab);
    k_embed<<<(N_NODES * 32 + 255) / 256, 256, 0, stream>>>(x, emb, hbf_a);
    k_count<<<(N_EDGES + 255) / 256, 256, 0, stream>>>(row, counts);
    const int NBLK = (N_NODES + 255) / 256;   // 196
    k_scan1<<<NBLK, 256, 0, stream>>>(counts, partial, blocksum);
    k_scan2<<<1, 256, 0, stream>>>(blocksum, NBLK);
    k_scan3<<<NBLK, 256, 0, stream>>>(partial, blocksum, offsets, bcur);
    k_bucket<<<(N_EDGES + CHUNK - 1) / CHUNK, 256, 0, stream>>>(row, col, eattr, bcur, bs);
    k_scatter<<<NBUCK, 256, 0, stream>>>(bs, offsets, meta);
    k_bounds<<<1, 128, 0, stream>>>(batch, gstart);

    ushort* hb_cur = hbf_a; ushort* hb_nxt = hbf_b;
    const int XLBLK = (N_NODES / 16 + 3) / 4;   // 3125 waves -> 782 blocks
    for (int i = 0; i < N_LAYERS; i++) {
        k_xl<<<XLBLK, 256, 0, stream>>>(hb_cur, pb + (size_t)i * 8 * 4 * 64,
                                        lb + i * HIDDEN, xlb);
        k_agg<<<(N_NODES + 3) / 4, 256, 0, stream>>>(xlb, meta, offsets,
                                                     ctab + (size_t)i * TAB * 64,
                                                     hb_cur, ln_g + i * HIDDEN,
                                                     ln_b + i * HIDDEN, hb_nxt);
        ushort* tb = hb_cur; hb_cur = hb_nxt; hb_nxt = tb;
    }
    k_pool_part<<<N_GRAPHS * PSPLIT, 256, 0, stream>>>(hb_cur, gstart, ppart);
    k_pool_fin<<<(N_GRAPHS * HIDDEN + 127) / 128, 128, 0, stream>>>(ppart, gstart, out);
}

// Round 10
// 373.907 us; speedup vs baseline: 2.9125x; 1.0278x over previous
//
#include <hip/hip_runtime.h>
#include <hip/hip_bf16.h>

#define N_NODES 50000
#define N_EDGES 640000
#define HIDDEN 128
#define N_LAYERS 4
#define NUM_RBF 50
#define CUTOFF 4.0f
#define N_GRAPHS 64
#define TAB 8192        // nearest-neighbor table (half-step 2.44e-4)
#define TG 8            // grid points per k_tab1 block
#define PSPLIT 16       // pool blocks per graph
#define COLBITS 17      // meta packing: col in [0,2^17), gi in high bits
#define NBUCK 196       // row buckets (256 rows each)
#define CHUNK 4096      // edges per k_bucket block

typedef unsigned int uint;
typedef unsigned short ushort;
typedef __attribute__((ext_vector_type(8))) short bf16x8;   // MFMA A/B frag (4 VGPRs)
typedef __attribute__((ext_vector_type(4))) float f32x4;    // MFMA C/D frag

__device__ inline ushort f2bf(float f) {   // RNE float->bf16 (finite inputs)
    uint u = __float_as_uint(f);
    uint r = (u + 0x7fffu + ((u >> 16) & 1u)) >> 16;
    return (ushort)r;
}
__device__ inline uint packbf(float lo, float hi) {
    return (uint)f2bf(lo) | ((uint)f2bf(hi) << 16);
}
__device__ inline float bflo(uint u) { return __uint_as_float(u << 16); }
__device__ inline float bfhi(uint u) { return __uint_as_float(u & 0xffff0000u); }

// ---------------------------------------------------------------------------
// Table stage 1: hidbf[(layer*TAB+g)][j] = bf16(relu(rbf(g) . fw1[:,j] + fb1[j]))
__global__ __launch_bounds__(128) void k_tab1(const float* __restrict__ fw1,
                                              const float* __restrict__ fb1,
                                              ushort* __restrict__ hidbf) {
    int bid = blockIdx.x;
    int layer = bid / (TAB / TG);
    int g0 = (bid % (TAB / TG)) * TG;
    int j = threadIdx.x;
    __shared__ float rbf[TG][NUM_RBF];
    for (int idx = j; idx < TG * NUM_RBF; idx += 128) {
        int gg = idx / NUM_RBF, r = idx % NUM_RBF;
        float d = (CUTOFF * (g0 + gg)) / (float)(TAB - 1);
        float offset = (CUTOFF * r) / (float)(NUM_RBF - 1);
        float delta = CUTOFF / (float)(NUM_RBF - 1);
        float coeff = -0.5f / (delta * delta);
        float t = d - offset;
        rbf[gg][r] = expf(coeff * t * t);
    }
    __syncthreads();
    const float* w1 = fw1 + layer * NUM_RBF * HIDDEN;
    float b1 = fb1[layer * HIDDEN + j];
    float acc[TG];
    #pragma unroll
    for (int gg = 0; gg < TG; gg++) acc[gg] = b1;
    for (int r = 0; r < NUM_RBF; r++) {
        float w = w1[r * HIDDEN + j];
        #pragma unroll
        for (int gg = 0; gg < TG; gg++) acc[gg] = fmaf(rbf[gg][r], w, acc[gg]);
    }
    #pragma unroll
    for (int gg = 0; gg < TG; gg++)
        hidbf[((size_t)layer * TAB + g0 + gg) * HIDDEN + j] = f2bf(fmaxf(acc[gg], 0.0f));
}

// ---------------------------------------------------------------------------
// Table stage 2 via MFMA: ctab_rows = hidbf @ fw2 + fb2, stored as bf16 rows.
__global__ __launch_bounds__(256) void k_tab2(const ushort* __restrict__ hidbf,
                                              const uint4* __restrict__ pb2,
                                              const float* __restrict__ fb2,
                                              ushort* __restrict__ ctab) {
    int wave = threadIdx.x >> 6, lane = threadIdx.x & 63;
    int m0 = (blockIdx.x * 4 + wave) * 16;          // global row (layer*TAB+g)
    int layer = m0 / TAB;
    int quad = lane >> 4, ml = lane & 15;
    const ushort* arow = hidbf + (size_t)(m0 + ml) * HIDDEN + quad * 8;
    bf16x8 a[4];
    #pragma unroll
    for (int kc = 0; kc < 4; kc++) a[kc] = *(const bf16x8*)(arow + kc * 32);
    const uint4* pb = pb2 + (size_t)layer * 8 * 4 * 64;
    const float* bias = fb2 + layer * HIDDEN;
    #pragma unroll
    for (int nt = 0; nt < 8; nt++) {
        f32x4 acc = {0.f, 0.f, 0.f, 0.f};
        #pragma unroll
        for (int kc = 0; kc < 4; kc++) {
            bf16x8 b = *(const bf16x8*)(pb + (nt * 4 + kc) * 64 + lane);
            acc = __builtin_amdgcn_mfma_f32_16x16x32_bf16(a[kc], b, acc, 0, 0, 0);
        }
        int col = nt * 16 + ml;
        float bv = bias[col];
        #pragma unroll
        for (int r = 0; r < 4; r++) {
            int row = m0 + quad * 4 + r;
            ctab[(size_t)row * HIDDEN + col] = f2bf(acc[r] + bv);
        }
    }
}

// ---------------------------------------------------------------------------
// Embedding gather: hbf[n][:] = bf16(emb[x[n]][:])
__global__ void k_embed(const int* __restrict__ x, const float* __restrict__ emb,
                        ushort* __restrict__ hbf) {
    int idx = blockIdx.x * 256 + threadIdx.x;   // over N_NODES*32 float4s
    if (idx >= N_NODES * 32) return;
    int n = idx >> 5, q = idx & 31;
    float4 v = ((const float4*)emb)[x[n] * 32 + q];
    uint2 p;
    p.x = packbf(v.x, v.y);
    p.y = packbf(v.z, v.w);
    ((uint2*)hbf)[idx] = p;
}

// ---------------------------------------------------------------------------
// Pack BOTH lw and fw2 into B-fragment order (one launch, 2*8192 items).
__global__ void k_packw(const float* __restrict__ lw, const float* __restrict__ fw2,
                        uint4* __restrict__ pb, uint4* __restrict__ pb2) {
    int idx = blockIdx.x * 256 + threadIdx.x;   // 2*N_LAYERS*8*4*64 = 16384
    if (idx >= 2 * N_LAYERS * 8 * 4 * 64) return;
    int which = idx >> 13;                      // 0: lw->pb, 1: fw2->pb2
    int rem = idx & 8191;
    int lane = rem & 63;
    int kc = (rem >> 6) & 3;
    int nt = (rem >> 8) & 7;
    int layer = rem >> 11;
    int quad = lane >> 4, nl = lane & 15;
    int n = nt * 16 + nl;
    const float* w = (which ? fw2 : lw) + layer * HIDDEN * HIDDEN;
    uint r[4];
    #pragma unroll
    for (int jj = 0; jj < 4; jj++) {
        int k = kc * 32 + quad * 8 + 2 * jj;
        r[jj] = packbf(w[k * HIDDEN + n], w[(k + 1) * HIDDEN + n]);
    }
    uint4 o; o.x = r[0]; o.y = r[1]; o.z = r[2]; o.w = r[3];
    (which ? pb2 : pb)[rem] = o;
}

// ---------------------------------------------------------------------------
// CSR build. row is ~uniform-random -> low contention.
__global__ void k_count(const int* __restrict__ row, int* __restrict__ counts) {
    int e = blockIdx.x * 256 + threadIdx.x;
    if (e < N_EDGES) atomicAdd(&counts[row[e]], 1);
}

__global__ void k_scan1(const int* __restrict__ counts, int* __restrict__ partial,
                        int* __restrict__ blocksum) {
    int i = blockIdx.x * 256 + threadIdx.x;
    int v = (i < N_NODES) ? counts[i] : 0;
    int lane = threadIdx.x & 63;
    int wid = threadIdx.x >> 6;
    int s = v;
    #pragma unroll
    for (int off = 1; off < 64; off <<= 1) {
        int t = __shfl_up(s, off, 64);
        if (lane >= off) s += t;
    }
    __shared__ int wsum[4];
    if (lane == 63) wsum[wid] = s;
    __syncthreads();
    int woff = 0;
    for (int w = 0; w < wid; w++) woff += wsum[w];
    int incl = s + woff;
    if (i < N_NODES) partial[i] = incl - v;           // exclusive within block
    if (threadIdx.x == 255) blocksum[blockIdx.x] = incl;
}

// scan of block sums + (merged) graph-boundary binary search.
__global__ void k_scan2(int* __restrict__ blocksum, int nblk,
                        const int* __restrict__ batch, int* __restrict__ gstart) {
    int tid = threadIdx.x;
    if (tid <= N_GRAPHS) {                 // merged k_bounds
        int lo = 0, hi = N_NODES;
        while (lo < hi) {
            int mid = (lo + hi) >> 1;
            if (batch[mid] < tid) lo = mid + 1; else hi = mid;
        }
        gstart[tid] = lo;
    }
    int v = (tid < nblk) ? blocksum[tid] : 0;
    int lane = tid & 63, wid = tid >> 6;
    int s = v;
    #pragma unroll
    for (int off = 1; off < 64; off <<= 1) {
        int t = __shfl_up(s, off, 64);
        if (lane >= off) s += t;
    }
    __shared__ int wsum[4];
    if (lane == 63) wsum[wid] = s;
    __syncthreads();
    int woff = 0;
    for (int w = 0; w < wid; w++) woff += wsum[w];
    int incl = s + woff;
    if (tid < nblk) blocksum[tid] = incl - v;         // exclusive
}

// Writes offsets; also seeds bucket cursors at bucket row boundaries.
__global__ void k_scan3(const int* __restrict__ partial, const int* __restrict__ blocksum,
                        int* __restrict__ offsets, int* __restrict__ bcur) {
    int i = blockIdx.x * 256 + threadIdx.x;
    if (i < N_NODES) {
        int o = partial[i] + blocksum[blockIdx.x];
        offsets[i] = o;
        if ((i & 255) == 0) bcur[i >> 8] = o;
    }
    if (i == 0) offsets[N_NODES] = N_EDGES;
}

// ---------------------------------------------------------------------------
// Bucket sort pass: chunk of CHUNK edges -> LDS histogram/scan/stage ->
// coalesced run writes into per-bucket global spans (8B: packed meta + row).
__global__ __launch_bounds__(256) void k_bucket(const int* __restrict__ row,
                                                const int* __restrict__ col,
                                                const float* __restrict__ eattr,
                                                int* __restrict__ bcur,
                                                uint2* __restrict__ bs) {
    __shared__ uint2 stage[CHUNK];
    __shared__ int hist[256], lscan[256], lcur[256], gbase[256];
    __shared__ int wsum[4];
    int t = threadIdx.x;
    int e0 = blockIdx.x * CHUNK;
    int ne = min(CHUNK, N_EDGES - e0);
    hist[t] = 0;
    __syncthreads();
    for (int i = t; i < ne; i += 256)
        atomicAdd(&hist[row[e0 + i] >> 8], 1);
    __syncthreads();
    int v = hist[t];
    int lane = t & 63, wid = t >> 6;
    int s = v;
    #pragma unroll
    for (int off = 1; off < 64; off <<= 1) {
        int u = __shfl_up(s, off, 64);
        if (lane >= off) s += u;
    }
    if (lane == 63) wsum[wid] = s;
    __syncthreads();
    int woff = 0;
    for (int w = 0; w < wid; w++) woff += wsum[w];
    int excl = s + woff - v;
    lscan[t] = excl;
    lcur[t] = excl;
    if (v > 0) gbase[t] = atomicAdd(&bcur[t], v);   // reserve span in bucket
    __syncthreads();
    for (int i = t; i < ne; i += 256) {
        int e = e0 + i;
        int r = row[e];
        float tt = eattr[e] * ((float)(TAB - 1) / CUTOFF);
        int gi = (int)(tt + 0.5f);
        gi = min(max(gi, 0), TAB - 1);
        int pos = atomicAdd(&lcur[r >> 8], 1);
        uint2 sv;
        sv.x = (uint)col[e] | ((uint)gi << COLBITS);
        sv.y = (uint)r;
        stage[pos] = sv;
    }
    __syncthreads();
    for (int i = t; i < ne; i += 256) {
        uint2 sv = stage[i];
        int b = sv.y >> 8;
        bs[gbase[b] + (i - lscan[b])] = sv;   // coalesced run writes
    }
}

// Fine scatter within each bucket's <=13KB meta window: single-writer block.
__global__ __launch_bounds__(256) void k_scatter(const uint2* __restrict__ bs,
                                                 const int* __restrict__ offsets,
                                                 uint* __restrict__ meta) {
    int b = blockIdx.x, t = threadIdx.x;
    int r0 = b << 8;
    __shared__ int cur[256];
    int rmax = min(r0 + 256, N_NODES);
    cur[t] = offsets[min(r0 + t, N_NODES)];
    __syncthreads();
    int s = offsets[r0], e = offsets[rmax];
    for (int i = s + t; i < e; i += 256) {
        uint2 v = bs[i];
        int slot = atomicAdd(&cur[v.y - r0], 1);
        meta[slot] = v.x;
    }
}

// ---------------------------------------------------------------------------
// xl = h @ lw + lb via bf16 MFMA. One wave = 16 rows x 128 cols.
__global__ __launch_bounds__(256) void k_xl(const ushort* __restrict__ hbf,
                                            const uint4* __restrict__ pb,
                                            const float* __restrict__ lb,
                                            ushort* __restrict__ xlb) {
    int wave = threadIdx.x >> 6, lane = threadIdx.x & 63;
    int m0 = (blockIdx.x * 4 + wave) * 16;
    if (m0 >= N_NODES) return;
    int quad = lane >> 4, ml = lane & 15;
    const ushort* arow = hbf + (size_t)(m0 + ml) * HIDDEN + quad * 8;
    bf16x8 a[4];
    #pragma unroll
    for (int kc = 0; kc < 4; kc++) a[kc] = *(const bf16x8*)(arow + kc * 32);
    #pragma unroll
    for (int nt = 0; nt < 8; nt++) {
        f32x4 acc = {0.f, 0.f, 0.f, 0.f};
        #pragma unroll
        for (int kc = 0; kc < 4; kc++) {
            bf16x8 b = *(const bf16x8*)(pb + (nt * 4 + kc) * 64 + lane);
            acc = __builtin_amdgcn_mfma_f32_16x16x32_bf16(a[kc], b, acc, 0, 0, 0);
        }
        int col = nt * 16 + ml;
        float bias = lb[col];
        #pragma unroll
        for (int r = 0; r < 4; r++) {
            int row = m0 + quad * 4 + r;
            xlb[(size_t)row * HIDDEN + col] = f2bf(acc[r] + bias);
        }
    }
}

// ---------------------------------------------------------------------------
// Aggregation + residual + LayerNorm, fused. One wave per node.
// Unroll-8: 16 independent gathers in flight per group (2x the MLP of R7).
#define EDGE1(mv) { \
    uint w_ = ctab[((mv) >> COLBITS) * 64 + lane]; \
    uint x_ = xl2[((mv) & ((1u << COLBITS) - 1)) * 64 + lane]; \
    accx = fmaf(bflo(w_), bflo(x_), accx); \
    accy = fmaf(bfhi(w_), bfhi(x_), accy); }

__global__ __launch_bounds__(256) void k_agg(const ushort* __restrict__ xlb,
                                             const uint* __restrict__ meta,
                                             const int* __restrict__ offsets,
                                             const uint* __restrict__ ctab,
                                             const ushort* __restrict__ hb_in,
                                             const float* __restrict__ g,
                                             const float* __restrict__ b,
                                             ushort* __restrict__ hbf_out) {
    int wid = threadIdx.x >> 6;
    int lane = threadIdx.x & 63;
    int n = blockIdx.x * 4 + wid;
    if (n >= N_NODES) return;
    const uint* xl2 = (const uint*)xlb;    // bf16 pair per uint
    float accx = 0.f, accy = 0.f;
    int p0 = offsets[n], p1 = offsets[n + 1];
    int cnt = p1 - p0;
    for (int base = 0; base < cnt; base += 64) {
        int li = p0 + base + lane;
        uint mlv = meta[min(li, N_EDGES - 1)];   // coalesced batch load
        int kk = min(64, cnt - base);
        int p = 0;
        for (; p + 8 <= kk; p += 8) {
            uint m0 = __builtin_amdgcn_readlane(mlv, p + 0);
            uint m1 = __builtin_amdgcn_readlane(mlv, p + 1);
            uint m2 = __builtin_amdgcn_readlane(mlv, p + 2);
            uint m3 = __builtin_amdgcn_readlane(mlv, p + 3);
            uint m4 = __builtin_amdgcn_readlane(mlv, p + 4);
            uint m5 = __builtin_amdgcn_readlane(mlv, p + 5);
            uint m6 = __builtin_amdgcn_readlane(mlv, p + 6);
            uint m7 = __builtin_amdgcn_readlane(mlv, p + 7);
            uint w0 = ctab[(m0 >> COLBITS) * 64 + lane];
            uint w1 = ctab[(m1 >> COLBITS) * 64 + lane];
            uint w2 = ctab[(m2 >> COLBITS) * 64 + lane];
            uint w3 = ctab[(m3 >> COLBITS) * 64 + lane];
            uint w4 = ctab[(m4 >> COLBITS) * 64 + lane];
            uint w5 = ctab[(m5 >> COLBITS) * 64 + lane];
            uint w6 = ctab[(m6 >> COLBITS) * 64 + lane];
            uint w7 = ctab[(m7 >> COLBITS) * 64 + lane];
            uint x0 = xl2[(m0 & ((1u << COLBITS) - 1)) * 64 + lane];
            uint x1 = xl2[(m1 & ((1u << COLBITS) - 1)) * 64 + lane];
            uint x2 = xl2[(m2 & ((1u << COLBITS) - 1)) * 64 + lane];
            uint x3 = xl2[(m3 & ((1u << COLBITS) - 1)) * 64 + lane];
            uint x4 = xl2[(m4 & ((1u << COLBITS) - 1)) * 64 + lane];
            uint x5 = xl2[(m5 & ((1u << COLBITS) - 1)) * 64 + lane];
            uint x6 = xl2[(m6 & ((1u << COLBITS) - 1)) * 64 + lane];
            uint x7 = xl2[(m7 & ((1u << COLBITS) - 1)) * 64 + lane];
            accx = fmaf(bflo(w0), bflo(x0), accx);
            accy = fmaf(bfhi(w0), bfhi(x0), accy);
            accx = fmaf(bflo(w1), bflo(x1), accx);
            accy = fmaf(bfhi(w1), bfhi(x1), accy);
            accx = fmaf(bflo(w2), bflo(x2), accx);
            accy = fmaf(bfhi(w2), bfhi(x2), accy);
            accx = fmaf(bflo(w3), bflo(x3), accx);
            accy = fmaf(bfhi(w3), bfhi(x3), accy);
            accx = fmaf(bflo(w4), bflo(x4), accx);
            accy = fmaf(bfhi(w4), bfhi(x4), accy);
            accx = fmaf(bflo(w5), bflo(x5), accx);
            accy = fmaf(bfhi(w5), bfhi(x5), accy);
            accx = fmaf(bflo(w6), bflo(x6), accx);
            accy = fmaf(bfhi(w6), bfhi(x6), accy);
            accx = fmaf(bflo(w7), bflo(x7), accx);
            accy = fmaf(bfhi(w7), bfhi(x7), accy);
        }
        for (; p + 4 <= kk; p += 4) {
            uint m0 = __builtin_amdgcn_readlane(mlv, p + 0);
            uint m1 = __builtin_amdgcn_readlane(mlv, p + 1);
            uint m2 = __builtin_amdgcn_readlane(mlv, p + 2);
            uint m3 = __builtin_amdgcn_readlane(mlv, p + 3);
            uint w0 = ctab[(m0 >> COLBITS) * 64 + lane];
            uint w1 = ctab[(m1 >> COLBITS) * 64 + lane];
            uint w2 = ctab[(m2 >> COLBITS) * 64 + lane];
            uint w3 = ctab[(m3 >> COLBITS) * 64 + lane];
            uint x0 = xl2[(m0 & ((1u << COLBITS) - 1)) * 64 + lane];
            uint x1 = xl2[(m1 & ((1u << COLBITS) - 1)) * 64 + lane];
            uint x2 = xl2[(m2 & ((1u << COLBITS) - 1)) * 64 + lane];
            uint x3 = xl2[(m3 & ((1u << COLBITS) - 1)) * 64 + lane];
            accx = fmaf(bflo(w0), bflo(x0), accx);
            accy = fmaf(bfhi(w0), bfhi(x0), accy);
            accx = fmaf(bflo(w1), bflo(x1), accx);
            accy = fmaf(bfhi(w1), bfhi(x1), accy);
            accx = fmaf(bflo(w2), bflo(x2), accx);
            accy = fmaf(bfhi(w2), bfhi(x2), accy);
            accx = fmaf(bflo(w3), bflo(x3), accx);
            accy = fmaf(bfhi(w3), bfhi(x3), accy);
        }
        for (; p < kk; p++) {
            uint m = __builtin_amdgcn_readlane(mlv, p);
            EDGE1(m);
        }
    }
    uint hvp = ((const uint*)hb_in)[n * 64 + lane];
    float vx = bflo(hvp) + accx, vy = bfhi(hvp) + accy;
    float s = vx + vy;
    #pragma unroll
    for (int off = 32; off; off >>= 1) s += __shfl_xor(s, off, 64);
    float mu = s * (1.0f / 128.0f);
    float dx = vx - mu, dy = vy - mu;
    float s2 = dx * dx + dy * dy;
    #pragma unroll
    for (int off = 32; off; off >>= 1) s2 += __shfl_xor(s2, off, 64);
    float rstd = rsqrtf(s2 * (1.0f / 128.0f) + 1e-5f);
    float2 gv = ((const float2*)g)[lane];
    float2 bv = ((const float2*)b)[lane];
    float ox = fmaf(dx * rstd, gv.x, bv.x);
    float oy = fmaf(dy * rstd, gv.y, bv.y);
    ((uint*)hbf_out)[n * 64 + lane] = packbf(ox, oy);
}

// ---------------------------------------------------------------------------
// Mean pool, stage 1: PSPLIT blocks per graph write partial sums (bf16 input).
__global__ __launch_bounds__(256) void k_pool_part(const ushort* __restrict__ hbf,
                                                   const int* __restrict__ gstart,
                                                   float* __restrict__ partial) {
    int g = blockIdx.x / PSPLIT;
    int t = blockIdx.x % PSPLIT;
    int jp = threadIdx.x & 63;       // bf16-pair index (2 feats per thread)
    int half = threadIdx.x >> 6;     // 4 node-rows in flight
    int s = gstart[g], e = gstart[g + 1];
    float accx = 0.f, accy = 0.f;
    const uint* h2 = (const uint*)hbf;
    for (int n = s + t * 4 + half; n < e; n += PSPLIT * 4) {
        uint v = h2[n * 64 + jp];
        accx += bflo(v);
        accy += bfhi(v);
    }
    __shared__ float redx[256], redy[256];
    redx[threadIdx.x] = accx;
    redy[threadIdx.x] = accy;
    __syncthreads();
    if (half == 0) {
        float tx = redx[jp] + redx[jp + 64] + redx[jp + 128] + redx[jp + 192];
        float ty = redy[jp] + redy[jp + 64] + redy[jp + 128] + redy[jp + 192];
        float2 o; o.x = tx; o.y = ty;
        ((float2*)partial)[(g * PSPLIT + t) * 64 + jp] = o;
    }
}

// Mean pool, stage 2: reduce PSPLIT partials, divide by count.
__global__ void k_pool_fin(const float* __restrict__ partial,
                           const int* __restrict__ gstart,
                           float* __restrict__ out) {
    int idx = blockIdx.x * 128 + threadIdx.x;   // N_GRAPHS*HIDDEN total
    int g = idx >> 7, j = idx & 127;
    float tot = 0.f;
    #pragma unroll
    for (int t = 0; t < PSPLIT; t++) tot += partial[(g * PSPLIT + t) * HIDDEN + j];
    float c = (float)(gstart[g + 1] - gstart[g]);
    out[idx] = tot / fmaxf(c, 1.0f);
}

// ---------------------------------------------------------------------------
extern "C" void kernel_launch(void* const* d_in, const int* in_sizes, int n_in,
                              void* d_out, int out_size, void* d_ws, size_t ws_size,
                              hipStream_t stream) {
    const int* x = (const int*)d_in[0];
    const int* edge_index = (const int*)d_in[1];
    const int* row = edge_index;               // edge_index[0]
    const int* col = edge_index + N_EDGES;     // edge_index[1]
    const float* eattr = (const float*)d_in[2];
    const int* batch = (const int*)d_in[3];
    const float* emb = (const float*)d_in[4];
    const float* fw1 = (const float*)d_in[5];
    const float* fb1 = (const float*)d_in[6];
    const float* fw2 = (const float*)d_in[7];
    const float* fb2 = (const float*)d_in[8];
    const float* lw = (const float*)d_in[9];
    const float* lb = (const float*)d_in[10];
    const float* ln_g = (const float*)d_in[11];
    const float* ln_b = (const float*)d_in[12];
    float* out = (float*)d_out;

    char* ws = (char*)d_ws;
    size_t off = 0;
    auto alloc = [&](size_t bytes) -> void* {
        void* p = ws + off;
        off = (off + bytes + 255) & ~(size_t)255;
        return p;
    };
    uint* ctab     = (uint*)alloc((size_t)N_LAYERS * TAB * 64 * 4);
    ushort* hidbf  = (ushort*)alloc((size_t)N_LAYERS * TAB * HIDDEN * 2);
    ushort* hbf_a  = (ushort*)alloc((size_t)N_NODES * HIDDEN * 2);
    ushort* hbf_b  = (ushort*)alloc((size_t)N_NODES * HIDDEN * 2);
    ushort* xlb    = (ushort*)alloc((size_t)N_NODES * HIDDEN * 2);
    uint4* pb      = (uint4*)alloc((size_t)N_LAYERS * 8 * 4 * 64 * 16);
    uint4* pb2     = (uint4*)alloc((size_t)N_LAYERS * 8 * 4 * 64 * 16);
    int* counts    = (int*)alloc((size_t)(N_NODES + 1) * 4);
    int* offsets   = (int*)alloc((size_t)(N_NODES + 1) * 4);
    int* partial   = (int*)alloc((size_t)N_NODES * 4);
    int* blocksum  = (int*)alloc(256 * 4);
    int* bcur      = (int*)alloc(256 * 4);
    uint2* bs      = (uint2*)alloc((size_t)N_EDGES * 8);
    uint* meta     = (uint*)alloc((size_t)N_EDGES * 4);
    int* gstart    = (int*)alloc((size_t)(N_GRAPHS + 1) * 4);
    float* ppart   = (float*)alloc((size_t)N_GRAPHS * PSPLIT * HIDDEN * 4);

    hipMemsetAsync(counts, 0, (size_t)(N_NODES + 1) * 4, stream);

    k_packw<<<(2 * N_LAYERS * 8 * 4 * 64 + 255) / 256, 256, 0, stream>>>(lw, fw2, pb, pb2);
    k_tab1<<<N_LAYERS * (TAB / TG), 128, 0, stream>>>(fw1, fb1, hidbf);
    k_tab2<<<(N_LAYERS * TAB) / 64, 256, 0, stream>>>(hidbf, pb2, fb2, (ushort*)ctab);
    k_embed<<<(N_NODES * 32 + 255) / 256, 256, 0, stream>>>(x, emb, hbf_a);
    k_count<<<(N_EDGES + 255) / 256, 256, 0, stream>>>(row, counts);
    const int NBLK = (N_NODES + 255) / 256;   // 196
    k_scan1<<<NBLK, 256, 0, stream>>>(counts, partial, blocksum);
    k_scan2<<<1, 256, 0, stream>>>(blocksum, NBLK, batch, gstart);
    k_scan3<<<NBLK, 256, 0, stream>>>(partial, blocksum, offsets, bcur);
    k_bucket<<<(N_EDGES + CHUNK - 1) / CHUNK, 256, 0, stream>>>(row, col, eattr, bcur, bs);
    k_scatter<<<NBUCK, 256, 0, stream>>>(bs, offsets, meta);

    ushort* hb_cur = hbf_a; ushort* hb_nxt = hbf_b;
    const int XLBLK = (N_NODES / 16 + 3) / 4;   // 3125 waves -> 782 blocks
    for (int i = 0; i < N_LAYERS; i++) {
        k_xl<<<XLBLK, 256, 0, stream>>>(hb_cur, pb + (size_t)i * 8 * 4 * 64,
                                        lb + i * HIDDEN, xlb);
        k_agg<<<(N_NODES + 3) / 4, 256, 0, stream>>>(xlb, meta, offsets,
                                                     ctab + (size_t)i * TAB * 64,
                                                     hb_cur, ln_g + i * HIDDEN,
                                                     ln_b + i * HIDDEN, hb_nxt);
        ushort* tb = hb_cur; hb_cur = hb_nxt; hb_nxt = tb;
    }
    k_pool_part<<<N_GRAPHS * PSPLIT, 256, 0, stream>>>(hb_cur, gstart, ppart);
    k_pool_fin<<<(N_GRAPHS * HIDDEN + 127) / 128, 128, 0, stream>>>(ppart, gstart, out);
}

// Round 11
// 372.962 us; speedup vs baseline: 2.9199x; 1.0025x over previous
//
#include <hip/hip_runtime.h>
#include <hip/hip_bf16.h>

#define N_NODES 50000
#define N_EDGES 640000
#define HIDDEN 128
#define N_LAYERS 4
#define NUM_RBF 50
#define CUTOFF 4.0f
#define N_GRAPHS 64
#define TAB 8192        // nearest-neighbor table (half-step 2.44e-4)
#define TG 8            // grid points per k_tab1 block
#define PSPLIT 16       // pool blocks per graph
#define COLBITS 17      // meta packing: col in [0,2^17), gi in high bits
#define NBUCK 196       // row buckets (256 rows each)
#define CHUNK 4096      // edges per k_bucket block
#define PADMETA 990208  // >= N_EDGES + N_NODES*7 (max padded CSR size)
#define DUMMY ((uint)N_NODES)   // col=N_NODES (zero xl row), gi=0

typedef unsigned int uint;
typedef unsigned short ushort;
typedef __attribute__((ext_vector_type(8))) short bf16x8;   // MFMA A/B frag (4 VGPRs)
typedef __attribute__((ext_vector_type(4))) float f32x4;    // MFMA C/D frag

__device__ inline ushort f2bf(float f) {   // RNE float->bf16 (finite inputs)
    uint u = __float_as_uint(f);
    uint r = (u + 0x7fffu + ((u >> 16) & 1u)) >> 16;
    return (ushort)r;
}
__device__ inline uint packbf(float lo, float hi) {
    return (uint)f2bf(lo) | ((uint)f2bf(hi) << 16);
}
__device__ inline float bflo(uint u) { return __uint_as_float(u << 16); }
__device__ inline float bfhi(uint u) { return __uint_as_float(u & 0xffff0000u); }

// ---------------------------------------------------------------------------
// Table stage 1: hidbf[(layer*TAB+g)][j] = bf16(relu(rbf(g) . fw1[:,j] + fb1[j]))
__global__ __launch_bounds__(128) void k_tab1(const float* __restrict__ fw1,
                                              const float* __restrict__ fb1,
                                              ushort* __restrict__ hidbf) {
    int bid = blockIdx.x;
    int layer = bid / (TAB / TG);
    int g0 = (bid % (TAB / TG)) * TG;
    int j = threadIdx.x;
    __shared__ float rbf[TG][NUM_RBF];
    for (int idx = j; idx < TG * NUM_RBF; idx += 128) {
        int gg = idx / NUM_RBF, r = idx % NUM_RBF;
        float d = (CUTOFF * (g0 + gg)) / (float)(TAB - 1);
        float offset = (CUTOFF * r) / (float)(NUM_RBF - 1);
        float delta = CUTOFF / (float)(NUM_RBF - 1);
        float coeff = -0.5f / (delta * delta);
        float t = d - offset;
        rbf[gg][r] = expf(coeff * t * t);
    }
    __syncthreads();
    const float* w1 = fw1 + layer * NUM_RBF * HIDDEN;
    float b1 = fb1[layer * HIDDEN + j];
    float acc[TG];
    #pragma unroll
    for (int gg = 0; gg < TG; gg++) acc[gg] = b1;
    for (int r = 0; r < NUM_RBF; r++) {
        float w = w1[r * HIDDEN + j];
        #pragma unroll
        for (int gg = 0; gg < TG; gg++) acc[gg] = fmaf(rbf[gg][r], w, acc[gg]);
    }
    #pragma unroll
    for (int gg = 0; gg < TG; gg++)
        hidbf[((size_t)layer * TAB + g0 + gg) * HIDDEN + j] = f2bf(fmaxf(acc[gg], 0.0f));
}

// ---------------------------------------------------------------------------
// Table stage 2 via MFMA: ctab_rows = hidbf @ fw2 + fb2, stored as bf16 rows.
__global__ __launch_bounds__(256) void k_tab2(const ushort* __restrict__ hidbf,
                                              const uint4* __restrict__ pb2,
                                              const float* __restrict__ fb2,
                                              ushort* __restrict__ ctab) {
    int wave = threadIdx.x >> 6, lane = threadIdx.x & 63;
    int m0 = (blockIdx.x * 4 + wave) * 16;          // global row (layer*TAB+g)
    int layer = m0 / TAB;
    int quad = lane >> 4, ml = lane & 15;
    const ushort* arow = hidbf + (size_t)(m0 + ml) * HIDDEN + quad * 8;
    bf16x8 a[4];
    #pragma unroll
    for (int kc = 0; kc < 4; kc++) a[kc] = *(const bf16x8*)(arow + kc * 32);
    const uint4* pb = pb2 + (size_t)layer * 8 * 4 * 64;
    const float* bias = fb2 + layer * HIDDEN;
    #pragma unroll
    for (int nt = 0; nt < 8; nt++) {
        f32x4 acc = {0.f, 0.f, 0.f, 0.f};
        #pragma unroll
        for (int kc = 0; kc < 4; kc++) {
            bf16x8 b = *(const bf16x8*)(pb + (nt * 4 + kc) * 64 + lane);
            acc = __builtin_amdgcn_mfma_f32_16x16x32_bf16(a[kc], b, acc, 0, 0, 0);
        }
        int col = nt * 16 + ml;
        float bv = bias[col];
        #pragma unroll
        for (int r = 0; r < 4; r++) {
            int row = m0 + quad * 4 + r;
            ctab[(size_t)row * HIDDEN + col] = f2bf(acc[r] + bv);
        }
    }
}

// ---------------------------------------------------------------------------
// Embedding gather: hbf[n][:] = bf16(emb[x[n]][:])
__global__ void k_embed(const int* __restrict__ x, const float* __restrict__ emb,
                        ushort* __restrict__ hbf) {
    int idx = blockIdx.x * 256 + threadIdx.x;   // over N_NODES*32 float4s
    if (idx >= N_NODES * 32) return;
    int n = idx >> 5, q = idx & 31;
    float4 v = ((const float4*)emb)[x[n] * 32 + q];
    uint2 p;
    p.x = packbf(v.x, v.y);
    p.y = packbf(v.z, v.w);
    ((uint2*)hbf)[idx] = p;
}

// ---------------------------------------------------------------------------
// Pack BOTH lw and fw2 into B-fragment order (one launch, 2*8192 items).
__global__ void k_packw(const float* __restrict__ lw, const float* __restrict__ fw2,
                        uint4* __restrict__ pb, uint4* __restrict__ pb2) {
    int idx = blockIdx.x * 256 + threadIdx.x;   // 2*N_LAYERS*8*4*64 = 16384
    if (idx >= 2 * N_LAYERS * 8 * 4 * 64) return;
    int which = idx >> 13;                      // 0: lw->pb, 1: fw2->pb2
    int rem = idx & 8191;
    int lane = rem & 63;
    int kc = (rem >> 6) & 3;
    int nt = (rem >> 8) & 7;
    int layer = rem >> 11;
    int quad = lane >> 4, nl = lane & 15;
    int n = nt * 16 + nl;
    const float* w = (which ? fw2 : lw) + layer * HIDDEN * HIDDEN;
    uint r[4];
    #pragma unroll
    for (int jj = 0; jj < 4; jj++) {
        int k = kc * 32 + quad * 8 + 2 * jj;
        r[jj] = packbf(w[k * HIDDEN + n], w[(k + 1) * HIDDEN + n]);
    }
    uint4 o; o.x = r[0]; o.y = r[1]; o.z = r[2]; o.w = r[3];
    (which ? pb2 : pb)[rem] = o;
}

// ---------------------------------------------------------------------------
// CSR build. row is ~uniform-random -> low contention.
__global__ void k_count(const int* __restrict__ row, int* __restrict__ counts) {
    int e = blockIdx.x * 256 + threadIdx.x;
    if (e < N_EDGES) atomicAdd(&counts[row[e]], 1);
}

// Scan over counts PADDED to multiples of 8 (gives padded CSR layout).
__global__ void k_scan1(const int* __restrict__ counts, int* __restrict__ partial,
                        int* __restrict__ blocksum) {
    int i = blockIdx.x * 256 + threadIdx.x;
    int c = (i < N_NODES) ? counts[i] : 0;
    int v = (c + 7) & ~7;                              // pad to x8
    int lane = threadIdx.x & 63;
    int wid = threadIdx.x >> 6;
    int s = v;
    #pragma unroll
    for (int off = 1; off < 64; off <<= 1) {
        int t = __shfl_up(s, off, 64);
        if (lane >= off) s += t;
    }
    __shared__ int wsum[4];
    if (lane == 63) wsum[wid] = s;
    __syncthreads();
    int woff = 0;
    for (int w = 0; w < wid; w++) woff += wsum[w];
    int incl = s + woff;
    if (i < N_NODES) partial[i] = incl - v;           // exclusive within block
    if (threadIdx.x == 255) blocksum[blockIdx.x] = incl;
}

// scan of block sums + (merged) graph-boundary binary search.
__global__ void k_scan2(int* __restrict__ blocksum, int nblk,
                        const int* __restrict__ batch, int* __restrict__ gstart,
                        int* __restrict__ padtotal) {
    int tid = threadIdx.x;
    if (tid <= N_GRAPHS) {                 // merged k_bounds
        int lo = 0, hi = N_NODES;
        while (lo < hi) {
            int mid = (lo + hi) >> 1;
            if (batch[mid] < tid) lo = mid + 1; else hi = mid;
        }
        gstart[tid] = lo;
    }
    int v = (tid < nblk) ? blocksum[tid] : 0;
    int lane = tid & 63, wid = tid >> 6;
    int s = v;
    #pragma unroll
    for (int off = 1; off < 64; off <<= 1) {
        int t = __shfl_up(s, off, 64);
        if (lane >= off) s += t;
    }
    __shared__ int wsum[4];
    if (lane == 63) wsum[wid] = s;
    __syncthreads();
    int woff = 0;
    for (int w = 0; w < wid; w++) woff += wsum[w];
    int incl = s + woff;
    if (tid < nblk) blocksum[tid] = incl - v;         // exclusive
    if (tid == nblk - 1) *padtotal = incl;            // total padded edges
}

// Writes padded offsets; seeds bucket cursors at bucket row boundaries.
__global__ void k_scan3(const int* __restrict__ partial, const int* __restrict__ blocksum,
                        const int* __restrict__ padtotal,
                        int* __restrict__ offsets, int* __restrict__ bcur) {
    int i = blockIdx.x * 256 + threadIdx.x;
    if (i < N_NODES) {
        int o = partial[i] + blocksum[blockIdx.x];
        offsets[i] = o;
        if ((i & 255) == 0) bcur[i >> 8] = o;
    }
    if (i == 0) offsets[N_NODES] = *padtotal;
}

// ---------------------------------------------------------------------------
// Bucket sort pass: chunk of CHUNK edges -> LDS histogram/scan/stage ->
// coalesced run writes into per-bucket global spans (8B: packed meta + row).
// Runs are contiguous from each bucket's padded start (no gaps within fill).
__global__ __launch_bounds__(256) void k_bucket(const int* __restrict__ row,
                                                const int* __restrict__ col,
                                                const float* __restrict__ eattr,
                                                int* __restrict__ bcur,
                                                uint2* __restrict__ bs) {
    __shared__ uint2 stage[CHUNK];
    __shared__ int hist[256], lscan[256], lcur[256], gbase[256];
    __shared__ int wsum[4];
    int t = threadIdx.x;
    int e0 = blockIdx.x * CHUNK;
    int ne = min(CHUNK, N_EDGES - e0);
    hist[t] = 0;
    __syncthreads();
    for (int i = t; i < ne; i += 256)
        atomicAdd(&hist[row[e0 + i] >> 8], 1);
    __syncthreads();
    int v = hist[t];
    int lane = t & 63, wid = t >> 6;
    int s = v;
    #pragma unroll
    for (int off = 1; off < 64; off <<= 1) {
        int u = __shfl_up(s, off, 64);
        if (lane >= off) s += u;
    }
    if (lane == 63) wsum[wid] = s;
    __syncthreads();
    int woff = 0;
    for (int w = 0; w < wid; w++) woff += wsum[w];
    int excl = s + woff - v;
    lscan[t] = excl;
    lcur[t] = excl;
    if (v > 0) gbase[t] = atomicAdd(&bcur[t], v);   // reserve span in bucket
    __syncthreads();
    for (int i = t; i < ne; i += 256) {
        int e = e0 + i;
        int r = row[e];
        float tt = eattr[e] * ((float)(TAB - 1) / CUTOFF);
        int gi = (int)(tt + 0.5f);
        gi = min(max(gi, 0), TAB - 1);
        int pos = atomicAdd(&lcur[r >> 8], 1);
        uint2 sv;
        sv.x = (uint)col[e] | ((uint)gi << COLBITS);
        sv.y = (uint)r;
        stage[pos] = sv;
    }
    __syncthreads();
    for (int i = t; i < ne; i += 256) {
        uint2 sv = stage[i];
        int b = sv.y >> 8;
        bs[gbase[b] + (i - lscan[b])] = sv;   // coalesced run writes
    }
}

// Fine scatter within each bucket's meta window (single-writer block), then
// fill each node's pad slots [real_end, padded_end) with DUMMY edges.
__global__ __launch_bounds__(256) void k_scatter(const uint2* __restrict__ bs,
                                                 const int* __restrict__ offsets,
                                                 const int* __restrict__ bend,
                                                 uint* __restrict__ meta) {
    int b = blockIdx.x, t = threadIdx.x;
    int r0 = b << 8;
    __shared__ int cur[256];
    int rmax = min(r0 + 256, N_NODES);
    cur[t] = offsets[min(r0 + t, N_NODES)];
    __syncthreads();
    int s = offsets[r0], e = bend[b];       // real edges live in [s, bend)
    for (int i = s + t; i < e; i += 256) {
        uint2 v = bs[i];
        int slot = atomicAdd(&cur[v.y - r0], 1);
        meta[slot] = v.x;
    }
    __syncthreads();
    int node = r0 + t;
    if (node < rmax) {
        int end = offsets[node + 1];
        for (int i = cur[t]; i < end; i++) meta[i] = DUMMY;
    }
}

// ---------------------------------------------------------------------------
// xl = h @ lw + lb via bf16 MFMA. One wave = 16 rows x 128 cols.
__global__ __launch_bounds__(256) void k_xl(const ushort* __restrict__ hbf,
                                            const uint4* __restrict__ pb,
                                            const float* __restrict__ lb,
                                            ushort* __restrict__ xlb) {
    int wave = threadIdx.x >> 6, lane = threadIdx.x & 63;
    int m0 = (blockIdx.x * 4 + wave) * 16;
    if (m0 >= N_NODES) return;
    int quad = lane >> 4, ml = lane & 15;
    const ushort* arow = hbf + (size_t)(m0 + ml) * HIDDEN + quad * 8;
    bf16x8 a[4];
    #pragma unroll
    for (int kc = 0; kc < 4; kc++) a[kc] = *(const bf16x8*)(arow + kc * 32);
    #pragma unroll
    for (int nt = 0; nt < 8; nt++) {
        f32x4 acc = {0.f, 0.f, 0.f, 0.f};
        #pragma unroll
        for (int kc = 0; kc < 4; kc++) {
            bf16x8 b = *(const bf16x8*)(pb + (nt * 4 + kc) * 64 + lane);
            acc = __builtin_amdgcn_mfma_f32_16x16x32_bf16(a[kc], b, acc, 0, 0, 0);
        }
        int col = nt * 16 + ml;
        float bias = lb[col];
        #pragma unroll
        for (int r = 0; r < 4; r++) {
            int row = m0 + quad * 4 + r;
            xlb[(size_t)row * HIDDEN + col] = f2bf(acc[r] + bias);
        }
    }
}

// ---------------------------------------------------------------------------
// Aggregation + residual + LayerNorm, fused. One wave per node.
// Edge lists padded to x8 with zero-contribution dummies -> only full-width
// 8-groups (16 independent gathers in flight), no serialized 4-group/tail.
__global__ __launch_bounds__(256) void k_agg(const ushort* __restrict__ xlb,
                                             const uint* __restrict__ meta,
                                             const int* __restrict__ offsets,
                                             const uint* __restrict__ ctab,
                                             const ushort* __restrict__ hb_in,
                                             const float* __restrict__ g,
                                             const float* __restrict__ b,
                                             ushort* __restrict__ hbf_out) {
    int wid = threadIdx.x >> 6;
    int lane = threadIdx.x & 63;
    int n = blockIdx.x * 4 + wid;
    if (n >= N_NODES) return;
    const uint* xl2 = (const uint*)xlb;    // bf16 pair per uint
    float accx = 0.f, accy = 0.f;
    int p0 = offsets[n], p1 = offsets[n + 1];
    int cnt = p1 - p0;                      // multiple of 8
    for (int base = 0; base < cnt; base += 64) {
        int li = p0 + base + lane;
        uint mlv = meta[min(li, PADMETA - 1)];   // coalesced batch load
        int kk = min(64, cnt - base);            // multiple of 8
        for (int p = 0; p < kk; p += 8) {
            uint m0 = __builtin_amdgcn_readlane(mlv, p + 0);
            uint m1 = __builtin_amdgcn_readlane(mlv, p + 1);
            uint m2 = __builtin_amdgcn_readlane(mlv, p + 2);
            uint m3 = __builtin_amdgcn_readlane(mlv, p + 3);
            uint m4 = __builtin_amdgcn_readlane(mlv, p + 4);
            uint m5 = __builtin_amdgcn_readlane(mlv, p + 5);
            uint m6 = __builtin_amdgcn_readlane(mlv, p + 6);
            uint m7 = __builtin_amdgcn_readlane(mlv, p + 7);
            uint w0 = ctab[(m0 >> COLBITS) * 64 + lane];
            uint w1 = ctab[(m1 >> COLBITS) * 64 + lane];
            uint w2 = ctab[(m2 >> COLBITS) * 64 + lane];
            uint w3 = ctab[(m3 >> COLBITS) * 64 + lane];
            uint w4 = ctab[(m4 >> COLBITS) * 64 + lane];
            uint w5 = ctab[(m5 >> COLBITS) * 64 + lane];
            uint w6 = ctab[(m6 >> COLBITS) * 64 + lane];
            uint w7 = ctab[(m7 >> COLBITS) * 64 + lane];
            uint x0 = xl2[(m0 & ((1u << COLBITS) - 1)) * 64 + lane];
            uint x1 = xl2[(m1 & ((1u << COLBITS) - 1)) * 64 + lane];
            uint x2 = xl2[(m2 & ((1u << COLBITS) - 1)) * 64 + lane];
            uint x3 = xl2[(m3 & ((1u << COLBITS) - 1)) * 64 + lane];
            uint x4 = xl2[(m4 & ((1u << COLBITS) - 1)) * 64 + lane];
            uint x5 = xl2[(m5 & ((1u << COLBITS) - 1)) * 64 + lane];
            uint x6 = xl2[(m6 & ((1u << COLBITS) - 1)) * 64 + lane];
            uint x7 = xl2[(m7 & ((1u << COLBITS) - 1)) * 64 + lane];
            accx = fmaf(bflo(w0), bflo(x0), accx);
            accy = fmaf(bfhi(w0), bfhi(x0), accy);
            accx = fmaf(bflo(w1), bflo(x1), accx);
            accy = fmaf(bfhi(w1), bfhi(x1), accy);
            accx = fmaf(bflo(w2), bflo(x2), accx);
            accy = fmaf(bfhi(w2), bfhi(x2), accy);
            accx = fmaf(bflo(w3), bflo(x3), accx);
            accy = fmaf(bfhi(w3), bfhi(x3), accy);
            accx = fmaf(bflo(w4), bflo(x4), accx);
            accy = fmaf(bfhi(w4), bfhi(x4), accy);
            accx = fmaf(bflo(w5), bflo(x5), accx);
            accy = fmaf(bfhi(w5), bfhi(x5), accy);
            accx = fmaf(bflo(w6), bflo(x6), accx);
            accy = fmaf(bfhi(w6), bfhi(x6), accy);
            accx = fmaf(bflo(w7), bflo(x7), accx);
            accy = fmaf(bfhi(w7), bfhi(x7), accy);
        }
    }
    uint hvp = ((const uint*)hb_in)[n * 64 + lane];
    float vx = bflo(hvp) + accx, vy = bfhi(hvp) + accy;
    float s = vx + vy;
    #pragma unroll
    for (int off = 32; off; off >>= 1) s += __shfl_xor(s, off, 64);
    float mu = s * (1.0f / 128.0f);
    float dx = vx - mu, dy = vy - mu;
    float s2 = dx * dx + dy * dy;
    #pragma unroll
    for (int off = 32; off; off >>= 1) s2 += __shfl_xor(s2, off, 64);
    float rstd = rsqrtf(s2 * (1.0f / 128.0f) + 1e-5f);
    float2 gv = ((const float2*)g)[lane];
    float2 bv = ((const float2*)b)[lane];
    float ox = fmaf(dx * rstd, gv.x, bv.x);
    float oy = fmaf(dy * rstd, gv.y, bv.y);
    ((uint*)hbf_out)[n * 64 + lane] = packbf(ox, oy);
}

// ---------------------------------------------------------------------------
// Mean pool, stage 1: PSPLIT blocks per graph write partial sums (bf16 input).
__global__ __launch_bounds__(256) void k_pool_part(const ushort* __restrict__ hbf,
                                                   const int* __restrict__ gstart,
                                                   float* __restrict__ partial) {
    int g = blockIdx.x / PSPLIT;
    int t = blockIdx.x % PSPLIT;
    int jp = threadIdx.x & 63;       // bf16-pair index (2 feats per thread)
    int half = threadIdx.x >> 6;     // 4 node-rows in flight
    int s = gstart[g], e = gstart[g + 1];
    float accx = 0.f, accy = 0.f;
    const uint* h2 = (const uint*)hbf;
    for (int n = s + t * 4 + half; n < e; n += PSPLIT * 4) {
        uint v = h2[n * 64 + jp];
        accx += bflo(v);
        accy += bfhi(v);
    }
    __shared__ float redx[256], redy[256];
    redx[threadIdx.x] = accx;
    redy[threadIdx.x] = accy;
    __syncthreads();
    if (half == 0) {
        float tx = redx[jp] + redx[jp + 64] + redx[jp + 128] + redx[jp + 192];
        float ty = redy[jp] + redy[jp + 64] + redy[jp + 128] + redy[jp + 192];
        float2 o; o.x = tx; o.y = ty;
        ((float2*)partial)[(g * PSPLIT + t) * 64 + jp] = o;
    }
}

// Mean pool, stage 2: reduce PSPLIT partials, divide by count.
__global__ void k_pool_fin(const float* __restrict__ partial,
                           const int* __restrict__ gstart,
                           float* __restrict__ out) {
    int idx = blockIdx.x * 128 + threadIdx.x;   // N_GRAPHS*HIDDEN total
    int g = idx >> 7, j = idx & 127;
    float tot = 0.f;
    #pragma unroll
    for (int t = 0; t < PSPLIT; t++) tot += partial[(g * PSPLIT + t) * HIDDEN + j];
    float c = (float)(gstart[g + 1] - gstart[g]);
    out[idx] = tot / fmaxf(c, 1.0f);
}

// ---------------------------------------------------------------------------
extern "C" void kernel_launch(void* const* d_in, const int* in_sizes, int n_in,
                              void* d_out, int out_size, void* d_ws, size_t ws_size,
                              hipStream_t stream) {
    const int* x = (const int*)d_in[0];
    const int* edge_index = (const int*)d_in[1];
    const int* row = edge_index;               // edge_index[0]
    const int* col = edge_index + N_EDGES;     // edge_index[1]
    const float* eattr = (const float*)d_in[2];
    const int* batch = (const int*)d_in[3];
    const float* emb = (const float*)d_in[4];
    const float* fw1 = (const float*)d_in[5];
    const float* fb1 = (const float*)d_in[6];
    const float* fw2 = (const float*)d_in[7];
    const float* fb2 = (const float*)d_in[8];
    const float* lw = (const float*)d_in[9];
    const float* lb = (const float*)d_in[10];
    const float* ln_g = (const float*)d_in[11];
    const float* ln_b = (const float*)d_in[12];
    float* out = (float*)d_out;

    char* ws = (char*)d_ws;
    size_t off = 0;
    auto alloc = [&](size_t bytes) -> void* {
        void* p = ws + off;
        off = (off + bytes + 255) & ~(size_t)255;
        return p;
    };
    uint* ctab     = (uint*)alloc((size_t)N_LAYERS * TAB * 64 * 4);
    ushort* hidbf  = (ushort*)alloc((size_t)N_LAYERS * TAB * HIDDEN * 2);
    ushort* hbf_a  = (ushort*)alloc((size_t)N_NODES * HIDDEN * 2);
    ushort* hbf_b  = (ushort*)alloc((size_t)N_NODES * HIDDEN * 2);
    ushort* xlb    = (ushort*)alloc((size_t)(N_NODES + 1) * HIDDEN * 2);  // +1 zero row
    uint4* pb      = (uint4*)alloc((size_t)N_LAYERS * 8 * 4 * 64 * 16);
    uint4* pb2     = (uint4*)alloc((size_t)N_LAYERS * 8 * 4 * 64 * 16);
    int* counts    = (int*)alloc((size_t)(N_NODES + 1) * 4);
    int* offsets   = (int*)alloc((size_t)(N_NODES + 1) * 4);
    int* partial   = (int*)alloc((size_t)N_NODES * 4);
    int* blocksum  = (int*)alloc(256 * 4);
    int* bcur      = (int*)alloc(256 * 4);
    int* padtotal  = (int*)alloc(256);
    uint2* bs      = (uint2*)alloc((size_t)PADMETA * 8);
    uint* meta     = (uint*)alloc((size_t)PADMETA * 4);
    int* gstart    = (int*)alloc((size_t)(N_GRAPHS + 1) * 4);
    float* ppart   = (float*)alloc((size_t)N_GRAPHS * PSPLIT * HIDDEN * 4);

    hipMemsetAsync(counts, 0, (size_t)(N_NODES + 1) * 4, stream);
    hipMemsetAsync(xlb + (size_t)N_NODES * HIDDEN, 0, HIDDEN * 2, stream); // zero xl row

    k_packw<<<(2 * N_LAYERS * 8 * 4 * 64 + 255) / 256, 256, 0, stream>>>(lw, fw2, pb, pb2);
    k_tab1<<<N_LAYERS * (TAB / TG), 128, 0, stream>>>(fw1, fb1, hidbf);
    k_tab2<<<(N_LAYERS * TAB) / 64, 256, 0, stream>>>(hidbf, pb2, fb2, (ushort*)ctab);
    k_embed<<<(N_NODES * 32 + 255) / 256, 256, 0, stream>>>(x, emb, hbf_a);
    k_count<<<(N_EDGES + 255) / 256, 256, 0, stream>>>(row, counts);
    const int NBLK = (N_NODES + 255) / 256;   // 196
    k_scan1<<<NBLK, 256, 0, stream>>>(counts, partial, blocksum);
    k_scan2<<<1, 256, 0, stream>>>(blocksum, NBLK, batch, gstart, padtotal);
    k_scan3<<<NBLK, 256, 0, stream>>>(partial, blocksum, padtotal, offsets, bcur);
    k_bucket<<<(N_EDGES + CHUNK - 1) / CHUNK, 256, 0, stream>>>(row, col, eattr, bcur, bs);
    k_scatter<<<NBUCK, 256, 0, stream>>>(bs, offsets, bcur, meta);

    ushort* hb_cur = hbf_a; ushort* hb_nxt = hbf_b;
    const int XLBLK = (N_NODES / 16 + 3) / 4;   // 3125 waves -> 782 blocks
    for (int i = 0; i < N_LAYERS; i++) {
        k_xl<<<XLBLK, 256, 0, stream>>>(hb_cur, pb + (size_t)i * 8 * 4 * 64,
                                        lb + i * HIDDEN, xlb);
        k_agg<<<(N_NODES + 3) / 4, 256, 0, stream>>>(xlb, meta, offsets,
                                                     ctab + (size_t)i * TAB * 64,
                                                     hb_cur, ln_g + i * HIDDEN,
                                                     ln_b + i * HIDDEN, hb_nxt);
        ushort* tb = hb_cur; hb_cur = hb_nxt; hb_nxt = tb;
    }
    k_pool_part<<<N_GRAPHS * PSPLIT, 256, 0, stream>>>(hb_cur, gstart, ppart);
    k_pool_fin<<<(N_GRAPHS * HIDDEN + 127) / 128, 128, 0, stream>>>(ppart, gstart, out);
}

// Round 12
// 371.457 us; speedup vs baseline: 2.9317x; 1.0041x over previous
//
#include <hip/hip_runtime.h>
#include <hip/hip_bf16.h>

#define N_NODES 50000
#define N_EDGES 640000
#define HIDDEN 128
#define N_LAYERS 4
#define NUM_RBF 50
#define CUTOFF 4.0f
#define N_GRAPHS 64
#define TAB 8192        // nearest-neighbor table (half-step 2.44e-4)
#define TG 8            // grid points per k_tab1 block
#define PSPLIT 16       // pool blocks per graph
#define COLBITS 17      // meta packing: col in [0,2^17), gi in high bits
#define CMASK ((1u << COLBITS) - 1)
#define NBUCK 196       // row buckets (256 rows each)
#define CHUNK 4096      // edges per k_bucket block
#define PADMETA 990208  // >= N_EDGES + N_NODES*7 (max padded CSR size)
#define DUMMY ((uint)N_NODES)   // col=N_NODES (zero xl row), gi=0

typedef unsigned int uint;
typedef unsigned short ushort;
typedef __attribute__((ext_vector_type(8))) short bf16x8;   // MFMA A/B frag (4 VGPRs)
typedef __attribute__((ext_vector_type(4))) float f32x4;    // MFMA C/D frag

__device__ inline ushort f2bf(float f) {   // RNE float->bf16 (finite inputs)
    uint u = __float_as_uint(f);
    uint r = (u + 0x7fffu + ((u >> 16) & 1u)) >> 16;
    return (ushort)r;
}
__device__ inline uint packbf(float lo, float hi) {
    return (uint)f2bf(lo) | ((uint)f2bf(hi) << 16);
}
__device__ inline float bflo(uint u) { return __uint_as_float(u << 16); }
__device__ inline float bfhi(uint u) { return __uint_as_float(u & 0xffff0000u); }

// ---------------------------------------------------------------------------
// Table stage 1: hidbf[(layer*TAB+g)][j] = bf16(relu(rbf(g) . fw1[:,j] + fb1[j]))
__global__ __launch_bounds__(128) void k_tab1(const float* __restrict__ fw1,
                                              const float* __restrict__ fb1,
                                              ushort* __restrict__ hidbf) {
    int bid = blockIdx.x;
    int layer = bid / (TAB / TG);
    int g0 = (bid % (TAB / TG)) * TG;
    int j = threadIdx.x;
    __shared__ float rbf[TG][NUM_RBF];
    for (int idx = j; idx < TG * NUM_RBF; idx += 128) {
        int gg = idx / NUM_RBF, r = idx % NUM_RBF;
        float d = (CUTOFF * (g0 + gg)) / (float)(TAB - 1);
        float offset = (CUTOFF * r) / (float)(NUM_RBF - 1);
        float delta = CUTOFF / (float)(NUM_RBF - 1);
        float coeff = -0.5f / (delta * delta);
        float t = d - offset;
        rbf[gg][r] = expf(coeff * t * t);
    }
    __syncthreads();
    const float* w1 = fw1 + layer * NUM_RBF * HIDDEN;
    float b1 = fb1[layer * HIDDEN + j];
    float acc[TG];
    #pragma unroll
    for (int gg = 0; gg < TG; gg++) acc[gg] = b1;
    for (int r = 0; r < NUM_RBF; r++) {
        float w = w1[r * HIDDEN + j];
        #pragma unroll
        for (int gg = 0; gg < TG; gg++) acc[gg] = fmaf(rbf[gg][r], w, acc[gg]);
    }
    #pragma unroll
    for (int gg = 0; gg < TG; gg++)
        hidbf[((size_t)layer * TAB + g0 + gg) * HIDDEN + j] = f2bf(fmaxf(acc[gg], 0.0f));
}

// ---------------------------------------------------------------------------
// Table stage 2 via MFMA: ctab_rows = hidbf @ fw2 + fb2, stored as bf16 rows.
__global__ __launch_bounds__(256) void k_tab2(const ushort* __restrict__ hidbf,
                                              const uint4* __restrict__ pb2,
                                              const float* __restrict__ fb2,
                                              ushort* __restrict__ ctab) {
    int wave = threadIdx.x >> 6, lane = threadIdx.x & 63;
    int m0 = (blockIdx.x * 4 + wave) * 16;          // global row (layer*TAB+g)
    int layer = m0 / TAB;
    int quad = lane >> 4, ml = lane & 15;
    const ushort* arow = hidbf + (size_t)(m0 + ml) * HIDDEN + quad * 8;
    bf16x8 a[4];
    #pragma unroll
    for (int kc = 0; kc < 4; kc++) a[kc] = *(const bf16x8*)(arow + kc * 32);
    const uint4* pb = pb2 + (size_t)layer * 8 * 4 * 64;
    const float* bias = fb2 + layer * HIDDEN;
    #pragma unroll
    for (int nt = 0; nt < 8; nt++) {
        f32x4 acc = {0.f, 0.f, 0.f, 0.f};
        #pragma unroll
        for (int kc = 0; kc < 4; kc++) {
            bf16x8 b = *(const bf16x8*)(pb + (nt * 4 + kc) * 64 + lane);
            acc = __builtin_amdgcn_mfma_f32_16x16x32_bf16(a[kc], b, acc, 0, 0, 0);
        }
        int col = nt * 16 + ml;
        float bv = bias[col];
        #pragma unroll
        for (int r = 0; r < 4; r++) {
            int row = m0 + quad * 4 + r;
            ctab[(size_t)row * HIDDEN + col] = f2bf(acc[r] + bv);
        }
    }
}

// ---------------------------------------------------------------------------
// Embedding gather: hbf[n][:] = bf16(emb[x[n]][:])
__global__ void k_embed(const int* __restrict__ x, const float* __restrict__ emb,
                        ushort* __restrict__ hbf) {
    int idx = blockIdx.x * 256 + threadIdx.x;   // over N_NODES*32 float4s
    if (idx >= N_NODES * 32) return;
    int n = idx >> 5, q = idx & 31;
    float4 v = ((const float4*)emb)[x[n] * 32 + q];
    uint2 p;
    p.x = packbf(v.x, v.y);
    p.y = packbf(v.z, v.w);
    ((uint2*)hbf)[idx] = p;
}

// ---------------------------------------------------------------------------
// Pack BOTH lw and fw2 into B-fragment order (one launch, 2*8192 items).
__global__ void k_packw(const float* __restrict__ lw, const float* __restrict__ fw2,
                        uint4* __restrict__ pb, uint4* __restrict__ pb2) {
    int idx = blockIdx.x * 256 + threadIdx.x;   // 2*N_LAYERS*8*4*64 = 16384
    if (idx >= 2 * N_LAYERS * 8 * 4 * 64) return;
    int which = idx >> 13;                      // 0: lw->pb, 1: fw2->pb2
    int rem = idx & 8191;
    int lane = rem & 63;
    int kc = (rem >> 6) & 3;
    int nt = (rem >> 8) & 7;
    int layer = rem >> 11;
    int quad = lane >> 4, nl = lane & 15;
    int n = nt * 16 + nl;
    const float* w = (which ? fw2 : lw) + layer * HIDDEN * HIDDEN;
    uint r[4];
    #pragma unroll
    for (int jj = 0; jj < 4; jj++) {
        int k = kc * 32 + quad * 8 + 2 * jj;
        r[jj] = packbf(w[k * HIDDEN + n], w[(k + 1) * HIDDEN + n]);
    }
    uint4 o; o.x = r[0]; o.y = r[1]; o.z = r[2]; o.w = r[3];
    (which ? pb2 : pb)[rem] = o;
}

// ---------------------------------------------------------------------------
// CSR build. row is ~uniform-random -> low contention.
__global__ void k_count(const int* __restrict__ row, int* __restrict__ counts) {
    int e = blockIdx.x * 256 + threadIdx.x;
    if (e < N_EDGES) atomicAdd(&counts[row[e]], 1);
}

// Scan over counts PADDED to multiples of 8 (gives padded CSR layout).
__global__ void k_scan1(const int* __restrict__ counts, int* __restrict__ partial,
                        int* __restrict__ blocksum) {
    int i = blockIdx.x * 256 + threadIdx.x;
    int c = (i < N_NODES) ? counts[i] : 0;
    int v = (c + 7) & ~7;                              // pad to x8
    int lane = threadIdx.x & 63;
    int wid = threadIdx.x >> 6;
    int s = v;
    #pragma unroll
    for (int off = 1; off < 64; off <<= 1) {
        int t = __shfl_up(s, off, 64);
        if (lane >= off) s += t;
    }
    __shared__ int wsum[4];
    if (lane == 63) wsum[wid] = s;
    __syncthreads();
    int woff = 0;
    for (int w = 0; w < wid; w++) woff += wsum[w];
    int incl = s + woff;
    if (i < N_NODES) partial[i] = incl - v;           // exclusive within block
    if (threadIdx.x == 255) blocksum[blockIdx.x] = incl;
}

// scan of block sums + (merged) graph-boundary binary search.
__global__ void k_scan2(int* __restrict__ blocksum, int nblk,
                        const int* __restrict__ batch, int* __restrict__ gstart,
                        int* __restrict__ padtotal) {
    int tid = threadIdx.x;
    if (tid <= N_GRAPHS) {                 // merged k_bounds
        int lo = 0, hi = N_NODES;
        while (lo < hi) {
            int mid = (lo + hi) >> 1;
            if (batch[mid] < tid) lo = mid + 1; else hi = mid;
        }
        gstart[tid] = lo;
    }
    int v = (tid < nblk) ? blocksum[tid] : 0;
    int lane = tid & 63, wid = tid >> 6;
    int s = v;
    #pragma unroll
    for (int off = 1; off < 64; off <<= 1) {
        int t = __shfl_up(s, off, 64);
        if (lane >= off) s += t;
    }
    __shared__ int wsum[4];
    if (lane == 63) wsum[wid] = s;
    __syncthreads();
    int woff = 0;
    for (int w = 0; w < wid; w++) woff += wsum[w];
    int incl = s + woff;
    if (tid < nblk) blocksum[tid] = incl - v;         // exclusive
    if (tid == nblk - 1) *padtotal = incl;            // total padded edges
}

// Writes padded offsets; seeds bucket cursors at bucket row boundaries.
__global__ void k_scan3(const int* __restrict__ partial, const int* __restrict__ blocksum,
                        const int* __restrict__ padtotal,
                        int* __restrict__ offsets, int* __restrict__ bcur) {
    int i = blockIdx.x * 256 + threadIdx.x;
    if (i < N_NODES) {
        int o = partial[i] + blocksum[blockIdx.x];
        offsets[i] = o;
        if ((i & 255) == 0) bcur[i >> 8] = o;
    }
    if (i == 0) offsets[N_NODES] = *padtotal;
}

// ---------------------------------------------------------------------------
// Bucket sort pass: chunk of CHUNK edges -> LDS histogram/scan/stage ->
// coalesced run writes into per-bucket global spans (8B: packed meta + row).
__global__ __launch_bounds__(256) void k_bucket(const int* __restrict__ row,
                                                const int* __restrict__ col,
                                                const float* __restrict__ eattr,
                                                int* __restrict__ bcur,
                                                uint2* __restrict__ bs) {
    __shared__ uint2 stage[CHUNK];
    __shared__ int hist[256], lscan[256], lcur[256], gbase[256];
    __shared__ int wsum[4];
    int t = threadIdx.x;
    int e0 = blockIdx.x * CHUNK;
    int ne = min(CHUNK, N_EDGES - e0);
    hist[t] = 0;
    __syncthreads();
    for (int i = t; i < ne; i += 256)
        atomicAdd(&hist[row[e0 + i] >> 8], 1);
    __syncthreads();
    int v = hist[t];
    int lane = t & 63, wid = t >> 6;
    int s = v;
    #pragma unroll
    for (int off = 1; off < 64; off <<= 1) {
        int u = __shfl_up(s, off, 64);
        if (lane >= off) s += u;
    }
    if (lane == 63) wsum[wid] = s;
    __syncthreads();
    int woff = 0;
    for (int w = 0; w < wid; w++) woff += wsum[w];
    int excl = s + woff - v;
    lscan[t] = excl;
    lcur[t] = excl;
    if (v > 0) gbase[t] = atomicAdd(&bcur[t], v);   // reserve span in bucket
    __syncthreads();
    for (int i = t; i < ne; i += 256) {
        int e = e0 + i;
        int r = row[e];
        float tt = eattr[e] * ((float)(TAB - 1) / CUTOFF);
        int gi = (int)(tt + 0.5f);
        gi = min(max(gi, 0), TAB - 1);
        int pos = atomicAdd(&lcur[r >> 8], 1);
        uint2 sv;
        sv.x = (uint)col[e] | ((uint)gi << COLBITS);
        sv.y = (uint)r;
        stage[pos] = sv;
    }
    __syncthreads();
    for (int i = t; i < ne; i += 256) {
        uint2 sv = stage[i];
        int b = sv.y >> 8;
        bs[gbase[b] + (i - lscan[b])] = sv;   // coalesced run writes
    }
}

// Fine scatter within each bucket's meta window (single-writer block), then
// fill each node's pad slots [real_end, padded_end) with DUMMY edges.
__global__ __launch_bounds__(256) void k_scatter(const uint2* __restrict__ bs,
                                                 const int* __restrict__ offsets,
                                                 const int* __restrict__ bend,
                                                 uint* __restrict__ meta) {
    int b = blockIdx.x, t = threadIdx.x;
    int r0 = b << 8;
    __shared__ int cur[256];
    int rmax = min(r0 + 256, N_NODES);
    cur[t] = offsets[min(r0 + t, N_NODES)];
    __syncthreads();
    int s = offsets[r0], e = bend[b];       // real edges live in [s, bend)
    for (int i = s + t; i < e; i += 256) {
        uint2 v = bs[i];
        int slot = atomicAdd(&cur[v.y - r0], 1);
        meta[slot] = v.x;
    }
    __syncthreads();
    int node = r0 + t;
    if (node < rmax) {
        int end = offsets[node + 1];
        for (int i = cur[t]; i < end; i++) meta[i] = DUMMY;
    }
}

// ---------------------------------------------------------------------------
// xl = h @ lw + lb via bf16 MFMA. One wave = 16 rows x 128 cols.
__global__ __launch_bounds__(256) void k_xl(const ushort* __restrict__ hbf,
                                            const uint4* __restrict__ pb,
                                            const float* __restrict__ lb,
                                            ushort* __restrict__ xlb) {
    int wave = threadIdx.x >> 6, lane = threadIdx.x & 63;
    int m0 = (blockIdx.x * 4 + wave) * 16;
    if (m0 >= N_NODES) return;
    int quad = lane >> 4, ml = lane & 15;
    const ushort* arow = hbf + (size_t)(m0 + ml) * HIDDEN + quad * 8;
    bf16x8 a[4];
    #pragma unroll
    for (int kc = 0; kc < 4; kc++) a[kc] = *(const bf16x8*)(arow + kc * 32);
    #pragma unroll
    for (int nt = 0; nt < 8; nt++) {
        f32x4 acc = {0.f, 0.f, 0.f, 0.f};
        #pragma unroll
        for (int kc = 0; kc < 4; kc++) {
            bf16x8 b = *(const bf16x8*)(pb + (nt * 4 + kc) * 64 + lane);
            acc = __builtin_amdgcn_mfma_f32_16x16x32_bf16(a[kc], b, acc, 0, 0, 0);
        }
        int col = nt * 16 + ml;
        float bias = lb[col];
        #pragma unroll
        for (int r = 0; r < 4; r++) {
            int row = m0 + quad * 4 + r;
            xlb[(size_t)row * HIDDEN + col] = f2bf(acc[r] + bias);
        }
    }
}

// ---------------------------------------------------------------------------
// Aggregation + residual + LayerNorm, fused. One wave per node.
// Edge lists padded to x8. Software-pipelined pairs of 8-groups: 32 gathers
// issued before the first fma (partial vmcnt wait covers group A while B
// stays in flight) -> one memory round-trip per node instead of two.
__global__ __launch_bounds__(256) void k_agg(const ushort* __restrict__ xlb,
                                             const uint* __restrict__ meta,
                                             const int* __restrict__ offsets,
                                             const uint* __restrict__ ctab,
                                             const ushort* __restrict__ hb_in,
                                             const float* __restrict__ g,
                                             const float* __restrict__ b,
                                             ushort* __restrict__ hbf_out) {
    int wid = threadIdx.x >> 6;
    int lane = threadIdx.x & 63;
    int n = blockIdx.x * 4 + wid;
    if (n >= N_NODES) return;
    const uint* xl2 = (const uint*)xlb;    // bf16 pair per uint
    float accx = 0.f, accy = 0.f;
    int p0 = offsets[n], p1 = offsets[n + 1];
    int cnt = p1 - p0;                      // multiple of 8
    for (int base = 0; base < cnt; base += 64) {
        int li = p0 + base + lane;
        uint mlv = meta[min(li, PADMETA - 1)];   // coalesced batch load
        int kk = min(64, cnt - base);            // multiple of 8
        int p = 0;
        for (; p + 16 <= kk; p += 16) {          // paired groups: 32 loads in flight
            uint wA[8], xA[8], wB[8], xB[8];
            #pragma unroll
            for (int i = 0; i < 8; i++) {
                uint m = __builtin_amdgcn_readlane(mlv, p + i);
                wA[i] = ctab[(m >> COLBITS) * 64 + lane];
                xA[i] = xl2[(m & CMASK) * 64 + lane];
            }
            #pragma unroll
            for (int i = 0; i < 8; i++) {
                uint m = __builtin_amdgcn_readlane(mlv, p + 8 + i);
                wB[i] = ctab[(m >> COLBITS) * 64 + lane];
                xB[i] = xl2[(m & CMASK) * 64 + lane];
            }
            #pragma unroll
            for (int i = 0; i < 8; i++) {
                accx = fmaf(bflo(wA[i]), bflo(xA[i]), accx);
                accy = fmaf(bfhi(wA[i]), bfhi(xA[i]), accy);
            }
            #pragma unroll
            for (int i = 0; i < 8; i++) {
                accx = fmaf(bflo(wB[i]), bflo(xB[i]), accx);
                accy = fmaf(bfhi(wB[i]), bfhi(xB[i]), accy);
            }
        }
        for (; p < kk; p += 8) {                 // at most one trailing group
            uint wA[8], xA[8];
            #pragma unroll
            for (int i = 0; i < 8; i++) {
                uint m = __builtin_amdgcn_readlane(mlv, p + i);
                wA[i] = ctab[(m >> COLBITS) * 64 + lane];
                xA[i] = xl2[(m & CMASK) * 64 + lane];
            }
            #pragma unroll
            for (int i = 0; i < 8; i++) {
                accx = fmaf(bflo(wA[i]), bflo(xA[i]), accx);
                accy = fmaf(bfhi(wA[i]), bfhi(xA[i]), accy);
            }
        }
    }
    uint hvp = ((const uint*)hb_in)[n * 64 + lane];
    float vx = bflo(hvp) + accx, vy = bfhi(hvp) + accy;
    float s = vx + vy;
    #pragma unroll
    for (int off = 32; off; off >>= 1) s += __shfl_xor(s, off, 64);
    float mu = s * (1.0f / 128.0f);
    float dx = vx - mu, dy = vy - mu;
    float s2 = dx * dx + dy * dy;
    #pragma unroll
    for (int off = 32; off; off >>= 1) s2 += __shfl_xor(s2, off, 64);
    float rstd = rsqrtf(s2 * (1.0f / 128.0f) + 1e-5f);
    float2 gv = ((const float2*)g)[lane];
    float2 bv = ((const float2*)b)[lane];
    float ox = fmaf(dx * rstd, gv.x, bv.x);
    float oy = fmaf(dy * rstd, gv.y, bv.y);
    ((uint*)hbf_out)[n * 64 + lane] = packbf(ox, oy);
}

// ---------------------------------------------------------------------------
// Mean pool, stage 1: PSPLIT blocks per graph write partial sums (bf16 input).
__global__ __launch_bounds__(256) void k_pool_part(const ushort* __restrict__ hbf,
                                                   const int* __restrict__ gstart,
                                                   float* __restrict__ partial) {
    int g = blockIdx.x / PSPLIT;
    int t = blockIdx.x % PSPLIT;
    int jp = threadIdx.x & 63;       // bf16-pair index (2 feats per thread)
    int half = threadIdx.x >> 6;     // 4 node-rows in flight
    int s = gstart[g], e = gstart[g + 1];
    float accx = 0.f, accy = 0.f;
    const uint* h2 = (const uint*)hbf;
    for (int n = s + t * 4 + half; n < e; n += PSPLIT * 4) {
        uint v = h2[n * 64 + jp];
        accx += bflo(v);
        accy += bfhi(v);
    }
    __shared__ float redx[256], redy[256];
    redx[threadIdx.x] = accx;
    redy[threadIdx.x] = accy;
    __syncthreads();
    if (half == 0) {
        float tx = redx[jp] + redx[jp + 64] + redx[jp + 128] + redx[jp + 192];
        float ty = redy[jp] + redy[jp + 64] + redy[jp + 128] + redy[jp + 192];
        float2 o; o.x = tx; o.y = ty;
        ((float2*)partial)[(g * PSPLIT + t) * 64 + jp] = o;
    }
}

// Mean pool, stage 2: reduce PSPLIT partials, divide by count.
__global__ void k_pool_fin(const float* __restrict__ partial,
                           const int* __restrict__ gstart,
                           float* __restrict__ out) {
    int idx = blockIdx.x * 128 + threadIdx.x;   // N_GRAPHS*HIDDEN total
    int g = idx >> 7, j = idx & 127;
    float tot = 0.f;
    #pragma unroll
    for (int t = 0; t < PSPLIT; t++) tot += partial[(g * PSPLIT + t) * HIDDEN + j];
    float c = (float)(gstart[g + 1] - gstart[g]);
    out[idx] = tot / fmaxf(c, 1.0f);
}

// ---------------------------------------------------------------------------
extern "C" void kernel_launch(void* const* d_in, const int* in_sizes, int n_in,
                              void* d_out, int out_size, void* d_ws, size_t ws_size,
                              hipStream_t stream) {
    const int* x = (const int*)d_in[0];
    const int* edge_index = (const int*)d_in[1];
    const int* row = edge_index;               // edge_index[0]
    const int* col = edge_index + N_EDGES;     // edge_index[1]
    const float* eattr = (const float*)d_in[2];
    const int* batch = (const int*)d_in[3];
    const float* emb = (const float*)d_in[4];
    const float* fw1 = (const float*)d_in[5];
    const float* fb1 = (const float*)d_in[6];
    const float* fw2 = (const float*)d_in[7];
    const float* fb2 = (const float*)d_in[8];
    const float* lw = (const float*)d_in[9];
    const float* lb = (const float*)d_in[10];
    const float* ln_g = (const float*)d_in[11];
    const float* ln_b = (const float*)d_in[12];
    float* out = (float*)d_out;

    char* ws = (char*)d_ws;
    size_t off = 0;
    auto alloc = [&](size_t bytes) -> void* {
        void* p = ws + off;
        off = (off + bytes + 255) & ~(size_t)255;
        return p;
    };
    uint* ctab     = (uint*)alloc((size_t)N_LAYERS * TAB * 64 * 4);
    ushort* hidbf  = (ushort*)alloc((size_t)N_LAYERS * TAB * HIDDEN * 2);
    ushort* hbf_a  = (ushort*)alloc((size_t)N_NODES * HIDDEN * 2);
    ushort* hbf_b  = (ushort*)alloc((size_t)N_NODES * HIDDEN * 2);
    ushort* xlb    = (ushort*)alloc((size_t)(N_NODES + 1) * HIDDEN * 2);  // +1 zero row
    uint4* pb      = (uint4*)alloc((size_t)N_LAYERS * 8 * 4 * 64 * 16);
    uint4* pb2     = (uint4*)alloc((size_t)N_LAYERS * 8 * 4 * 64 * 16);
    int* counts    = (int*)alloc((size_t)(N_NODES + 1) * 4);
    int* offsets   = (int*)alloc((size_t)(N_NODES + 1) * 4);
    int* partial   = (int*)alloc((size_t)N_NODES * 4);
    int* blocksum  = (int*)alloc(256 * 4);
    int* bcur      = (int*)alloc(256 * 4);
    int* padtotal  = (int*)alloc(256);
    uint2* bs      = (uint2*)alloc((size_t)PADMETA * 8);
    uint* meta     = (uint*)alloc((size_t)PADMETA * 4);
    int* gstart    = (int*)alloc((size_t)(N_GRAPHS + 1) * 4);
    float* ppart   = (float*)alloc((size_t)N_GRAPHS * PSPLIT * HIDDEN * 4);

    hipMemsetAsync(counts, 0, (size_t)(N_NODES + 1) * 4, stream);
    hipMemsetAsync(xlb + (size_t)N_NODES * HIDDEN, 0, HIDDEN * 2, stream); // zero xl row

    k_packw<<<(2 * N_LAYERS * 8 * 4 * 64 + 255) / 256, 256, 0, stream>>>(lw, fw2, pb, pb2);
    k_tab1<<<N_LAYERS * (TAB / TG), 128, 0, stream>>>(fw1, fb1, hidbf);
    k_tab2<<<(N_LAYERS * TAB) / 64, 256, 0, stream>>>(hidbf, pb2, fb2, (ushort*)ctab);
    k_embed<<<(N_NODES * 32 + 255) / 256, 256, 0, stream>>>(x, emb, hbf_a);
    k_count<<<(N_EDGES + 255) / 256, 256, 0, stream>>>(row, counts);
    const int NBLK = (N_NODES + 255) / 256;   // 196
    k_scan1<<<NBLK, 256, 0, stream>>>(counts, partial, blocksum);
    k_scan2<<<1, 256, 0, stream>>>(blocksum, NBLK, batch, gstart, padtotal);
    k_scan3<<<NBLK, 256, 0, stream>>>(partial, blocksum, padtotal, offsets, bcur);
    k_bucket<<<(N_EDGES + CHUNK - 1) / CHUNK, 256, 0, stream>>>(row, col, eattr, bcur, bs);
    k_scatter<<<NBUCK, 256, 0, stream>>>(bs, offsets, bcur, meta);

    ushort* hb_cur = hbf_a; ushort* hb_nxt = hbf_b;
    const int XLBLK = (N_NODES / 16 + 3) / 4;   // 3125 waves -> 782 blocks
    for (int i = 0; i < N_LAYERS; i++) {
        k_xl<<<XLBLK, 256, 0, stream>>>(hb_cur, pb + (size_t)i * 8 * 4 * 64,
                                        lb + i * HIDDEN, xlb);
        k_agg<<<(N_NODES + 3) / 4, 256, 0, stream>>>(xlb, meta, offsets,
                                                     ctab + (size_t)i * TAB * 64,
                                                     hb_cur, ln_g + i * HIDDEN,
                                                     ln_b + i * HIDDEN, hb_nxt);
        ushort* tb = hb_cur; hb_cur = hb_nxt; hb_nxt = tb;
    }
    k_pool_part<<<N_GRAPHS * PSPLIT, 256, 0, stream>>>(hb_cur, gstart, ppart);
    k_pool_fin<<<(N_GRAPHS * HIDDEN + 127) / 128, 128, 0, stream>>>(ppart, gstart, out);
}